// Round 8
// baseline (3713.589 us; speedup 1.0000x reference)
//
#include <hip/hip_runtime.h>

// MoE block: B=4,S=2048 -> T=8192 tokens, D=2048, F=8192, E=8, K=2
#define T_TOK 8192
#define DIM   2048
#define FFN   8192
#define NE    8
#define TOPK  2

typedef unsigned short ushort_t;
typedef unsigned short ushort8  __attribute__((ext_vector_type(8)));
typedef unsigned short ushort4v __attribute__((ext_vector_type(4)));
typedef short bf16x8 __attribute__((ext_vector_type(8)));
typedef float f32x4  __attribute__((ext_vector_type(4)));

__device__ __forceinline__ ushort_t f2bf(float f) {
  unsigned int u = __float_as_uint(f);
  u += 0x7FFFu + ((u >> 16) & 1u);   // RNE
  return (ushort_t)(u >> 16);
}
__device__ __forceinline__ float bf2f(ushort_t u) {
  return __uint_as_float(((unsigned int)u) << 16);
}

// async global->LDS, 16B per lane. LDS dest wave-uniform base; HW adds lane*16.
__device__ __forceinline__ void gload16(const void* g, void* l) {
  __builtin_amdgcn_global_load_lds((const __attribute__((address_space(1))) void*)g,
                                   (__attribute__((address_space(3))) void*)l, 16, 0, 0);
}
#define SBAR()  { __builtin_amdgcn_sched_barrier(0); __builtin_amdgcn_s_barrier(); __builtin_amdgcn_sched_barrier(0); }

// exact-erf GELU via Abramowitz-Stegun 7.1.26 (|err| <= 1.5e-7)
__device__ __forceinline__ float gelu_exact(float v) {
  float s = v * 0.70710678118654752f;
  float a = fabsf(s);
  float t = __builtin_amdgcn_rcpf(1.0f + 0.3275911f * a);
  float p = t * (0.254829592f +
            t * (-0.284496736f +
            t * (1.421413741f +
            t * (-1.453152027f +
            t * 1.061405429f))));
  float er = 1.0f - p * __expf(-a * a);
  er = copysignf(er, s);
  return 0.5f * v * (1.0f + er);
}

// ---------------- cast x -> bf16 ----------------
__global__ void k_cast(const float* __restrict__ x, ushort_t* __restrict__ xbf) {
  int i = blockIdx.x * blockDim.x + threadIdx.x;
  float4 v = reinterpret_cast<const float4*>(x)[i];
  ushort4v o;
  o.x = f2bf(v.x); o.y = f2bf(v.y); o.z = f2bf(v.z); o.w = f2bf(v.w);
  reinterpret_cast<ushort4v*>(xbf)[i] = o;
}

// ---------------- weight convert+transpose: fp32 [R][C] -> bf16 [C][R] ----------------
#define TT 64
__global__ __launch_bounds__(256) void k_wcvt(const float* __restrict__ in,
                                              ushort_t* __restrict__ outp, int R, int C) {
  __shared__ ushort_t t[TT][TT + 8];
  int e = blockIdx.z;
  const float* src = in + (size_t)e * R * C;
  ushort_t* dst = outp + (size_t)e * R * C;
  int r0 = blockIdx.y * TT, c0 = blockIdx.x * TT;
  int tid = threadIdx.x;
  int rr = tid >> 4;
  int c4 = tid & 15;
#pragma unroll
  for (int i = 0; i < 4; i++) {
    int r = rr + i * 16;
    float4 v = *reinterpret_cast<const float4*>(src + (size_t)(r0 + r) * C + c0 + c4 * 4);
    ushort4v p;
    p.x = f2bf(v.x); p.y = f2bf(v.y); p.z = f2bf(v.z); p.w = f2bf(v.w);
    *reinterpret_cast<ushort4v*>(&t[r][c4 * 4]) = p;
  }
  __syncthreads();
  int c = tid >> 2, rs = tid & 3;
  ushort_t tmp[16];
#pragma unroll
  for (int i = 0; i < 16; i++) tmp[i] = t[rs * 16 + i][c];
  ushort8 v0, v1;
#pragma unroll
  for (int i = 0; i < 8; i++) { v0[i] = tmp[i]; v1[i] = tmp[8 + i]; }
  ushort_t* drow = dst + (size_t)(c0 + c) * R + r0 + rs * 16;
  *reinterpret_cast<ushort8*>(drow) = v0;
  *reinterpret_cast<ushort8*>(drow + 8) = v1;
}

// ---------------- router ----------------
__global__ __launch_bounds__(256) void k_router(
    const float* __restrict__ x, const float* __restrict__ rw,
    int* __restrict__ tidx, float* __restrict__ twt, int* __restrict__ counts) {
  int t = blockIdx.x;
  int tid = threadIdx.x;
  int lane = tid & 63, wave = tid >> 6;
  float acc[NE];
#pragma unroll
  for (int e = 0; e < NE; e++) acc[e] = 0.f;
  const float* xr = x + (size_t)t * DIM;
  for (int d = tid; d < DIM; d += 256) {
    float xv = xr[d];
    const float* r = rw + d * NE;
#pragma unroll
    for (int e = 0; e < NE; e++) acc[e] += xv * r[e];
  }
  __shared__ float wsum[4][NE];
#pragma unroll
  for (int e = 0; e < NE; e++) {
    float v = acc[e];
#pragma unroll
    for (int off = 32; off > 0; off >>= 1) v += __shfl_down(v, off);
    if (lane == 0) wsum[wave][e] = v;
  }
  __syncthreads();
  if (tid == 0) {
    float lg[NE];
#pragma unroll
    for (int e = 0; e < NE; e++) lg[e] = wsum[0][e] + wsum[1][e] + wsum[2][e] + wsum[3][e];
    int i0 = 0; float v0 = lg[0];
#pragma unroll
    for (int e = 1; e < NE; e++) if (lg[e] > v0) { v0 = lg[e]; i0 = e; }
    int i1 = -1; float v1 = -3.4e38f;
#pragma unroll
    for (int e = 0; e < NE; e++) if (e != i0 && lg[e] > v1) { v1 = lg[e]; i1 = e; }
    float e1 = expf(v1 - v0);
    float s = 1.f + e1;
    tidx[t * 2 + 0] = i0; tidx[t * 2 + 1] = i1;
    twt[t * 2 + 0] = 1.f / s; twt[t * 2 + 1] = e1 / s;
    atomicAdd(&counts[i0], 1);
    atomicAdd(&counts[i1], 1);
  }
}

__global__ void k_scan(const int* __restrict__ counts, int* __restrict__ offsets) {
  if (threadIdx.x == 0) {
    int s = 0;
    for (int e = 0; e < NE; e++) { offsets[e] = s; s += counts[e]; }
    offsets[NE] = s;
  }
}

__global__ void k_fill(const int* __restrict__ tidx, const float* __restrict__ twt,
                       const int* __restrict__ offsets, int* __restrict__ cursors,
                       int* __restrict__ ltok, float* __restrict__ lwt, int* __restrict__ ppos) {
  int t = blockIdx.x * blockDim.x + threadIdx.x;
  if (t >= T_TOK) return;
#pragma unroll
  for (int k = 0; k < TOPK; k++) {
    int e = tidx[t * 2 + k];
    int pos = atomicAdd(&cursors[e], 1);
    int p = offsets[e] + pos;
    ltok[p] = t;
    lwt[p] = twt[t * 2 + k];
    ppos[t * 2 + k] = p;
  }
}

// ============ NEW GEMM1: 256x256xBK64, 8 waves, 4-phase deep pipeline ============
// LDS [buf][op A/B][half][128 rows x 64 cols] bf16 = 128 KiB (1 block/CU).
// XOR chunk swizzle (r7-verified, 0 conflicts): slot' = slot ^ (row&7), applied
// at stage SOURCE and ds_read, LDS dest stays linear.
// Schedule per K-tile t (c=t&1, o=c^1):
//  p0: read B[c](8)+A[c]q0(4); stage A[o]<-t+1 (4 ld); bar; MFMA q0; bar
//  p1: read A[c]q1;            stage B[c]h0<-t+2 (2);  bar; MFMA q1; bar
//  p2: read A[c]q2;            stage B[c]h1<-t+2 (2);  bar; MFMA q2; bar
//  p3: read A[c]q3;                                    bar; MFMA q3; vmcnt(4); bar
// vmcnt(4) leaves only this iter's B stages (read at t+2, covered by next boundary).
#define QBM 256
#define QBN 256
#define QBK 64

__global__ __launch_bounds__(512, 2) void k_gemm1(
    const ushort_t* __restrict__ xbf, const ushort_t* __restrict__ w1t, const float* __restrict__ b1,
    const int* __restrict__ counts, const int* __restrict__ offsets,
    const int* __restrict__ ltok, ushort_t* __restrict__ H) {
  int e = blockIdx.z;
  int cnt = counts[e];
  int row0 = blockIdx.x * QBM;
  if (row0 >= cnt) return;
  int base = offsets[e];
  int col0 = blockIdx.y * QBN;
  const ushort_t* Bt = w1t + (size_t)e * DIM * FFN;

  __shared__ __align__(16) ushort_t lds[2][2][2][128 * 64];

  int tid = threadIdx.x;
  int wid = tid >> 6, lane = tid & 63;
  int wm = wid >> 2, wn = wid & 3;        // 2x4 waves; wave output 128x64
  int lm = lane & 15, lg = lane >> 4;
  int swz = (lm & 7) * 8;                 // read-side XOR (elems)

  // staging sources: load l covers chunks l*512+tid; row=c>>3, slot=c&7, src slot=slot^(row&7)
  const ushort_t* aS[2][2]; const ushort_t* bS[2][2];
#pragma unroll
  for (int l = 0; l < 2; l++) {
    int ch = l * 512 + tid;
    int rr = ch >> 3;
    int ss = (ch & 7) ^ (rr & 7);
#pragma unroll
    for (int h = 0; h < 2; h++) {
      int ar = min(row0 + h * 128 + rr, cnt - 1);
      aS[h][l] = xbf + (size_t)ltok[base + ar] * DIM + ss * 8;
      bS[h][l] = Bt + (size_t)(col0 + h * 128 + rr) * DIM + ss * 8;
    }
  }
  auto STAGE_A = [&](int b, int k0) {
#pragma unroll
    for (int h = 0; h < 2; h++)
#pragma unroll
      for (int l = 0; l < 2; l++)
        gload16(aS[h][l] + k0, &lds[b][0][h][(l * 512 + wid * 64) * 8]);
  };
  auto STAGE_B = [&](int b, int h, int k0) {
#pragma unroll
    for (int l = 0; l < 2; l++)
      gload16(bS[h][l] + k0, &lds[b][1][h][(l * 512 + wid * 64) * 8]);
  };

  f32x4 acc[8][4];
#pragma unroll
  for (int m = 0; m < 8; m++)
#pragma unroll
    for (int n = 0; n < 4; n++) acc[m][n] = (f32x4){0.f, 0.f, 0.f, 0.f};

  bf16x8 bfr[4][2];
  auto LD_B = [&](int b) {
#pragma unroll
    for (int nf = 0; nf < 4; nf++) {
      int cI = wn * 64 + nf * 16 + lm;
      const ushort_t* Bh = &lds[b][1][cI >> 7][(cI & 127) * 64];
#pragma unroll
      for (int kk = 0; kk < 2; kk++)
        bfr[nf][kk] = *reinterpret_cast<const bf16x8*>(&Bh[((kk * 4 + lg) * 8) ^ swz]);
    }
  };
  auto PHASE_A_MM = [&](int b, int q) {   // q literal at call sites -> const-folded
    bf16x8 af[2][2];
#pragma unroll
    for (int mf = 0; mf < 2; mf++) {
      int rIH = q * 32 + mf * 16 + lm;
      const ushort_t* Ah = &lds[b][0][wm][rIH * 64];
#pragma unroll
      for (int kk = 0; kk < 2; kk++)
        af[mf][kk] = *reinterpret_cast<const bf16x8*>(&Ah[((kk * 4 + lg) * 8) ^ swz]);
    }
    SBAR();                                // pre-MFMA barrier
    __builtin_amdgcn_s_setprio(1);
#pragma unroll
    for (int mf = 0; mf < 2; mf++)
#pragma unroll
      for (int nf = 0; nf < 4; nf++)
#pragma unroll
        for (int kk = 0; kk < 2; kk++)
          acc[q * 2 + mf][nf] =
              __builtin_amdgcn_mfma_f32_16x16x32_bf16(af[mf][kk], bfr[nf][kk], acc[q * 2 + mf][nf], 0, 0, 0);
    __builtin_amdgcn_s_setprio(0);
  };

  // prologue: A[0]<-t0, B[0]<-t0, B[1]<-t1
  STAGE_A(0, 0);
  STAGE_B(0, 0, 0); STAGE_B(0, 1, 0);
  STAGE_B(1, 0, QBK); STAGE_B(1, 1, QBK);
  asm volatile("s_waitcnt vmcnt(0)" ::: "memory");
  SBAR();

  const int NT = DIM / QBK;
  for (int t = 0; t < NT; ++t) {
    int c = t & 1, o = c ^ 1;
    int kA = ((t + 1) * QBK) & (DIM - 1);   // A[o] <- tile t+1 (wraps harmlessly at tail)
    int kB = ((t + 2) * QBK) & (DIM - 1);   // B[c] <- tile t+2
    // p0
    LD_B(c);
    STAGE_A(o, kA);
    PHASE_A_MM(c, 0);
    SBAR();
    // p1
    STAGE_B(c, 0, kB);
    PHASE_A_MM(c, 1);
    SBAR();
    // p2
    STAGE_B(c, 1, kB);
    PHASE_A_MM(c, 2);
    SBAR();
    // p3
    PHASE_A_MM(c, 3);
    asm volatile("s_waitcnt vmcnt(4)" ::: "memory");   // A[o] + older landed; B(t+2) may fly
    SBAR();
  }

  // epilogue
#pragma unroll
  for (int m = 0; m < 8; m++) {
#pragma unroll
    for (int n = 0; n < 4; n++) {
      int f = col0 + wn * 64 + n * 16 + lm;
      float bias = b1[e * FFN + f];
#pragma unroll
      for (int r = 0; r < 4; r++) {
        int row = row0 + wm * 128 + m * 16 + lg * 4 + r;
        if (row < cnt) {
          float v = acc[m][n][r] + bias;
          H[(size_t)(base + row) * FFN + f] = f2bf(gelu_exact(v));
        }
      }
    }
  }
}

// ---------------- GEMM2: round-6 proven (128x128xBK32, 2-barrier, XCD swizzle) ----------------
#define G2BM 128
#define G2BN 128
#define G2BK 32

__device__ __forceinline__ void xcd_decode(int lin, int nwg, int nx, int& xt, int& yt) {
  int q = nwg >> 3;
  int w = (lin & 7) * q + (lin >> 3);
  xt = w % nx;
  yt = w / nx;
}

__global__ __launch_bounds__(256) void k_gemm2(
    const ushort_t* __restrict__ H, const ushort_t* __restrict__ w2t, const float* __restrict__ b2,
    const int* __restrict__ counts, const int* __restrict__ offsets,
    const float* __restrict__ lwt, ushort_t* __restrict__ contrib) {
  int e = blockIdx.z;
  int cnt = counts[e];
  int xt, yt;
  xcd_decode(blockIdx.x, (T_TOK / G2BM) * (DIM / G2BN), T_TOK / G2BM, xt, yt);
  int row0 = xt * G2BM;
  if (row0 >= cnt) return;
  int base = offsets[e];
  int col0 = yt * G2BN;
  const ushort_t* Bt = w2t + (size_t)e * DIM * FFN;

  __shared__ __align__(16) ushort_t As[G2BM * G2BK];
  __shared__ __align__(16) ushort_t Bs[G2BM * G2BK];

  int tid = threadIdx.x;
  int wave = tid >> 6, lane = tid & 63;
  int wm = wave >> 1, wn = wave & 1;
  int lm = lane & 15, lg = lane >> 4;

  int srow = tid >> 2, seg = tid & 3;
  const ushort_t* asrc[2]; const ushort_t* bsrc[2];
#pragma unroll
  for (int j = 0; j < 2; j++) {
    int ar = min(row0 + j * 64 + srow, cnt - 1);
    asrc[j] = H + (size_t)(base + ar) * FFN + seg * 8;
    bsrc[j] = Bt + (size_t)(col0 + j * 64 + srow) * FFN + seg * 8;
  }
  f32x4 acc[4][4];
#pragma unroll
  for (int m = 0; m < 4; m++)
#pragma unroll
    for (int n = 0; n < 4; n++) acc[m][n] = (f32x4){0.f, 0.f, 0.f, 0.f};

  for (int k0 = 0; k0 < FFN; k0 += G2BK) {
#pragma unroll
    for (int j = 0; j < 2; j++) {
      gload16(asrc[j] + k0, &As[(j * 256 + wave * 64) * 8]);
      gload16(bsrc[j] + k0, &Bs[(j * 256 + wave * 64) * 8]);
    }
    __syncthreads();
    bf16x8 af[4], bfv[4];
#pragma unroll
    for (int m = 0; m < 4; m++)
      af[m] = *reinterpret_cast<const bf16x8*>(&As[(wm * 64 + m * 16 + lm) * G2BK + lg * 8]);
#pragma unroll
    for (int n = 0; n < 4; n++)
      bfv[n] = *reinterpret_cast<const bf16x8*>(&Bs[(wn * 64 + n * 16 + lm) * G2BK + lg * 8]);
#pragma unroll
    for (int m = 0; m < 4; m++)
#pragma unroll
      for (int n = 0; n < 4; n++)
        acc[m][n] = __builtin_amdgcn_mfma_f32_16x16x32_bf16(af[m], bfv[n], acc[m][n], 0, 0, 0);
    __syncthreads();
  }
#pragma unroll
  for (int m = 0; m < 4; m++) {
#pragma unroll
    for (int n = 0; n < 4; n++) {
      int d = col0 + wn * 64 + n * 16 + lm;
      float bias = b2[e * DIM + d];
#pragma unroll
      for (int r = 0; r < 4; r++) {
        int row = row0 + wm * 64 + m * 16 + lg * 4 + r;
        if (row < cnt) {
          float v = (acc[m][n][r] + bias) * lwt[base + row];
          contrib[(size_t)(base + row) * DIM + d] = f2bf(v);
        }
      }
    }
  }
}

// ---------------- combine: out = x + contrib[p0] + contrib[p1] ----------------
__global__ void k_combine(const float* __restrict__ x, const ushort_t* __restrict__ contrib,
                          const int* __restrict__ ppos, float* __restrict__ out) {
  int i = blockIdx.x * blockDim.x + threadIdx.x;
  int t = i / (DIM / 4);
  int dq = i % (DIM / 4);
  int p0 = ppos[t * 2 + 0], p1 = ppos[t * 2 + 1];
  float4 xv = reinterpret_cast<const float4*>(x)[i];
  ushort4v c0 = reinterpret_cast<const ushort4v*>(contrib + (size_t)p0 * DIM)[dq];
  ushort4v c1 = reinterpret_cast<const ushort4v*>(contrib + (size_t)p1 * DIM)[dq];
  float4 o;
  o.x = xv.x + bf2f(c0.x) + bf2f(c1.x);
  o.y = xv.y + bf2f(c0.y) + bf2f(c1.y);
  o.z = xv.z + bf2f(c0.z) + bf2f(c1.z);
  o.w = xv.w + bf2f(c0.w) + bf2f(c1.w);
  reinterpret_cast<float4*>(out)[i] = o;
}

extern "C" void kernel_launch(void* const* d_in, const int* in_sizes, int n_in,
                              void* d_out, int out_size, void* d_ws, size_t ws_size,
                              hipStream_t stream) {
  const float* x  = (const float*)d_in[0];
  const float* rw = (const float*)d_in[1];
  const float* w1 = (const float*)d_in[2];
  const float* b1 = (const float*)d_in[3];
  const float* w2 = (const float*)d_in[4];
  const float* b2 = (const float*)d_in[5];
  float* out = (float*)d_out;
  char* ws = (char*)d_ws;

  const size_t MB = 1u << 20;
  int*   counts  = (int*)(ws);
  int*   offsets = (int*)(ws + 64);
  int*   cursors = (int*)(ws + 128);
  int*   tidx    = (int*)(ws + 1 * MB);
  float* twt     = (float*)(ws + 2 * MB);
  int*   ltok    = (int*)(ws + 3 * MB);
  float* lwt     = (float*)(ws + 4 * MB);
  int*   ppos    = (int*)(ws + 5 * MB);
  // overlaid big buffers (lifetimes disjoint where they overlap):
  ushort_t* xbf     = (ushort_t*)(ws + 8 * MB);     // 32 MB, live cast..gemm1
  ushort_t* contrib = (ushort_t*)(ws + 8 * MB);     // 64 MB, live gemm2..combine (xbf dead)
  ushort_t* Hbuf    = (ushort_t*)(ws + 72 * MB);    // 256 MB, live gemm1..gemm2
  ushort_t* w1t     = (ushort_t*)(ws + 328 * MB);   // 256 MB, live wcvt1..gemm1
  ushort_t* w2t     = (ushort_t*)(ws + 328 * MB);   // 256 MB, live wcvt2..gemm2 (after gemm1)
  const size_t NEED = 584 * MB;
  if (ws_size < NEED) {
    hipMemsetAsync(d_out, 0, (size_t)out_size * sizeof(float), stream);
    return;
  }

  hipMemsetAsync(ws, 0, 256, stream);  // counts + cursors
  k_cast<<<dim3((T_TOK * (size_t)DIM / 4) / 256), 256, 0, stream>>>(x, xbf);
  k_router<<<T_TOK, 256, 0, stream>>>(x, rw, tidx, twt, counts);
  k_scan<<<1, 64, 0, stream>>>(counts, offsets);
  k_fill<<<T_TOK / 256, 256, 0, stream>>>(tidx, twt, offsets, cursors, ltok, lwt, ppos);
  // w1: [E][D][F] fp32 -> w1t [E][F][D] bf16
  k_wcvt<<<dim3(FFN / TT, DIM / TT, NE), 256, 0, stream>>>(w1, w1t, DIM, FFN);
  k_gemm1<<<dim3(T_TOK / QBM, FFN / QBN, NE), 512, 0, stream>>>(xbf, w1t, b1, counts, offsets, ltok, Hbuf);
  // w2: [E][F][D] fp32 -> w2t [E][D][F] bf16  (after gemm1; reuses w1t region)
  k_wcvt<<<dim3(DIM / TT, FFN / TT, NE), 256, 0, stream>>>(w2, w2t, FFN, DIM);
  k_gemm2<<<dim3((T_TOK / G2BM) * (DIM / G2BN), 1, NE), 256, 0, stream>>>(Hbuf, w2t, b2, counts, offsets, lwt, contrib);
  k_combine<<<dim3((T_TOK * (size_t)DIM / 4) / 256), 256, 0, stream>>>(x, contrib, ppos, out);
}

// Round 9
// 2385.064 us; speedup vs baseline: 1.5570x; 1.5570x over previous
//
#include <hip/hip_runtime.h>

// MoE block: B=4,S=2048 -> T=8192 tokens, D=2048, F=8192, E=8, K=2
#define T_TOK 8192
#define DIM   2048
#define FFN   8192
#define NE    8
#define TOPK  2

typedef unsigned short ushort_t;
typedef unsigned short ushort8  __attribute__((ext_vector_type(8)));
typedef unsigned short ushort4v __attribute__((ext_vector_type(4)));
typedef short bf16x8 __attribute__((ext_vector_type(8)));
typedef float f32x4  __attribute__((ext_vector_type(4)));

__device__ __forceinline__ ushort_t f2bf(float f) {
  unsigned int u = __float_as_uint(f);
  u += 0x7FFFu + ((u >> 16) & 1u);   // RNE
  return (ushort_t)(u >> 16);
}
__device__ __forceinline__ float bf2f(ushort_t u) {
  return __uint_as_float(((unsigned int)u) << 16);
}

// async global->LDS, 16B per lane. LDS dest wave-uniform base; HW adds lane*16.
__device__ __forceinline__ void gload16(const void* g, void* l) {
  __builtin_amdgcn_global_load_lds((const __attribute__((address_space(1))) void*)g,
                                   (__attribute__((address_space(3))) void*)l, 16, 0, 0);
}
// LDS byte offset of a shared-memory pointer (for inline-asm ds_read)
__device__ __forceinline__ unsigned lds_off(const ushort_t* p) {
  return (unsigned)(uintptr_t)(__attribute__((address_space(3))) const ushort_t*)p;
}
// invisible LDS read: compiler can't see this touches LDS -> no auto vmcnt drain
__device__ __forceinline__ bf16x8 ds_read128(unsigned off) {
  bf16x8 r;
  asm volatile("ds_read_b128 %0, %1" : "=v"(r) : "v"(off));
  return r;
}

// exact-erf GELU via Abramowitz-Stegun 7.1.26 (|err| <= 1.5e-7)
__device__ __forceinline__ float gelu_exact(float v) {
  float s = v * 0.70710678118654752f;
  float a = fabsf(s);
  float t = __builtin_amdgcn_rcpf(1.0f + 0.3275911f * a);
  float p = t * (0.254829592f +
            t * (-0.284496736f +
            t * (1.421413741f +
            t * (-1.453152027f +
            t * 1.061405429f))));
  float er = 1.0f - p * __expf(-a * a);
  er = copysignf(er, s);
  return 0.5f * v * (1.0f + er);
}

// ---------------- cast x -> bf16 ----------------
__global__ void k_cast(const float* __restrict__ x, ushort_t* __restrict__ xbf) {
  int i = blockIdx.x * blockDim.x + threadIdx.x;
  float4 v = reinterpret_cast<const float4*>(x)[i];
  ushort4v o;
  o.x = f2bf(v.x); o.y = f2bf(v.y); o.z = f2bf(v.z); o.w = f2bf(v.w);
  reinterpret_cast<ushort4v*>(xbf)[i] = o;
}

// ---------------- weight convert+transpose: fp32 [R][C] -> bf16 [C][R] ----------------
#define TT 64
__global__ __launch_bounds__(256) void k_wcvt(const float* __restrict__ in,
                                              ushort_t* __restrict__ outp, int R, int C) {
  __shared__ ushort_t t[TT][TT + 8];
  int e = blockIdx.z;
  const float* src = in + (size_t)e * R * C;
  ushort_t* dst = outp + (size_t)e * R * C;
  int r0 = blockIdx.y * TT, c0 = blockIdx.x * TT;
  int tid = threadIdx.x;
  int rr = tid >> 4;
  int c4 = tid & 15;
#pragma unroll
  for (int i = 0; i < 4; i++) {
    int r = rr + i * 16;
    float4 v = *reinterpret_cast<const float4*>(src + (size_t)(r0 + r) * C + c0 + c4 * 4);
    ushort4v p;
    p.x = f2bf(v.x); p.y = f2bf(v.y); p.z = f2bf(v.z); p.w = f2bf(v.w);
    *reinterpret_cast<ushort4v*>(&t[r][c4 * 4]) = p;
  }
  __syncthreads();
  int c = tid >> 2, rs = tid & 3;
  ushort_t tmp[16];
#pragma unroll
  for (int i = 0; i < 16; i++) tmp[i] = t[rs * 16 + i][c];
  ushort8 v0, v1;
#pragma unroll
  for (int i = 0; i < 8; i++) { v0[i] = tmp[i]; v1[i] = tmp[8 + i]; }
  ushort_t* drow = dst + (size_t)(c0 + c) * R + r0 + rs * 16;
  *reinterpret_cast<ushort8*>(drow) = v0;
  *reinterpret_cast<ushort8*>(drow + 8) = v1;
}

// ---------------- router ----------------
__global__ __launch_bounds__(256) void k_router(
    const float* __restrict__ x, const float* __restrict__ rw,
    int* __restrict__ tidx, float* __restrict__ twt, int* __restrict__ counts) {
  int t = blockIdx.x;
  int tid = threadIdx.x;
  int lane = tid & 63, wave = tid >> 6;
  float acc[NE];
#pragma unroll
  for (int e = 0; e < NE; e++) acc[e] = 0.f;
  const float* xr = x + (size_t)t * DIM;
  for (int d = tid; d < DIM; d += 256) {
    float xv = xr[d];
    const float* r = rw + d * NE;
#pragma unroll
    for (int e = 0; e < NE; e++) acc[e] += xv * r[e];
  }
  __shared__ float wsum[4][NE];
#pragma unroll
  for (int e = 0; e < NE; e++) {
    float v = acc[e];
#pragma unroll
    for (int off = 32; off > 0; off >>= 1) v += __shfl_down(v, off);
    if (lane == 0) wsum[wave][e] = v;
  }
  __syncthreads();
  if (tid == 0) {
    float lg[NE];
#pragma unroll
    for (int e = 0; e < NE; e++) lg[e] = wsum[0][e] + wsum[1][e] + wsum[2][e] + wsum[3][e];
    int i0 = 0; float v0 = lg[0];
#pragma unroll
    for (int e = 1; e < NE; e++) if (lg[e] > v0) { v0 = lg[e]; i0 = e; }
    int i1 = -1; float v1 = -3.4e38f;
#pragma unroll
    for (int e = 0; e < NE; e++) if (e != i0 && lg[e] > v1) { v1 = lg[e]; i1 = e; }
    float e1 = expf(v1 - v0);
    float s = 1.f + e1;
    tidx[t * 2 + 0] = i0; tidx[t * 2 + 1] = i1;
    twt[t * 2 + 0] = 1.f / s; twt[t * 2 + 1] = e1 / s;
    atomicAdd(&counts[i0], 1);
    atomicAdd(&counts[i1], 1);
  }
}

__global__ void k_scan(const int* __restrict__ counts, int* __restrict__ offsets) {
  if (threadIdx.x == 0) {
    int s = 0;
    for (int e = 0; e < NE; e++) { offsets[e] = s; s += counts[e]; }
    offsets[NE] = s;
  }
}

__global__ void k_fill(const int* __restrict__ tidx, const float* __restrict__ twt,
                       const int* __restrict__ offsets, int* __restrict__ cursors,
                       int* __restrict__ ltok, float* __restrict__ lwt, int* __restrict__ ppos) {
  int t = blockIdx.x * blockDim.x + threadIdx.x;
  if (t >= T_TOK) return;
#pragma unroll
  for (int k = 0; k < TOPK; k++) {
    int e = tidx[t * 2 + k];
    int pos = atomicAdd(&cursors[e], 1);
    int p = offsets[e] + pos;
    ltok[p] = t;
    lwt[p] = twt[t * 2 + k];
    ppos[t * 2 + k] = p;
  }
}

// ==== GEMMs: 128x128xBK32 (r6-proven) + LDS dbuf + counted vmcnt + asm ds_read ====
#define BM 128
#define BN 128
#define BK 32
#define BUFB (BM * BK * 2)   // bytes per A (or B) buffer

__device__ __forceinline__ void xcd_decode(int lin, int nwg, int nx, int& xt, int& yt) {
  int q = nwg >> 3;
  int w = (lin & 7) * q + (lin >> 3);
  xt = w % nx;
  yt = w / nx;
}

// The shared K-loop body for both GEMMs. aptrs/bptrs advance by k; LDS dbuf.
// Per iter: STAGE(next) -> vmcnt(4) -> barrier -> asm ds_read(cur) ->
// lgkmcnt(0)+sched_barrier -> 16 MFMA -> barrier. No vmcnt(0) in steady state.
template <int NT>
__device__ __forceinline__ void gemm_loop(const ushort_t* __restrict__ a0,
                                          const ushort_t* __restrict__ a1,
                                          const ushort_t* __restrict__ b0,
                                          const ushort_t* __restrict__ b1,
                                          ushort_t* AsLds, ushort_t* BsLds,
                                          f32x4 (&acc)[4][4]) {
  int tid = threadIdx.x;
  int wave = tid >> 6, lane = tid & 63;
  int wm = wave >> 1, wn = wave & 1;
  int lm = lane & 15, lg = lane >> 4;

  unsigned abase = lds_off(AsLds), bbase = lds_off(BsLds);
  // fragment byte offsets (k-invariant, per-thread constant)
  unsigned aoff[4], boff[4];
#pragma unroll
  for (int m = 0; m < 4; m++)
    aoff[m] = abase + ((wm * 64 + m * 16 + lm) * BK + lg * 8) * 2;
#pragma unroll
  for (int n = 0; n < 4; n++)
    boff[n] = bbase + ((wn * 64 + n * 16 + lm) * BK + lg * 8) * 2;

  // stage dest (per-wave uniform) inside a buffer, in bytes from buffer start
  unsigned sdA = (unsigned)((size_t)(wave * 64) * 16);   // + j*256 chunks *16B
  const ushort_t* ap[2] = {a0, a1};
  const ushort_t* bp[2] = {b0, b1};

  auto STAGE = [&](int buf, int k0) {
#pragma unroll
    for (int j = 0; j < 2; j++) {
      gload16(ap[j] + k0, AsLds + buf * (BM * BK) + (j * 256 + wave * 64) * 8);
      gload16(bp[j] + k0, BsLds + buf * (BM * BK) + (j * 256 + wave * 64) * 8);
    }
  };
  (void)sdA;

  STAGE(0, 0);
  int cur = 0;
  for (int t = 0; t < NT; ++t) {
    if (t < NT - 1) {
      STAGE(cur ^ 1, (t + 1) * BK);
      __builtin_amdgcn_sched_barrier(0);
      asm volatile("s_waitcnt vmcnt(4)" ::: "memory");   // cur's 4 loads landed
    } else {
      __builtin_amdgcn_sched_barrier(0);
      asm volatile("s_waitcnt vmcnt(0)" ::: "memory");
    }
    __builtin_amdgcn_s_barrier();
    __builtin_amdgcn_sched_barrier(0);
    unsigned cb = (unsigned)(cur * BUFB);
    bf16x8 af[4], bv[4];
#pragma unroll
    for (int m = 0; m < 4; m++) af[m] = ds_read128(aoff[m] + cb);
#pragma unroll
    for (int n = 0; n < 4; n++) bv[n] = ds_read128(boff[n] + cb);
    asm volatile("s_waitcnt lgkmcnt(0)" ::: "memory");
    __builtin_amdgcn_sched_barrier(0);
#pragma unroll
    for (int m = 0; m < 4; m++)
#pragma unroll
      for (int n = 0; n < 4; n++)
        acc[m][n] = __builtin_amdgcn_mfma_f32_16x16x32_bf16(af[m], bv[n], acc[m][n], 0, 0, 0);
    __builtin_amdgcn_sched_barrier(0);
    __builtin_amdgcn_s_barrier();     // protects cur buffer from next STAGE overwrite
    __builtin_amdgcn_sched_barrier(0);
    cur ^= 1;
  }
}

// GEMM1: H[p,f] = gelu( gather(x)[p,:] @ w1t[e]^T + b1[e] )   w1t: [F][D] bf16
__global__ __launch_bounds__(256) void k_gemm1(
    const ushort_t* __restrict__ xbf, const ushort_t* __restrict__ w1t, const float* __restrict__ b1,
    const int* __restrict__ counts, const int* __restrict__ offsets,
    const int* __restrict__ ltok, ushort_t* __restrict__ H) {
  int e = blockIdx.z;
  int cnt = counts[e];
  int xt, yt;
  xcd_decode(blockIdx.x, (T_TOK / BM) * (FFN / BN), T_TOK / BM, xt, yt);
  int row0 = xt * BM;
  if (row0 >= cnt) return;
  int base = offsets[e];
  int col0 = yt * BN;
  const ushort_t* Bt = w1t + (size_t)e * DIM * FFN;

  __shared__ __align__(16) ushort_t As[2 * BM * BK];
  __shared__ __align__(16) ushort_t Bs[2 * BM * BK];

  int tid = threadIdx.x;
  int srow = tid >> 2, seg = tid & 3;
  const ushort_t* asrc[2]; const ushort_t* bsrc[2];
#pragma unroll
  for (int j = 0; j < 2; j++) {
    int ar = min(row0 + j * 64 + srow, cnt - 1);
    asrc[j] = xbf + (size_t)ltok[base + ar] * DIM + seg * 8;
    bsrc[j] = Bt + (size_t)(col0 + j * 64 + srow) * DIM + seg * 8;
  }
  f32x4 acc[4][4];
#pragma unroll
  for (int m = 0; m < 4; m++)
#pragma unroll
    for (int n = 0; n < 4; n++) acc[m][n] = (f32x4){0.f, 0.f, 0.f, 0.f};

  gemm_loop<DIM / BK>(asrc[0], asrc[1], bsrc[0], bsrc[1], As, Bs, acc);

  int wave = tid >> 6, lane = tid & 63;
  int wm = wave >> 1, wn = wave & 1;
  int lm = lane & 15, lg = lane >> 4;
#pragma unroll
  for (int m = 0; m < 4; m++) {
#pragma unroll
    for (int n = 0; n < 4; n++) {
      int f = col0 + wn * 64 + n * 16 + lm;
      float bias = b1[e * FFN + f];
#pragma unroll
      for (int r = 0; r < 4; r++) {
        int row = row0 + wm * 64 + m * 16 + lg * 4 + r;
        if (row < cnt) {
          float v = acc[m][n][r] + bias;
          H[(size_t)(base + row) * FFN + f] = f2bf(gelu_exact(v));
        }
      }
    }
  }
}

// GEMM2: contrib[p,d] = cw[p] * ( H[p,:] @ w2t[e]^T + b2[e] )   w2t: [D][F] bf16
__global__ __launch_bounds__(256) void k_gemm2(
    const ushort_t* __restrict__ H, const ushort_t* __restrict__ w2t, const float* __restrict__ b2,
    const int* __restrict__ counts, const int* __restrict__ offsets,
    const float* __restrict__ lwt, ushort_t* __restrict__ contrib) {
  int e = blockIdx.z;
  int cnt = counts[e];
  int xt, yt;
  xcd_decode(blockIdx.x, (T_TOK / BM) * (DIM / BN), T_TOK / BM, xt, yt);
  int row0 = xt * BM;
  if (row0 >= cnt) return;
  int base = offsets[e];
  int col0 = yt * BN;
  const ushort_t* Bt = w2t + (size_t)e * DIM * FFN;

  __shared__ __align__(16) ushort_t As[2 * BM * BK];
  __shared__ __align__(16) ushort_t Bs[2 * BM * BK];

  int tid = threadIdx.x;
  int srow = tid >> 2, seg = tid & 3;
  const ushort_t* asrc[2]; const ushort_t* bsrc[2];
#pragma unroll
  for (int j = 0; j < 2; j++) {
    int ar = min(row0 + j * 64 + srow, cnt - 1);
    asrc[j] = H + (size_t)(base + ar) * FFN + seg * 8;
    bsrc[j] = Bt + (size_t)(col0 + j * 64 + srow) * FFN + seg * 8;
  }
  f32x4 acc[4][4];
#pragma unroll
  for (int m = 0; m < 4; m++)
#pragma unroll
    for (int n = 0; n < 4; n++) acc[m][n] = (f32x4){0.f, 0.f, 0.f, 0.f};

  gemm_loop<FFN / BK>(asrc[0], asrc[1], bsrc[0], bsrc[1], As, Bs, acc);

  int wave = tid >> 6, lane = tid & 63;
  int wm = wave >> 1, wn = wave & 1;
  int lm = lane & 15, lg = lane >> 4;
#pragma unroll
  for (int m = 0; m < 4; m++) {
#pragma unroll
    for (int n = 0; n < 4; n++) {
      int d = col0 + wn * 64 + n * 16 + lm;
      float bias = b2[e * DIM + d];
#pragma unroll
      for (int r = 0; r < 4; r++) {
        int row = row0 + wm * 64 + m * 16 + lg * 4 + r;
        if (row < cnt) {
          float v = (acc[m][n][r] + bias) * lwt[base + row];
          contrib[(size_t)(base + row) * DIM + d] = f2bf(v);
        }
      }
    }
  }
}

// ---------------- combine: out = x + contrib[p0] + contrib[p1] ----------------
__global__ void k_combine(const float* __restrict__ x, const ushort_t* __restrict__ contrib,
                          const int* __restrict__ ppos, float* __restrict__ out) {
  int i = blockIdx.x * blockDim.x + threadIdx.x;
  int t = i / (DIM / 4);
  int dq = i % (DIM / 4);
  int p0 = ppos[t * 2 + 0], p1 = ppos[t * 2 + 1];
  float4 xv = reinterpret_cast<const float4*>(x)[i];
  ushort4v c0 = reinterpret_cast<const ushort4v*>(contrib + (size_t)p0 * DIM)[dq];
  ushort4v c1 = reinterpret_cast<const ushort4v*>(contrib + (size_t)p1 * DIM)[dq];
  float4 o;
  o.x = xv.x + bf2f(c0.x) + bf2f(c1.x);
  o.y = xv.y + bf2f(c0.y) + bf2f(c1.y);
  o.z = xv.z + bf2f(c0.z) + bf2f(c1.z);
  o.w = xv.w + bf2f(c0.w) + bf2f(c1.w);
  reinterpret_cast<float4*>(out)[i] = o;
}

extern "C" void kernel_launch(void* const* d_in, const int* in_sizes, int n_in,
                              void* d_out, int out_size, void* d_ws, size_t ws_size,
                              hipStream_t stream) {
  const float* x  = (const float*)d_in[0];
  const float* rw = (const float*)d_in[1];
  const float* w1 = (const float*)d_in[2];
  const float* b1 = (const float*)d_in[3];
  const float* w2 = (const float*)d_in[4];
  const float* b2 = (const float*)d_in[5];
  float* out = (float*)d_out;
  char* ws = (char*)d_ws;

  const size_t MB = 1u << 20;
  int*   counts  = (int*)(ws);
  int*   offsets = (int*)(ws + 64);
  int*   cursors = (int*)(ws + 128);
  int*   tidx    = (int*)(ws + 1 * MB);
  float* twt     = (float*)(ws + 2 * MB);
  int*   ltok    = (int*)(ws + 3 * MB);
  float* lwt     = (float*)(ws + 4 * MB);
  int*   ppos    = (int*)(ws + 5 * MB);
  // overlaid big buffers (lifetimes disjoint where they overlap):
  ushort_t* xbf     = (ushort_t*)(ws + 8 * MB);     // 32 MB, live cast..gemm1
  ushort_t* contrib = (ushort_t*)(ws + 8 * MB);     // 64 MB, live gemm2..combine (xbf dead)
  ushort_t* Hbuf    = (ushort_t*)(ws + 72 * MB);    // 256 MB, live gemm1..gemm2
  ushort_t* w1t     = (ushort_t*)(ws + 328 * MB);   // 256 MB, live wcvt1..gemm1
  ushort_t* w2t     = (ushort_t*)(ws + 328 * MB);   // 256 MB, live wcvt2..gemm2 (after gemm1)
  const size_t NEED = 584 * MB;
  if (ws_size < NEED) {
    hipMemsetAsync(d_out, 0, (size_t)out_size * sizeof(float), stream);
    return;
  }

  hipMemsetAsync(ws, 0, 256, stream);  // counts + cursors
  k_cast<<<dim3((T_TOK * (size_t)DIM / 4) / 256), 256, 0, stream>>>(x, xbf);
  k_router<<<T_TOK, 256, 0, stream>>>(x, rw, tidx, twt, counts);
  k_scan<<<1, 64, 0, stream>>>(counts, offsets);
  k_fill<<<T_TOK / 256, 256, 0, stream>>>(tidx, twt, offsets, cursors, ltok, lwt, ppos);
  // w1: [E][D][F] fp32 -> w1t [E][F][D] bf16
  k_wcvt<<<dim3(FFN / TT, DIM / TT, NE), 256, 0, stream>>>(w1, w1t, DIM, FFN);
  k_gemm1<<<dim3((T_TOK / BM) * (FFN / BN), 1, NE), 256, 0, stream>>>(xbf, w1t, b1, counts, offsets, ltok, Hbuf);
  // w2: [E][F][D] fp32 -> w2t [E][D][F] bf16  (after gemm1; reuses w1t region)
  k_wcvt<<<dim3(DIM / TT, FFN / TT, NE), 256, 0, stream>>>(w2, w2t, FFN, DIM);
  k_gemm2<<<dim3((T_TOK / BM) * (DIM / BN), 1, NE), 256, 0, stream>>>(Hbuf, w2t, b2, counts, offsets, lwt, contrib);
  k_combine<<<dim3((T_TOK * (size_t)DIM / 4) / 256), 256, 0, stream>>>(x, contrib, ppos, out);
}

// Round 10
// 2339.699 us; speedup vs baseline: 1.5872x; 1.0194x over previous
//
#include <hip/hip_runtime.h>

// MoE block: B=4,S=2048 -> T=8192 tokens, D=2048, F=8192, E=8, K=2
#define T_TOK 8192
#define DIM   2048
#define FFN   8192
#define NE    8
#define TOPK  2

typedef unsigned short ushort_t;
typedef unsigned short ushort8  __attribute__((ext_vector_type(8)));
typedef unsigned short ushort4v __attribute__((ext_vector_type(4)));
typedef short bf16x8 __attribute__((ext_vector_type(8)));
typedef float f32x4  __attribute__((ext_vector_type(4)));

__device__ __forceinline__ ushort_t f2bf(float f) {
  unsigned int u = __float_as_uint(f);
  u += 0x7FFFu + ((u >> 16) & 1u);   // RNE
  return (ushort_t)(u >> 16);
}
__device__ __forceinline__ float bf2f(ushort_t u) {
  return __uint_as_float(((unsigned int)u) << 16);
}

// async global->LDS, 16B per lane. LDS dest wave-uniform base; HW adds lane*16.
__device__ __forceinline__ void gload16(const void* g, void* l) {
  __builtin_amdgcn_global_load_lds((const __attribute__((address_space(1))) void*)g,
                                   (__attribute__((address_space(3))) void*)l, 16, 0, 0);
}
// LDS byte offset of a shared-memory pointer (for inline-asm ds_read)
__device__ __forceinline__ unsigned lds_off(const ushort_t* p) {
  return (unsigned)(uintptr_t)(__attribute__((address_space(3))) const ushort_t*)p;
}
// invisible LDS read: compiler can't see this touches LDS -> no auto vmcnt drain
__device__ __forceinline__ bf16x8 ds_read128(unsigned off) {
  bf16x8 r;
  asm volatile("ds_read_b128 %0, %1" : "=v"(r) : "v"(off));
  return r;
}

// exact-erf GELU via Abramowitz-Stegun 7.1.26 (|err| <= 1.5e-7)
__device__ __forceinline__ float gelu_exact(float v) {
  float s = v * 0.70710678118654752f;
  float a = fabsf(s);
  float t = __builtin_amdgcn_rcpf(1.0f + 0.3275911f * a);
  float p = t * (0.254829592f +
            t * (-0.284496736f +
            t * (1.421413741f +
            t * (-1.453152027f +
            t * 1.061405429f))));
  float er = 1.0f - p * __expf(-a * a);
  er = copysignf(er, s);
  return 0.5f * v * (1.0f + er);
}

// ---------------- cast x -> bf16 ----------------
__global__ void k_cast(const float* __restrict__ x, ushort_t* __restrict__ xbf) {
  int i = blockIdx.x * blockDim.x + threadIdx.x;
  float4 v = reinterpret_cast<const float4*>(x)[i];
  ushort4v o;
  o.x = f2bf(v.x); o.y = f2bf(v.y); o.z = f2bf(v.z); o.w = f2bf(v.w);
  reinterpret_cast<ushort4v*>(xbf)[i] = o;
}

// ---------------- weight convert+transpose: fp32 [R][C] -> bf16 [C][R] ----------------
#define TT 64
__global__ __launch_bounds__(256) void k_wcvt(const float* __restrict__ in,
                                              ushort_t* __restrict__ outp, int R, int C) {
  __shared__ ushort_t t[TT][TT + 8];
  int e = blockIdx.z;
  const float* src = in + (size_t)e * R * C;
  ushort_t* dst = outp + (size_t)e * R * C;
  int r0 = blockIdx.y * TT, c0 = blockIdx.x * TT;
  int tid = threadIdx.x;
  int rr = tid >> 4;
  int c4 = tid & 15;
#pragma unroll
  for (int i = 0; i < 4; i++) {
    int r = rr + i * 16;
    float4 v = *reinterpret_cast<const float4*>(src + (size_t)(r0 + r) * C + c0 + c4 * 4);
    ushort4v p;
    p.x = f2bf(v.x); p.y = f2bf(v.y); p.z = f2bf(v.z); p.w = f2bf(v.w);
    *reinterpret_cast<ushort4v*>(&t[r][c4 * 4]) = p;
  }
  __syncthreads();
  int c = tid >> 2, rs = tid & 3;
  ushort_t tmp[16];
#pragma unroll
  for (int i = 0; i < 16; i++) tmp[i] = t[rs * 16 + i][c];
  ushort8 v0, v1;
#pragma unroll
  for (int i = 0; i < 8; i++) { v0[i] = tmp[i]; v1[i] = tmp[8 + i]; }
  ushort_t* drow = dst + (size_t)(c0 + c) * R + r0 + rs * 16;
  *reinterpret_cast<ushort8*>(drow) = v0;
  *reinterpret_cast<ushort8*>(drow + 8) = v1;
}

// ---------------- router ----------------
__global__ __launch_bounds__(256) void k_router(
    const float* __restrict__ x, const float* __restrict__ rw,
    int* __restrict__ tidx, float* __restrict__ twt, int* __restrict__ counts) {
  int t = blockIdx.x;
  int tid = threadIdx.x;
  int lane = tid & 63, wave = tid >> 6;
  float acc[NE];
#pragma unroll
  for (int e = 0; e < NE; e++) acc[e] = 0.f;
  const float* xr = x + (size_t)t * DIM;
  for (int d = tid; d < DIM; d += 256) {
    float xv = xr[d];
    const float* r = rw + d * NE;
#pragma unroll
    for (int e = 0; e < NE; e++) acc[e] += xv * r[e];
  }
  __shared__ float wsum[4][NE];
#pragma unroll
  for (int e = 0; e < NE; e++) {
    float v = acc[e];
#pragma unroll
    for (int off = 32; off > 0; off >>= 1) v += __shfl_down(v, off);
    if (lane == 0) wsum[wave][e] = v;
  }
  __syncthreads();
  if (tid == 0) {
    float lg[NE];
#pragma unroll
    for (int e = 0; e < NE; e++) lg[e] = wsum[0][e] + wsum[1][e] + wsum[2][e] + wsum[3][e];
    int i0 = 0; float v0 = lg[0];
#pragma unroll
    for (int e = 1; e < NE; e++) if (lg[e] > v0) { v0 = lg[e]; i0 = e; }
    int i1 = -1; float v1 = -3.4e38f;
#pragma unroll
    for (int e = 0; e < NE; e++) if (e != i0 && lg[e] > v1) { v1 = lg[e]; i1 = e; }
    float e1 = expf(v1 - v0);
    float s = 1.f + e1;
    tidx[t * 2 + 0] = i0; tidx[t * 2 + 1] = i1;
    twt[t * 2 + 0] = 1.f / s; twt[t * 2 + 1] = e1 / s;
    atomicAdd(&counts[i0], 1);
    atomicAdd(&counts[i1], 1);
  }
}

__global__ void k_scan(const int* __restrict__ counts, int* __restrict__ offsets) {
  if (threadIdx.x == 0) {
    int s = 0;
    for (int e = 0; e < NE; e++) { offsets[e] = s; s += counts[e]; }
    offsets[NE] = s;
  }
}

__global__ void k_fill(const int* __restrict__ tidx, const float* __restrict__ twt,
                       const int* __restrict__ offsets, int* __restrict__ cursors,
                       int* __restrict__ ltok, float* __restrict__ lwt, int* __restrict__ ppos) {
  int t = blockIdx.x * blockDim.x + threadIdx.x;
  if (t >= T_TOK) return;
#pragma unroll
  for (int k = 0; k < TOPK; k++) {
    int e = tidx[t * 2 + k];
    int pos = atomicAdd(&cursors[e], 1);
    int p = offsets[e] + pos;
    ltok[p] = t;
    lwt[p] = twt[t * 2 + k];
    ppos[t * 2 + k] = p;
  }
}

// ==== GEMMs: 128x128xBK32, 3-deep LDS pipeline, counted vmcnt, asm ds_read ====
#define BM 128
#define BN 128
#define BK 32
#define BUFB (BM * BK * 2)   // bytes per buffer slot

__device__ __forceinline__ void xcd_decode(int lin, int nwg, int nx, int& xt, int& yt) {
  int q = nwg >> 3;
  int w = (lin & 7) * q + (lin >> 3);
  xt = w % nx;
  yt = w / nx;
}

// Per iter: STAGE(t+2 into slot (t+2)%3) -> vmcnt(8) (oldest tile landed; 2 newer
// tiles stay in flight, aged 2 compute phases) -> barrier -> asm ds_read(cur) ->
// lgkmcnt(0) -> MFMA -> barrier. No vmcnt(0) until the last iteration.
template <int NT>
__device__ __forceinline__ void gemm_loop(const ushort_t* __restrict__ a0,
                                          const ushort_t* __restrict__ a1,
                                          const ushort_t* __restrict__ b0,
                                          const ushort_t* __restrict__ b1,
                                          ushort_t* AsLds, ushort_t* BsLds,
                                          f32x4 (&acc)[4][4]) {
  int tid = threadIdx.x;
  int wave = tid >> 6, lane = tid & 63;
  int wm = wave >> 1, wn = wave & 1;
  int lm = lane & 15, lg = lane >> 4;

  unsigned abase = lds_off(AsLds), bbase = lds_off(BsLds);
  unsigned aoff[4], boff[4];
#pragma unroll
  for (int m = 0; m < 4; m++)
    aoff[m] = abase + ((wm * 64 + m * 16 + lm) * BK + lg * 8) * 2;
#pragma unroll
  for (int n = 0; n < 4; n++)
    boff[n] = bbase + ((wn * 64 + n * 16 + lm) * BK + lg * 8) * 2;

  const ushort_t* ap[2] = {a0, a1};
  const ushort_t* bp[2] = {b0, b1};

  auto STAGE = [&](int buf, int k0) {
#pragma unroll
    for (int j = 0; j < 2; j++) {
      gload16(ap[j] + k0, AsLds + buf * (BM * BK) + (j * 256 + wave * 64) * 8);
      gload16(bp[j] + k0, BsLds + buf * (BM * BK) + (j * 256 + wave * 64) * 8);
    }
  };

  STAGE(0, 0);
  STAGE(1, BK);
  int cur = 0;
  for (int t = 0; t < NT; ++t) {
    int s2 = cur + 2; if (s2 >= 3) s2 -= 3;
    if (t + 2 < NT) {
      STAGE(s2, (t + 2) * BK);
      __builtin_amdgcn_sched_barrier(0);
      asm volatile("s_waitcnt vmcnt(8)" ::: "memory");   // tile t's 4 loads landed
    } else if (t + 1 < NT) {
      __builtin_amdgcn_sched_barrier(0);
      asm volatile("s_waitcnt vmcnt(4)" ::: "memory");
    } else {
      __builtin_amdgcn_sched_barrier(0);
      asm volatile("s_waitcnt vmcnt(0)" ::: "memory");
    }
    __builtin_amdgcn_s_barrier();
    __builtin_amdgcn_sched_barrier(0);
    unsigned cb = (unsigned)(cur * BUFB);
    bf16x8 af[4], bv[4];
#pragma unroll
    for (int m = 0; m < 4; m++) af[m] = ds_read128(aoff[m] + cb);
#pragma unroll
    for (int n = 0; n < 4; n++) bv[n] = ds_read128(boff[n] + cb);
    asm volatile("s_waitcnt lgkmcnt(0)" ::: "memory");
    __builtin_amdgcn_sched_barrier(0);
#pragma unroll
    for (int m = 0; m < 4; m++)
#pragma unroll
      for (int n = 0; n < 4; n++)
        acc[m][n] = __builtin_amdgcn_mfma_f32_16x16x32_bf16(af[m], bv[n], acc[m][n], 0, 0, 0);
    __builtin_amdgcn_sched_barrier(0);
    __builtin_amdgcn_s_barrier();     // cur fully read before it is restaged next iter
    __builtin_amdgcn_sched_barrier(0);
    cur += 1; if (cur == 3) cur = 0;
  }
}

// GEMM1: H[p,f] = gelu( gather(x)[p,:] @ w1t[e]^T + b1[e] )   w1t: [F][D] bf16
__global__ __launch_bounds__(256) void k_gemm1(
    const ushort_t* __restrict__ xbf, const ushort_t* __restrict__ w1t, const float* __restrict__ b1,
    const int* __restrict__ counts, const int* __restrict__ offsets,
    const int* __restrict__ ltok, ushort_t* __restrict__ H) {
  int e = blockIdx.z;
  int cnt = counts[e];
  int xt, yt;
  xcd_decode(blockIdx.x, (T_TOK / BM) * (FFN / BN), T_TOK / BM, xt, yt);
  int row0 = xt * BM;
  if (row0 >= cnt) return;
  int base = offsets[e];
  int col0 = yt * BN;
  const ushort_t* Bt = w1t + (size_t)e * DIM * FFN;

  __shared__ __align__(16) ushort_t As[3 * BM * BK];
  __shared__ __align__(16) ushort_t Bs[3 * BM * BK];

  int tid = threadIdx.x;
  int srow = tid >> 2, seg = tid & 3;
  const ushort_t* asrc[2]; const ushort_t* bsrc[2];
#pragma unroll
  for (int j = 0; j < 2; j++) {
    int ar = min(row0 + j * 64 + srow, cnt - 1);
    asrc[j] = xbf + (size_t)ltok[base + ar] * DIM + seg * 8;
    bsrc[j] = Bt + (size_t)(col0 + j * 64 + srow) * DIM + seg * 8;
  }
  f32x4 acc[4][4];
#pragma unroll
  for (int m = 0; m < 4; m++)
#pragma unroll
    for (int n = 0; n < 4; n++) acc[m][n] = (f32x4){0.f, 0.f, 0.f, 0.f};

  gemm_loop<DIM / BK>(asrc[0], asrc[1], bsrc[0], bsrc[1], As, Bs, acc);

  int wave = tid >> 6, lane = tid & 63;
  int wm = wave >> 1, wn = wave & 1;
  int lm = lane & 15, lg = lane >> 4;
#pragma unroll
  for (int m = 0; m < 4; m++) {
#pragma unroll
    for (int n = 0; n < 4; n++) {
      int f = col0 + wn * 64 + n * 16 + lm;
      float bias = b1[e * FFN + f];
#pragma unroll
      for (int r = 0; r < 4; r++) {
        int row = row0 + wm * 64 + m * 16 + lg * 4 + r;
        if (row < cnt) {
          float v = acc[m][n][r] + bias;
          H[(size_t)(base + row) * FFN + f] = f2bf(gelu_exact(v));
        }
      }
    }
  }
}

// GEMM2: contrib[p,d] = cw[p] * ( H[p,:] @ w2t[e]^T + b2[e] )   w2t: [D][F] bf16
__global__ __launch_bounds__(256) void k_gemm2(
    const ushort_t* __restrict__ H, const ushort_t* __restrict__ w2t, const float* __restrict__ b2,
    const int* __restrict__ counts, const int* __restrict__ offsets,
    const float* __restrict__ lwt, ushort_t* __restrict__ contrib) {
  int e = blockIdx.z;
  int cnt = counts[e];
  int xt, yt;
  xcd_decode(blockIdx.x, (T_TOK / BM) * (DIM / BN), T_TOK / BM, xt, yt);
  int row0 = xt * BM;
  if (row0 >= cnt) return;
  int base = offsets[e];
  int col0 = yt * BN;
  const ushort_t* Bt = w2t + (size_t)e * DIM * FFN;

  __shared__ __align__(16) ushort_t As[3 * BM * BK];
  __shared__ __align__(16) ushort_t Bs[3 * BM * BK];

  int tid = threadIdx.x;
  int srow = tid >> 2, seg = tid & 3;
  const ushort_t* asrc[2]; const ushort_t* bsrc[2];
#pragma unroll
  for (int j = 0; j < 2; j++) {
    int ar = min(row0 + j * 64 + srow, cnt - 1);
    asrc[j] = H + (size_t)(base + ar) * FFN + seg * 8;
    bsrc[j] = Bt + (size_t)(col0 + j * 64 + srow) * FFN + seg * 8;
  }
  f32x4 acc[4][4];
#pragma unroll
  for (int m = 0; m < 4; m++)
#pragma unroll
    for (int n = 0; n < 4; n++) acc[m][n] = (f32x4){0.f, 0.f, 0.f, 0.f};

  gemm_loop<FFN / BK>(asrc[0], asrc[1], bsrc[0], bsrc[1], As, Bs, acc);

  int wave = tid >> 6, lane = tid & 63;
  int wm = wave >> 1, wn = wave & 1;
  int lm = lane & 15, lg = lane >> 4;
#pragma unroll
  for (int m = 0; m < 4; m++) {
#pragma unroll
    for (int n = 0; n < 4; n++) {
      int d = col0 + wn * 64 + n * 16 + lm;
      float bias = b2[e * DIM + d];
#pragma unroll
      for (int r = 0; r < 4; r++) {
        int row = row0 + wm * 64 + m * 16 + lg * 4 + r;
        if (row < cnt) {
          float v = (acc[m][n][r] + bias) * lwt[base + row];
          contrib[(size_t)(base + row) * DIM + d] = f2bf(v);
        }
      }
    }
  }
}

// ---------------- combine: out = x + contrib[p0] + contrib[p1] ----------------
__global__ void k_combine(const float* __restrict__ x, const ushort_t* __restrict__ contrib,
                          const int* __restrict__ ppos, float* __restrict__ out) {
  int i = blockIdx.x * blockDim.x + threadIdx.x;
  int t = i / (DIM / 4);
  int dq = i % (DIM / 4);
  int p0 = ppos[t * 2 + 0], p1 = ppos[t * 2 + 1];
  float4 xv = reinterpret_cast<const float4*>(x)[i];
  ushort4v c0 = reinterpret_cast<const ushort4v*>(contrib + (size_t)p0 * DIM)[dq];
  ushort4v c1 = reinterpret_cast<const ushort4v*>(contrib + (size_t)p1 * DIM)[dq];
  float4 o;
  o.x = xv.x + bf2f(c0.x) + bf2f(c1.x);
  o.y = xv.y + bf2f(c0.y) + bf2f(c1.y);
  o.z = xv.z + bf2f(c0.z) + bf2f(c1.z);
  o.w = xv.w + bf2f(c0.w) + bf2f(c1.w);
  reinterpret_cast<float4*>(out)[i] = o;
}

extern "C" void kernel_launch(void* const* d_in, const int* in_sizes, int n_in,
                              void* d_out, int out_size, void* d_ws, size_t ws_size,
                              hipStream_t stream) {
  const float* x  = (const float*)d_in[0];
  const float* rw = (const float*)d_in[1];
  const float* w1 = (const float*)d_in[2];
  const float* b1 = (const float*)d_in[3];
  const float* w2 = (const float*)d_in[4];
  const float* b2 = (const float*)d_in[5];
  float* out = (float*)d_out;
  char* ws = (char*)d_ws;

  const size_t MB = 1u << 20;
  int*   counts  = (int*)(ws);
  int*   offsets = (int*)(ws + 64);
  int*   cursors = (int*)(ws + 128);
  int*   tidx    = (int*)(ws + 1 * MB);
  float* twt     = (float*)(ws + 2 * MB);
  int*   ltok    = (int*)(ws + 3 * MB);
  float* lwt     = (float*)(ws + 4 * MB);
  int*   ppos    = (int*)(ws + 5 * MB);
  // overlaid big buffers (lifetimes disjoint where they overlap):
  ushort_t* xbf     = (ushort_t*)(ws + 8 * MB);     // 32 MB, live cast..gemm1
  ushort_t* contrib = (ushort_t*)(ws + 8 * MB);     // 64 MB, live gemm2..combine (xbf dead)
  ushort_t* Hbuf    = (ushort_t*)(ws + 72 * MB);    // 256 MB, live gemm1..gemm2
  ushort_t* w1t     = (ushort_t*)(ws + 328 * MB);   // 256 MB, live wcvt1..gemm1
  ushort_t* w2t     = (ushort_t*)(ws + 328 * MB);   // 256 MB, live wcvt2..gemm2 (after gemm1)
  const size_t NEED = 584 * MB;
  if (ws_size < NEED) {
    hipMemsetAsync(d_out, 0, (size_t)out_size * sizeof(float), stream);
    return;
  }

  hipMemsetAsync(ws, 0, 256, stream);  // counts + cursors
  k_cast<<<dim3((T_TOK * (size_t)DIM / 4) / 256), 256, 0, stream>>>(x, xbf);
  k_router<<<T_TOK, 256, 0, stream>>>(x, rw, tidx, twt, counts);
  k_scan<<<1, 64, 0, stream>>>(counts, offsets);
  k_fill<<<T_TOK / 256, 256, 0, stream>>>(tidx, twt, offsets, cursors, ltok, lwt, ppos);
  // w1: [E][D][F] fp32 -> w1t [E][F][D] bf16
  k_wcvt<<<dim3(FFN / TT, DIM / TT, NE), 256, 0, stream>>>(w1, w1t, DIM, FFN);
  k_gemm1<<<dim3((T_TOK / BM) * (FFN / BN), 1, NE), 256, 0, stream>>>(xbf, w1t, b1, counts, offsets, ltok, Hbuf);
  // w2: [E][F][D] fp32 -> w2t [E][D][F] bf16  (after gemm1; reuses w1t region)
  k_wcvt<<<dim3(DIM / TT, FFN / TT, NE), 256, 0, stream>>>(w2, w2t, FFN, DIM);
  k_gemm2<<<dim3((T_TOK / BM) * (DIM / BN), 1, NE), 256, 0, stream>>>(Hbuf, w2t, b2, counts, offsets, lwt, contrib);
  k_combine<<<dim3((T_TOK * (size_t)DIM / 4) / 256), 256, 0, stream>>>(x, contrib, ppos, out);
}

// Round 11
// 2338.391 us; speedup vs baseline: 1.5881x; 1.0006x over previous
//
#include <hip/hip_runtime.h>

// MoE block: B=4,S=2048 -> T=8192 tokens, D=2048, F=8192, E=8, K=2
#define T_TOK 8192
#define DIM   2048
#define FFN   8192
#define NE    8
#define TOPK  2

typedef unsigned short ushort_t;
typedef unsigned short ushort8  __attribute__((ext_vector_type(8)));
typedef unsigned short ushort4v __attribute__((ext_vector_type(4)));
typedef short bf16x8 __attribute__((ext_vector_type(8)));
typedef float f32x4  __attribute__((ext_vector_type(4)));

__device__ __forceinline__ ushort_t f2bf(float f) {
  unsigned int u = __float_as_uint(f);
  u += 0x7FFFu + ((u >> 16) & 1u);   // RNE
  return (ushort_t)(u >> 16);
}
__device__ __forceinline__ float bf2f(ushort_t u) {
  return __uint_as_float(((unsigned int)u) << 16);
}

// async global->LDS, 16B per lane. LDS dest wave-uniform base; HW adds lane*16.
__device__ __forceinline__ void gload16(const void* g, void* l) {
  __builtin_amdgcn_global_load_lds((const __attribute__((address_space(1))) void*)g,
                                   (__attribute__((address_space(3))) void*)l, 16, 0, 0);
}
// LDS byte offset of a shared-memory pointer (for inline-asm ds_read)
__device__ __forceinline__ unsigned lds_off(const ushort_t* p) {
  return (unsigned)(uintptr_t)(__attribute__((address_space(3))) const ushort_t*)p;
}
// invisible LDS read: compiler can't see this touches LDS -> no auto vmcnt drain
__device__ __forceinline__ bf16x8 ds_read128(unsigned off) {
  bf16x8 r;
  asm volatile("ds_read_b128 %0, %1" : "=v"(r) : "v"(off));
  return r;
}

// exact-erf GELU via Abramowitz-Stegun 7.1.26 (|err| <= 1.5e-7)
__device__ __forceinline__ float gelu_exact(float v) {
  float s = v * 0.70710678118654752f;
  float a = fabsf(s);
  float t = __builtin_amdgcn_rcpf(1.0f + 0.3275911f * a);
  float p = t * (0.254829592f +
            t * (-0.284496736f +
            t * (1.421413741f +
            t * (-1.453152027f +
            t * 1.061405429f))));
  float er = 1.0f - p * __expf(-a * a);
  er = copysignf(er, s);
  return 0.5f * v * (1.0f + er);
}

// ---------------- cast x -> bf16 ----------------
__global__ void k_cast(const float* __restrict__ x, ushort_t* __restrict__ xbf) {
  int i = blockIdx.x * blockDim.x + threadIdx.x;
  float4 v = reinterpret_cast<const float4*>(x)[i];
  ushort4v o;
  o.x = f2bf(v.x); o.y = f2bf(v.y); o.z = f2bf(v.z); o.w = f2bf(v.w);
  reinterpret_cast<ushort4v*>(xbf)[i] = o;
}

// ---------------- weight convert+transpose: fp32 [R][C] -> bf16 [C][R] ----------------
#define TT 64
__global__ __launch_bounds__(256) void k_wcvt(const float* __restrict__ in,
                                              ushort_t* __restrict__ outp, int R, int C) {
  __shared__ ushort_t t[TT][TT + 8];
  int e = blockIdx.z;
  const float* src = in + (size_t)e * R * C;
  ushort_t* dst = outp + (size_t)e * R * C;
  int r0 = blockIdx.y * TT, c0 = blockIdx.x * TT;
  int tid = threadIdx.x;
  int rr = tid >> 4;
  int c4 = tid & 15;
#pragma unroll
  for (int i = 0; i < 4; i++) {
    int r = rr + i * 16;
    float4 v = *reinterpret_cast<const float4*>(src + (size_t)(r0 + r) * C + c0 + c4 * 4);
    ushort4v p;
    p.x = f2bf(v.x); p.y = f2bf(v.y); p.z = f2bf(v.z); p.w = f2bf(v.w);
    *reinterpret_cast<ushort4v*>(&t[r][c4 * 4]) = p;
  }
  __syncthreads();
  int c = tid >> 2, rs = tid & 3;
  ushort_t tmp[16];
#pragma unroll
  for (int i = 0; i < 16; i++) tmp[i] = t[rs * 16 + i][c];
  ushort8 v0, v1;
#pragma unroll
  for (int i = 0; i < 8; i++) { v0[i] = tmp[i]; v1[i] = tmp[8 + i]; }
  ushort_t* drow = dst + (size_t)(c0 + c) * R + r0 + rs * 16;
  *reinterpret_cast<ushort8*>(drow) = v0;
  *reinterpret_cast<ushort8*>(drow + 8) = v1;
}

// ---------------- router ----------------
__global__ __launch_bounds__(256) void k_router(
    const float* __restrict__ x, const float* __restrict__ rw,
    int* __restrict__ tidx, float* __restrict__ twt, int* __restrict__ counts) {
  int t = blockIdx.x;
  int tid = threadIdx.x;
  int lane = tid & 63, wave = tid >> 6;
  float acc[NE];
#pragma unroll
  for (int e = 0; e < NE; e++) acc[e] = 0.f;
  const float* xr = x + (size_t)t * DIM;
  for (int d = tid; d < DIM; d += 256) {
    float xv = xr[d];
    const float* r = rw + d * NE;
#pragma unroll
    for (int e = 0; e < NE; e++) acc[e] += xv * r[e];
  }
  __shared__ float wsum[4][NE];
#pragma unroll
  for (int e = 0; e < NE; e++) {
    float v = acc[e];
#pragma unroll
    for (int off = 32; off > 0; off >>= 1) v += __shfl_down(v, off);
    if (lane == 0) wsum[wave][e] = v;
  }
  __syncthreads();
  if (tid == 0) {
    float lg[NE];
#pragma unroll
    for (int e = 0; e < NE; e++) lg[e] = wsum[0][e] + wsum[1][e] + wsum[2][e] + wsum[3][e];
    int i0 = 0; float v0 = lg[0];
#pragma unroll
    for (int e = 1; e < NE; e++) if (lg[e] > v0) { v0 = lg[e]; i0 = e; }
    int i1 = -1; float v1 = -3.4e38f;
#pragma unroll
    for (int e = 0; e < NE; e++) if (e != i0 && lg[e] > v1) { v1 = lg[e]; i1 = e; }
    float e1 = expf(v1 - v0);
    float s = 1.f + e1;
    tidx[t * 2 + 0] = i0; tidx[t * 2 + 1] = i1;
    twt[t * 2 + 0] = 1.f / s; twt[t * 2 + 1] = e1 / s;
    atomicAdd(&counts[i0], 1);
    atomicAdd(&counts[i1], 1);
  }
}

__global__ void k_scan(const int* __restrict__ counts, int* __restrict__ offsets) {
  if (threadIdx.x == 0) {
    int s = 0;
    for (int e = 0; e < NE; e++) { offsets[e] = s; s += counts[e]; }
    offsets[NE] = s;
  }
}

__global__ void k_fill(const int* __restrict__ tidx, const float* __restrict__ twt,
                       const int* __restrict__ offsets, int* __restrict__ cursors,
                       int* __restrict__ ltok, float* __restrict__ lwt, int* __restrict__ ppos) {
  int t = blockIdx.x * blockDim.x + threadIdx.x;
  if (t >= T_TOK) return;
#pragma unroll
  for (int k = 0; k < TOPK; k++) {
    int e = tidx[t * 2 + k];
    int pos = atomicAdd(&cursors[e], 1);
    int p = offsets[e] + pos;
    ltok[p] = t;
    lwt[p] = twt[t * 2 + k];
    ppos[t * 2 + k] = p;
  }
}

// ==== GEMMs: 256x256xBK32, 8 waves, 3-deep LDS pipeline, counted vmcnt, asm ds_read ====
#define BM 256
#define BN 256
#define BK 32
#define SLOT (BM * BK)          // elems per operand slot
#define SLOTB (SLOT * 2)        // bytes per slot

__device__ __forceinline__ void xcd_decode(int lin, int nwg, int nx, int& xt, int& yt) {
  int q = nwg >> 3;
  int w = (lin & 7) * q + (lin >> 3);
  xt = w % nx;
  yt = w / nx;
}

// Per iter: STAGE(t+2, slot (t+2)%3) -> vmcnt(8) (tile t's 4 loads landed; newer 8
// in flight, aged 2 compute phases > HBM latency) -> barrier -> 12 asm ds_read ->
// lgkmcnt(0) -> 32 MFMA -> barrier. vmcnt(0) only on the final iteration.
template <int NT>
__device__ __forceinline__ void gemm_loop(const ushort_t* __restrict__ a0,
                                          const ushort_t* __restrict__ a1,
                                          const ushort_t* __restrict__ b0,
                                          const ushort_t* __restrict__ b1,
                                          ushort_t* AsLds, ushort_t* BsLds,
                                          f32x4 (&acc)[8][4]) {
  int tid = threadIdx.x;
  int wid = tid >> 6, lane = tid & 63;
  int wm = wid >> 2, wn = wid & 3;        // 2x4 waves; wave tile 128x64
  int lm = lane & 15, lg = lane >> 4;

  unsigned abase = lds_off(AsLds), bbase = lds_off(BsLds);
  unsigned aoff[8], boff[4];
#pragma unroll
  for (int m = 0; m < 8; m++)
    aoff[m] = abase + (unsigned)(((wm * 128 + m * 16 + lm) * BK + lg * 8) * 2);
#pragma unroll
  for (int n = 0; n < 4; n++)
    boff[n] = bbase + (unsigned)(((wn * 64 + n * 16 + lm) * BK + lg * 8) * 2);

  const ushort_t* ap[2] = {a0, a1};
  const ushort_t* bp[2] = {b0, b1};

  auto STAGE = [&](int buf, int k0) {
#pragma unroll
    for (int j = 0; j < 2; j++) {
      gload16(ap[j] + k0, AsLds + buf * SLOT + (j * 512 + wid * 64) * 8);
      gload16(bp[j] + k0, BsLds + buf * SLOT + (j * 512 + wid * 64) * 8);
    }
  };

  STAGE(0, 0);
  STAGE(1, BK);
  int cur = 0;
  for (int t = 0; t < NT; ++t) {
    int s2 = cur + 2; if (s2 >= 3) s2 -= 3;
    if (t + 2 < NT) {
      STAGE(s2, (t + 2) * BK);
      __builtin_amdgcn_sched_barrier(0);
      asm volatile("s_waitcnt vmcnt(8)" ::: "memory");
    } else if (t + 1 < NT) {
      __builtin_amdgcn_sched_barrier(0);
      asm volatile("s_waitcnt vmcnt(4)" ::: "memory");
    } else {
      __builtin_amdgcn_sched_barrier(0);
      asm volatile("s_waitcnt vmcnt(0)" ::: "memory");
    }
    __builtin_amdgcn_s_barrier();
    __builtin_amdgcn_sched_barrier(0);
    unsigned cb = (unsigned)(cur * SLOTB);
    bf16x8 af[8], bv[4];
#pragma unroll
    for (int m = 0; m < 8; m++) af[m] = ds_read128(aoff[m] + cb);
#pragma unroll
    for (int n = 0; n < 4; n++) bv[n] = ds_read128(boff[n] + cb);
    asm volatile("s_waitcnt lgkmcnt(0)" ::: "memory");
    __builtin_amdgcn_sched_barrier(0);
    __builtin_amdgcn_s_setprio(1);
#pragma unroll
    for (int m = 0; m < 8; m++)
#pragma unroll
      for (int n = 0; n < 4; n++)
        acc[m][n] = __builtin_amdgcn_mfma_f32_16x16x32_bf16(af[m], bv[n], acc[m][n], 0, 0, 0);
    __builtin_amdgcn_s_setprio(0);
    __builtin_amdgcn_sched_barrier(0);
    __builtin_amdgcn_s_barrier();     // cur fully read before restaged
    __builtin_amdgcn_sched_barrier(0);
    cur += 1; if (cur == 3) cur = 0;
  }
}

// GEMM1: H[p,f] = gelu( gather(x)[p,:] @ w1t[e]^T + b1[e] )   w1t: [F][D] bf16
__global__ __launch_bounds__(512) void k_gemm1(
    const ushort_t* __restrict__ xbf, const ushort_t* __restrict__ w1t, const float* __restrict__ b1,
    const int* __restrict__ counts, const int* __restrict__ offsets,
    const int* __restrict__ ltok, ushort_t* __restrict__ H) {
  int e = blockIdx.z;
  int cnt = counts[e];
  int xt, yt;
  xcd_decode(blockIdx.x, (T_TOK / BM) * (FFN / BN), T_TOK / BM, xt, yt);
  int row0 = xt * BM;
  if (row0 >= cnt) return;
  int base = offsets[e];
  int col0 = yt * BN;
  const ushort_t* Bt = w1t + (size_t)e * DIM * FFN;

  __shared__ __align__(16) ushort_t As[3 * SLOT];
  __shared__ __align__(16) ushort_t Bs[3 * SLOT];

  int tid = threadIdx.x;
  int rsub = tid >> 2, seg = tid & 3;
  const ushort_t* asrc[2]; const ushort_t* bsrc[2];
#pragma unroll
  for (int j = 0; j < 2; j++) {
    int row = j * 128 + rsub;
    int ar = min(row0 + row, cnt - 1);
    asrc[j] = xbf + (size_t)ltok[base + ar] * DIM + seg * 8;
    bsrc[j] = Bt + (size_t)(col0 + row) * DIM + seg * 8;
  }
  f32x4 acc[8][4];
#pragma unroll
  for (int m = 0; m < 8; m++)
#pragma unroll
    for (int n = 0; n < 4; n++) acc[m][n] = (f32x4){0.f, 0.f, 0.f, 0.f};

  gemm_loop<DIM / BK>(asrc[0], asrc[1], bsrc[0], bsrc[1], As, Bs, acc);

  int wid = tid >> 6, lane = tid & 63;
  int wm = wid >> 2, wn = wid & 3;
  int lm = lane & 15, lg = lane >> 4;
#pragma unroll
  for (int m = 0; m < 8; m++) {
#pragma unroll
    for (int n = 0; n < 4; n++) {
      int f = col0 + wn * 64 + n * 16 + lm;
      float bias = b1[e * FFN + f];
#pragma unroll
      for (int r = 0; r < 4; r++) {
        int row = row0 + wm * 128 + m * 16 + lg * 4 + r;
        if (row < cnt) {
          float v = acc[m][n][r] + bias;
          H[(size_t)(base + row) * FFN + f] = f2bf(gelu_exact(v));
        }
      }
    }
  }
}

// GEMM2: contrib[p,d] = cw[p] * ( H[p,:] @ w2t[e]^T + b2[e] )   w2t: [D][F] bf16
__global__ __launch_bounds__(512) void k_gemm2(
    const ushort_t* __restrict__ H, const ushort_t* __restrict__ w2t, const float* __restrict__ b2,
    const int* __restrict__ counts, const int* __restrict__ offsets,
    const float* __restrict__ lwt, ushort_t* __restrict__ contrib) {
  int e = blockIdx.z;
  int cnt = counts[e];
  int xt, yt;
  xcd_decode(blockIdx.x, (T_TOK / BM) * (DIM / BN), T_TOK / BM, xt, yt);
  int row0 = xt * BM;
  if (row0 >= cnt) return;
  int base = offsets[e];
  int col0 = yt * BN;
  const ushort_t* Bt = w2t + (size_t)e * DIM * FFN;

  __shared__ __align__(16) ushort_t As[3 * SLOT];
  __shared__ __align__(16) ushort_t Bs[3 * SLOT];

  int tid = threadIdx.x;
  int rsub = tid >> 2, seg = tid & 3;
  const ushort_t* asrc[2]; const ushort_t* bsrc[2];
#pragma unroll
  for (int j = 0; j < 2; j++) {
    int row = j * 128 + rsub;
    int ar = min(row0 + row, cnt - 1);
    asrc[j] = H + (size_t)(base + ar) * FFN + seg * 8;
    bsrc[j] = Bt + (size_t)(col0 + row) * FFN + seg * 8;
  }
  f32x4 acc[8][4];
#pragma unroll
  for (int m = 0; m < 8; m++)
#pragma unroll
    for (int n = 0; n < 4; n++) acc[m][n] = (f32x4){0.f, 0.f, 0.f, 0.f};

  gemm_loop<FFN / BK>(asrc[0], asrc[1], bsrc[0], bsrc[1], As, Bs, acc);

  int wid = tid >> 6, lane = tid & 63;
  int wm = wid >> 2, wn = wid & 3;
  int lm = lane & 15, lg = lane >> 4;
#pragma unroll
  for (int m = 0; m < 8; m++) {
#pragma unroll
    for (int n = 0; n < 4; n++) {
      int d = col0 + wn * 64 + n * 16 + lm;
      float bias = b2[e * DIM + d];
#pragma unroll
      for (int r = 0; r < 4; r++) {
        int row = row0 + wm * 128 + m * 16 + lg * 4 + r;
        if (row < cnt) {
          float v = (acc[m][n][r] + bias) * lwt[base + row];
          contrib[(size_t)(base + row) * DIM + d] = f2bf(v);
        }
      }
    }
  }
}

// ---------------- combine: out = x + contrib[p0] + contrib[p1] ----------------
__global__ void k_combine(const float* __restrict__ x, const ushort_t* __restrict__ contrib,
                          const int* __restrict__ ppos, float* __restrict__ out) {
  int i = blockIdx.x * blockDim.x + threadIdx.x;
  int t = i / (DIM / 4);
  int dq = i % (DIM / 4);
  int p0 = ppos[t * 2 + 0], p1 = ppos[t * 2 + 1];
  float4 xv = reinterpret_cast<const float4*>(x)[i];
  ushort4v c0 = reinterpret_cast<const ushort4v*>(contrib + (size_t)p0 * DIM)[dq];
  ushort4v c1 = reinterpret_cast<const ushort4v*>(contrib + (size_t)p1 * DIM)[dq];
  float4 o;
  o.x = xv.x + bf2f(c0.x) + bf2f(c1.x);
  o.y = xv.y + bf2f(c0.y) + bf2f(c1.y);
  o.z = xv.z + bf2f(c0.z) + bf2f(c1.z);
  o.w = xv.w + bf2f(c0.w) + bf2f(c1.w);
  reinterpret_cast<float4*>(out)[i] = o;
}

extern "C" void kernel_launch(void* const* d_in, const int* in_sizes, int n_in,
                              void* d_out, int out_size, void* d_ws, size_t ws_size,
                              hipStream_t stream) {
  const float* x  = (const float*)d_in[0];
  const float* rw = (const float*)d_in[1];
  const float* w1 = (const float*)d_in[2];
  const float* b1 = (const float*)d_in[3];
  const float* w2 = (const float*)d_in[4];
  const float* b2 = (const float*)d_in[5];
  float* out = (float*)d_out;
  char* ws = (char*)d_ws;

  const size_t MB = 1u << 20;
  int*   counts  = (int*)(ws);
  int*   offsets = (int*)(ws + 64);
  int*   cursors = (int*)(ws + 128);
  int*   tidx    = (int*)(ws + 1 * MB);
  float* twt     = (float*)(ws + 2 * MB);
  int*   ltok    = (int*)(ws + 3 * MB);
  float* lwt     = (float*)(ws + 4 * MB);
  int*   ppos    = (int*)(ws + 5 * MB);
  // overlaid big buffers (lifetimes disjoint where they overlap):
  ushort_t* xbf     = (ushort_t*)(ws + 8 * MB);     // 32 MB, live cast..gemm1
  ushort_t* contrib = (ushort_t*)(ws + 8 * MB);     // 64 MB, live gemm2..combine (xbf dead)
  ushort_t* Hbuf    = (ushort_t*)(ws + 72 * MB);    // 256 MB, live gemm1..gemm2
  ushort_t* w1t     = (ushort_t*)(ws + 328 * MB);   // 256 MB, live wcvt1..gemm1
  ushort_t* w2t     = (ushort_t*)(ws + 328 * MB);   // 256 MB, live wcvt2..gemm2 (after gemm1)
  const size_t NEED = 584 * MB;
  if (ws_size < NEED) {
    hipMemsetAsync(d_out, 0, (size_t)out_size * sizeof(float), stream);
    return;
  }

  hipMemsetAsync(ws, 0, 256, stream);  // counts + cursors
  k_cast<<<dim3((T_TOK * (size_t)DIM / 4) / 256), 256, 0, stream>>>(x, xbf);
  k_router<<<T_TOK, 256, 0, stream>>>(x, rw, tidx, twt, counts);
  k_scan<<<1, 64, 0, stream>>>(counts, offsets);
  k_fill<<<T_TOK / 256, 256, 0, stream>>>(tidx, twt, offsets, cursors, ltok, lwt, ppos);
  // w1: [E][D][F] fp32 -> w1t [E][F][D] bf16
  k_wcvt<<<dim3(FFN / TT, DIM / TT, NE), 256, 0, stream>>>(w1, w1t, DIM, FFN);
  k_gemm1<<<dim3((T_TOK / BM) * (FFN / BN), 1, NE), 512, 0, stream>>>(xbf, w1t, b1, counts, offsets, ltok, Hbuf);
  // w2: [E][F][D] fp32 -> w2t [E][D][F] bf16  (after gemm1; reuses w1t region)
  k_wcvt<<<dim3(DIM / TT, FFN / TT, NE), 256, 0, stream>>>(w2, w2t, FFN, DIM);
  k_gemm2<<<dim3((T_TOK / BM) * (DIM / BN), 1, NE), 512, 0, stream>>>(Hbuf, w2t, b2, counts, offsets, lwt, contrib);
  k_combine<<<dim3((T_TOK * (size_t)DIM / 4) / 256), 256, 0, stream>>>(x, contrib, ppos, out);
}

// Round 12
// 2322.383 us; speedup vs baseline: 1.5990x; 1.0069x over previous
//
#include <hip/hip_runtime.h>

// MoE block: B=4,S=2048 -> T=8192 tokens, D=2048, F=8192, E=8, K=2
#define T_TOK 8192
#define DIM   2048
#define FFN   8192
#define NE    8
#define TOPK  2

typedef unsigned short ushort_t;
typedef unsigned short ushort8  __attribute__((ext_vector_type(8)));
typedef unsigned short ushort4v __attribute__((ext_vector_type(4)));
typedef short bf16x8 __attribute__((ext_vector_type(8)));
typedef float f32x4  __attribute__((ext_vector_type(4)));

__device__ __forceinline__ ushort_t f2bf(float f) {
  unsigned int u = __float_as_uint(f);
  u += 0x7FFFu + ((u >> 16) & 1u);   // RNE
  return (ushort_t)(u >> 16);
}
__device__ __forceinline__ float bf2f(ushort_t u) {
  return __uint_as_float(((unsigned int)u) << 16);
}

// async global->LDS, 16B per lane. LDS dest wave-uniform base; HW adds lane*16.
__device__ __forceinline__ void gload16(const void* g, void* l) {
  __builtin_amdgcn_global_load_lds((const __attribute__((address_space(1))) void*)g,
                                   (__attribute__((address_space(3))) void*)l, 16, 0, 0);
}
// LDS byte offset of a shared-memory pointer (for inline-asm ds_read)
__device__ __forceinline__ unsigned lds_off(const ushort_t* p) {
  return (unsigned)(uintptr_t)(__attribute__((address_space(3))) const ushort_t*)p;
}
// invisible LDS read: compiler can't see this touches LDS -> no auto vmcnt drain
__device__ __forceinline__ bf16x8 ds_read128(unsigned off) {
  bf16x8 r;
  asm volatile("ds_read_b128 %0, %1" : "=v"(r) : "v"(off));
  return r;
}

// exact-erf GELU via Abramowitz-Stegun 7.1.26 (|err| <= 1.5e-7)
__device__ __forceinline__ float gelu_exact(float v) {
  float s = v * 0.70710678118654752f;
  float a = fabsf(s);
  float t = __builtin_amdgcn_rcpf(1.0f + 0.3275911f * a);
  float p = t * (0.254829592f +
            t * (-0.284496736f +
            t * (1.421413741f +
            t * (-1.453152027f +
            t * 1.061405429f))));
  float er = 1.0f - p * __expf(-a * a);
  er = copysignf(er, s);
  return 0.5f * v * (1.0f + er);
}

// ---------------- cast x -> bf16 ----------------
__global__ void k_cast(const float* __restrict__ x, ushort_t* __restrict__ xbf) {
  int i = blockIdx.x * blockDim.x + threadIdx.x;
  float4 v = reinterpret_cast<const float4*>(x)[i];
  ushort4v o;
  o.x = f2bf(v.x); o.y = f2bf(v.y); o.z = f2bf(v.z); o.w = f2bf(v.w);
  reinterpret_cast<ushort4v*>(xbf)[i] = o;
}

// ---------------- weight convert+transpose: fp32 [R][C] -> bf16 [C][R] ----------------
#define TT 64
__global__ __launch_bounds__(256) void k_wcvt(const float* __restrict__ in,
                                              ushort_t* __restrict__ outp, int R, int C) {
  __shared__ ushort_t t[TT][TT + 8];
  int e = blockIdx.z;
  const float* src = in + (size_t)e * R * C;
  ushort_t* dst = outp + (size_t)e * R * C;
  int r0 = blockIdx.y * TT, c0 = blockIdx.x * TT;
  int tid = threadIdx.x;
  int rr = tid >> 4;
  int c4 = tid & 15;
#pragma unroll
  for (int i = 0; i < 4; i++) {
    int r = rr + i * 16;
    float4 v = *reinterpret_cast<const float4*>(src + (size_t)(r0 + r) * C + c0 + c4 * 4);
    ushort4v p;
    p.x = f2bf(v.x); p.y = f2bf(v.y); p.z = f2bf(v.z); p.w = f2bf(v.w);
    *reinterpret_cast<ushort4v*>(&t[r][c4 * 4]) = p;
  }
  __syncthreads();
  int c = tid >> 2, rs = tid & 3;
  ushort_t tmp[16];
#pragma unroll
  for (int i = 0; i < 16; i++) tmp[i] = t[rs * 16 + i][c];
  ushort8 v0, v1;
#pragma unroll
  for (int i = 0; i < 8; i++) { v0[i] = tmp[i]; v1[i] = tmp[8 + i]; }
  ushort_t* drow = dst + (size_t)(c0 + c) * R + r0 + rs * 16;
  *reinterpret_cast<ushort8*>(drow) = v0;
  *reinterpret_cast<ushort8*>(drow + 8) = v1;
}

// ---------------- router ----------------
__global__ __launch_bounds__(256) void k_router(
    const float* __restrict__ x, const float* __restrict__ rw,
    int* __restrict__ tidx, float* __restrict__ twt, int* __restrict__ counts) {
  int t = blockIdx.x;
  int tid = threadIdx.x;
  int lane = tid & 63, wave = tid >> 6;
  float acc[NE];
#pragma unroll
  for (int e = 0; e < NE; e++) acc[e] = 0.f;
  const float* xr = x + (size_t)t * DIM;
  for (int d = tid; d < DIM; d += 256) {
    float xv = xr[d];
    const float* r = rw + d * NE;
#pragma unroll
    for (int e = 0; e < NE; e++) acc[e] += xv * r[e];
  }
  __shared__ float wsum[4][NE];
#pragma unroll
  for (int e = 0; e < NE; e++) {
    float v = acc[e];
#pragma unroll
    for (int off = 32; off > 0; off >>= 1) v += __shfl_down(v, off);
    if (lane == 0) wsum[wave][e] = v;
  }
  __syncthreads();
  if (tid == 0) {
    float lg[NE];
#pragma unroll
    for (int e = 0; e < NE; e++) lg[e] = wsum[0][e] + wsum[1][e] + wsum[2][e] + wsum[3][e];
    int i0 = 0; float v0 = lg[0];
#pragma unroll
    for (int e = 1; e < NE; e++) if (lg[e] > v0) { v0 = lg[e]; i0 = e; }
    int i1 = -1; float v1 = -3.4e38f;
#pragma unroll
    for (int e = 0; e < NE; e++) if (e != i0 && lg[e] > v1) { v1 = lg[e]; i1 = e; }
    float e1 = expf(v1 - v0);
    float s = 1.f + e1;
    tidx[t * 2 + 0] = i0; tidx[t * 2 + 1] = i1;
    twt[t * 2 + 0] = 1.f / s; twt[t * 2 + 1] = e1 / s;
    atomicAdd(&counts[i0], 1);
    atomicAdd(&counts[i1], 1);
  }
}

__global__ void k_scan(const int* __restrict__ counts, int* __restrict__ offsets) {
  if (threadIdx.x == 0) {
    int s = 0;
    for (int e = 0; e < NE; e++) { offsets[e] = s; s += counts[e]; }
    offsets[NE] = s;
  }
}

__global__ void k_fill(const int* __restrict__ tidx, const float* __restrict__ twt,
                       const int* __restrict__ offsets, int* __restrict__ cursors,
                       int* __restrict__ ltok, float* __restrict__ lwt, int* __restrict__ ppos) {
  int t = blockIdx.x * blockDim.x + threadIdx.x;
  if (t >= T_TOK) return;
#pragma unroll
  for (int k = 0; k < TOPK; k++) {
    int e = tidx[t * 2 + k];
    int pos = atomicAdd(&cursors[e], 1);
    int p = offsets[e] + pos;
    ltok[p] = t;
    lwt[p] = twt[t * 2 + k];
    ppos[t * 2 + k] = p;
  }
}

// ==== GEMMs: 256x256xBK32, 8 waves, 3-deep LDS, 4-phase interleave, XOR swizzle ====
#define BM 256
#define BN 256
#define BK 32
#define SLOT (BM * BK)          // elems per operand slot
#define SLOTB (SLOT * 2)        // bytes per slot

__device__ __forceinline__ void xcd_decode(int lin, int nwg, int nx, int& xt, int& yt) {
  int q = nwg >> 3;
  int w = (lin & 7) * q + (lin >> 3);
  xt = w % nx;
  yt = w / nx;
}

// Swizzle: row r's physical 16B-chunk c holds logical chunk c^(r&3)
// (stage source seg' = seg^(row&3); read phys chunk = lg^(row&3)). 8-way -> 4-way.
// Per K-tile: STAGE(t+2) -> vmcnt(8) -> B0 -> 4 phases of
//   {issue 2 A-reads (pre-barrier, hidden under other waves' MFMA) -> barrier ->
//    lgkmcnt(0) -> 8 MFMA (setprio)} ; B-frags read once in phase 0.
template <int NT>
__device__ __forceinline__ void gemm_loop(const ushort_t* __restrict__ a0,
                                          const ushort_t* __restrict__ a1,
                                          const ushort_t* __restrict__ b0,
                                          const ushort_t* __restrict__ b1,
                                          ushort_t* AsLds, ushort_t* BsLds,
                                          f32x4 (&acc)[8][4]) {
  int tid = threadIdx.x;
  int wid = tid >> 6, lane = tid & 63;
  int wm = wid >> 2, wn = wid & 3;        // 2x4 waves; wave tile 128x64
  int lm = lane & 15, lg = lane >> 4;
  int pc = lg ^ (lm & 3);                  // swizzled phys chunk for reads

  unsigned abase = lds_off(AsLds), bbase = lds_off(BsLds);
  unsigned aoff[8], boff[4];
#pragma unroll
  for (int m = 0; m < 8; m++)
    aoff[m] = abase + (unsigned)(((wm * 128 + m * 16 + lm) * BK + pc * 8) * 2);
#pragma unroll
  for (int n = 0; n < 4; n++)
    boff[n] = bbase + (unsigned)(((wn * 64 + n * 16 + lm) * BK + pc * 8) * 2);

  const ushort_t* ap[2] = {a0, a1};
  const ushort_t* bp[2] = {b0, b1};

  auto STAGE = [&](int buf, int k0) {
#pragma unroll
    for (int j = 0; j < 2; j++) {
      gload16(ap[j] + k0, AsLds + buf * SLOT + (j * 512 + wid * 64) * 8);
      gload16(bp[j] + k0, BsLds + buf * SLOT + (j * 512 + wid * 64) * 8);
    }
  };

  STAGE(0, 0);
  STAGE(1, BK);
  int cur = 0;
  for (int t = 0; t < NT; ++t) {
    int s2 = cur + 2; if (s2 >= 3) s2 -= 3;
    if (t + 2 < NT) {
      STAGE(s2, (t + 2) * BK);
      __builtin_amdgcn_sched_barrier(0);
      asm volatile("s_waitcnt vmcnt(8)" ::: "memory");   // tile t's loads landed
    } else if (t + 1 < NT) {
      __builtin_amdgcn_sched_barrier(0);
      asm volatile("s_waitcnt vmcnt(4)" ::: "memory");
    } else {
      __builtin_amdgcn_sched_barrier(0);
      asm volatile("s_waitcnt vmcnt(0)" ::: "memory");
    }
    __builtin_amdgcn_s_barrier();       // B0: tile t visible to all waves
    __builtin_amdgcn_sched_barrier(0);
    unsigned cb = (unsigned)(cur * SLOTB);

    bf16x8 bv[4], af0, af1;
    // phase 0: B frags + A quadrant 0
#pragma unroll
    for (int n = 0; n < 4; n++) bv[n] = ds_read128(boff[n] + cb);
    af0 = ds_read128(aoff[0] + cb);
    af1 = ds_read128(aoff[1] + cb);
    asm volatile("s_waitcnt lgkmcnt(0)" ::: "memory");
    __builtin_amdgcn_sched_barrier(0);
    __builtin_amdgcn_s_setprio(1);
#pragma unroll
    for (int n = 0; n < 4; n++) {
      acc[0][n] = __builtin_amdgcn_mfma_f32_16x16x32_bf16(af0, bv[n], acc[0][n], 0, 0, 0);
      acc[1][n] = __builtin_amdgcn_mfma_f32_16x16x32_bf16(af1, bv[n], acc[1][n], 0, 0, 0);
    }
    __builtin_amdgcn_s_setprio(0);
    // phases 1..3: issue next quadrant's reads pre-barrier (hidden under MFMA)
#pragma unroll
    for (int q = 1; q < 4; q++) {
      bf16x8 nf0 = ds_read128(aoff[2 * q] + cb);
      bf16x8 nf1 = ds_read128(aoff[2 * q + 1] + cb);
      __builtin_amdgcn_sched_barrier(0);
      __builtin_amdgcn_s_barrier();
      asm volatile("s_waitcnt lgkmcnt(0)" ::: "memory");
      __builtin_amdgcn_sched_barrier(0);
      __builtin_amdgcn_s_setprio(1);
#pragma unroll
      for (int n = 0; n < 4; n++) {
        acc[2 * q][n]     = __builtin_amdgcn_mfma_f32_16x16x32_bf16(nf0, bv[n], acc[2 * q][n], 0, 0, 0);
        acc[2 * q + 1][n] = __builtin_amdgcn_mfma_f32_16x16x32_bf16(nf1, bv[n], acc[2 * q + 1][n], 0, 0, 0);
      }
      __builtin_amdgcn_s_setprio(0);
    }
    __builtin_amdgcn_sched_barrier(0);
    __builtin_amdgcn_s_barrier();       // end: all reads of cur done -> safe restage
    __builtin_amdgcn_sched_barrier(0);
    cur += 1; if (cur == 3) cur = 0;
  }
}

// GEMM1: H[p,f] = gelu( gather(x)[p,:] @ w1t[e]^T + b1[e] )   w1t: [F][D] bf16
__global__ __launch_bounds__(512) void k_gemm1(
    const ushort_t* __restrict__ xbf, const ushort_t* __restrict__ w1t, const float* __restrict__ b1,
    const int* __restrict__ counts, const int* __restrict__ offsets,
    const int* __restrict__ ltok, ushort_t* __restrict__ H) {
  int e = blockIdx.z;
  int cnt = counts[e];
  int xt, yt;
  xcd_decode(blockIdx.x, (T_TOK / BM) * (FFN / BN), T_TOK / BM, xt, yt);
  int row0 = xt * BM;
  if (row0 >= cnt) return;
  int base = offsets[e];
  int col0 = yt * BN;
  const ushort_t* Bt = w1t + (size_t)e * DIM * FFN;

  __shared__ __align__(16) ushort_t As[3 * SLOT];
  __shared__ __align__(16) ushort_t Bs[3 * SLOT];

  int tid = threadIdx.x;
  int rsub = tid >> 2;
  int seg = (tid & 3) ^ (rsub & 3);      // swizzled source chunk
  const ushort_t* asrc[2]; const ushort_t* bsrc[2];
#pragma unroll
  for (int j = 0; j < 2; j++) {
    int row = j * 128 + rsub;
    int ar = min(row0 + row, cnt - 1);
    asrc[j] = xbf + (size_t)ltok[base + ar] * DIM + seg * 8;
    bsrc[j] = Bt + (size_t)(col0 + row) * DIM + seg * 8;
  }
  f32x4 acc[8][4];
#pragma unroll
  for (int m = 0; m < 8; m++)
#pragma unroll
    for (int n = 0; n < 4; n++) acc[m][n] = (f32x4){0.f, 0.f, 0.f, 0.f};

  gemm_loop<DIM / BK>(asrc[0], asrc[1], bsrc[0], bsrc[1], As, Bs, acc);

  int wid = tid >> 6, lane = tid & 63;
  int wm = wid >> 2, wn = wid & 3;
  int lm = lane & 15, lg = lane >> 4;
#pragma unroll
  for (int m = 0; m < 8; m++) {
#pragma unroll
    for (int n = 0; n < 4; n++) {
      int f = col0 + wn * 64 + n * 16 + lm;
      float bias = b1[e * FFN + f];
#pragma unroll
      for (int r = 0; r < 4; r++) {
        int row = row0 + wm * 128 + m * 16 + lg * 4 + r;
        if (row < cnt) {
          float v = acc[m][n][r] + bias;
          H[(size_t)(base + row) * FFN + f] = f2bf(gelu_exact(v));
        }
      }
    }
  }
}

// GEMM2: contrib[p,d] = cw[p] * ( H[p,:] @ w2t[e]^T + b2[e] )   w2t: [D][F] bf16
__global__ __launch_bounds__(512) void k_gemm2(
    const ushort_t* __restrict__ H, const ushort_t* __restrict__ w2t, const float* __restrict__ b2,
    const int* __restrict__ counts, const int* __restrict__ offsets,
    const float* __restrict__ lwt, ushort_t* __restrict__ contrib) {
  int e = blockIdx.z;
  int cnt = counts[e];
  int xt, yt;
  xcd_decode(blockIdx.x, (T_TOK / BM) * (DIM / BN), T_TOK / BM, xt, yt);
  int row0 = xt * BM;
  if (row0 >= cnt) return;
  int base = offsets[e];
  int col0 = yt * BN;
  const ushort_t* Bt = w2t + (size_t)e * DIM * FFN;

  __shared__ __align__(16) ushort_t As[3 * SLOT];
  __shared__ __align__(16) ushort_t Bs[3 * SLOT];

  int tid = threadIdx.x;
  int rsub = tid >> 2;
  int seg = (tid & 3) ^ (rsub & 3);
  const ushort_t* asrc[2]; const ushort_t* bsrc[2];
#pragma unroll
  for (int j = 0; j < 2; j++) {
    int row = j * 128 + rsub;
    int ar = min(row0 + row, cnt - 1);
    asrc[j] = H + (size_t)(base + ar) * FFN + seg * 8;
    bsrc[j] = Bt + (size_t)(col0 + row) * FFN + seg * 8;
  }
  f32x4 acc[8][4];
#pragma unroll
  for (int m = 0; m < 8; m++)
#pragma unroll
    for (int n = 0; n < 4; n++) acc[m][n] = (f32x4){0.f, 0.f, 0.f, 0.f};

  gemm_loop<FFN / BK>(asrc[0], asrc[1], bsrc[0], bsrc[1], As, Bs, acc);

  int wid = tid >> 6, lane = tid & 63;
  int wm = wid >> 2, wn = wid & 3;
  int lm = lane & 15, lg = lane >> 4;
#pragma unroll
  for (int m = 0; m < 8; m++) {
#pragma unroll
    for (int n = 0; n < 4; n++) {
      int d = col0 + wn * 64 + n * 16 + lm;
      float bias = b2[e * DIM + d];
#pragma unroll
      for (int r = 0; r < 4; r++) {
        int row = row0 + wm * 128 + m * 16 + lg * 4 + r;
        if (row < cnt) {
          float v = (acc[m][n][r] + bias) * lwt[base + row];
          contrib[(size_t)(base + row) * DIM + d] = f2bf(v);
        }
      }
    }
  }
}

// ---------------- combine: out = x + contrib[p0] + contrib[p1] ----------------
__global__ void k_combine(const float* __restrict__ x, const ushort_t* __restrict__ contrib,
                          const int* __restrict__ ppos, float* __restrict__ out) {
  int i = blockIdx.x * blockDim.x + threadIdx.x;
  int t = i / (DIM / 4);
  int dq = i % (DIM / 4);
  int p0 = ppos[t * 2 + 0], p1 = ppos[t * 2 + 1];
  float4 xv = reinterpret_cast<const float4*>(x)[i];
  ushort4v c0 = reinterpret_cast<const ushort4v*>(contrib + (size_t)p0 * DIM)[dq];
  ushort4v c1 = reinterpret_cast<const ushort4v*>(contrib + (size_t)p1 * DIM)[dq];
  float4 o;
  o.x = xv.x + bf2f(c0.x) + bf2f(c1.x);
  o.y = xv.y + bf2f(c0.y) + bf2f(c1.y);
  o.z = xv.z + bf2f(c0.z) + bf2f(c1.z);
  o.w = xv.w + bf2f(c0.w) + bf2f(c1.w);
  reinterpret_cast<float4*>(out)[i] = o;
}

extern "C" void kernel_launch(void* const* d_in, const int* in_sizes, int n_in,
                              void* d_out, int out_size, void* d_ws, size_t ws_size,
                              hipStream_t stream) {
  const float* x  = (const float*)d_in[0];
  const float* rw = (const float*)d_in[1];
  const float* w1 = (const float*)d_in[2];
  const float* b1 = (const float*)d_in[3];
  const float* w2 = (const float*)d_in[4];
  const float* b2 = (const float*)d_in[5];
  float* out = (float*)d_out;
  char* ws = (char*)d_ws;

  const size_t MB = 1u << 20;
  int*   counts  = (int*)(ws);
  int*   offsets = (int*)(ws + 64);
  int*   cursors = (int*)(ws + 128);
  int*   tidx    = (int*)(ws + 1 * MB);
  float* twt     = (float*)(ws + 2 * MB);
  int*   ltok    = (int*)(ws + 3 * MB);
  float* lwt     = (float*)(ws + 4 * MB);
  int*   ppos    = (int*)(ws + 5 * MB);
  // overlaid big buffers (lifetimes disjoint where they overlap):
  ushort_t* xbf     = (ushort_t*)(ws + 8 * MB);     // 32 MB, live cast..gemm1
  ushort_t* contrib = (ushort_t*)(ws + 8 * MB);     // 64 MB, live gemm2..combine (xbf dead)
  ushort_t* Hbuf    = (ushort_t*)(ws + 72 * MB);    // 256 MB, live gemm1..gemm2
  ushort_t* w1t     = (ushort_t*)(ws + 328 * MB);   // 256 MB, live wcvt1..gemm1
  ushort_t* w2t     = (ushort_t*)(ws + 328 * MB);   // 256 MB, live wcvt2..gemm2 (after gemm1)
  const size_t NEED = 584 * MB;
  if (ws_size < NEED) {
    hipMemsetAsync(d_out, 0, (size_t)out_size * sizeof(float), stream);
    return;
  }

  hipMemsetAsync(ws, 0, 256, stream);  // counts + cursors
  k_cast<<<dim3((T_TOK * (size_t)DIM / 4) / 256), 256, 0, stream>>>(x, xbf);
  k_router<<<T_TOK, 256, 0, stream>>>(x, rw, tidx, twt, counts);
  k_scan<<<1, 64, 0, stream>>>(counts, offsets);
  k_fill<<<T_TOK / 256, 256, 0, stream>>>(tidx, twt, offsets, cursors, ltok, lwt, ppos);
  // w1: [E][D][F] fp32 -> w1t [E][F][D] bf16
  k_wcvt<<<dim3(FFN / TT, DIM / TT, NE), 256, 0, stream>>>(w1, w1t, DIM, FFN);
  k_gemm1<<<dim3((T_TOK / BM) * (FFN / BN), 1, NE), 512, 0, stream>>>(xbf, w1t, b1, counts, offsets, ltok, Hbuf);
  // w2: [E][F][D] fp32 -> w2t [E][D][F] bf16  (after gemm1; reuses w1t region)
  k_wcvt<<<dim3(DIM / TT, FFN / TT, NE), 256, 0, stream>>>(w2, w2t, FFN, DIM);
  k_gemm2<<<dim3((T_TOK / BM) * (DIM / BN), 1, NE), 512, 0, stream>>>(Hbuf, w2t, b2, counts, offsets, lwt, contrib);
  k_combine<<<dim3((T_TOK * (size_t)DIM / 4) / 256), 256, 0, stream>>>(x, contrib, ppos, out);
}

// Round 13
// 2167.810 us; speedup vs baseline: 1.7131x; 1.0713x over previous
//
#include <hip/hip_runtime.h>

// MoE block: B=4,S=2048 -> T=8192 tokens, D=2048, F=8192, E=8, K=2
#define T_TOK 8192
#define DIM   2048
#define FFN   8192
#define NE    8
#define TOPK  2

typedef unsigned short ushort_t;
typedef unsigned short ushort8  __attribute__((ext_vector_type(8)));
typedef unsigned short ushort4v __attribute__((ext_vector_type(4)));
typedef short bf16x8 __attribute__((ext_vector_type(8)));
typedef float f32x4  __attribute__((ext_vector_type(4)));

__device__ __forceinline__ ushort_t f2bf(float f) {
  unsigned int u = __float_as_uint(f);
  u += 0x7FFFu + ((u >> 16) & 1u);   // RNE
  return (ushort_t)(u >> 16);
}
__device__ __forceinline__ float bf2f(ushort_t u) {
  return __uint_as_float(((unsigned int)u) << 16);
}

// async global->LDS, 16B per lane. LDS dest wave-uniform base; HW adds lane*16.
__device__ __forceinline__ void gload16(const void* g, void* l) {
  __builtin_amdgcn_global_load_lds((const __attribute__((address_space(1))) void*)g,
                                   (__attribute__((address_space(3))) void*)l, 16, 0, 0);
}

// exact-erf GELU via Abramowitz-Stegun 7.1.26 (|err| <= 1.5e-7)
__device__ __forceinline__ float gelu_exact(float v) {
  float s = v * 0.70710678118654752f;
  float a = fabsf(s);
  float t = __builtin_amdgcn_rcpf(1.0f + 0.3275911f * a);
  float p = t * (0.254829592f +
            t * (-0.284496736f +
            t * (1.421413741f +
            t * (-1.453152027f +
            t * 1.061405429f))));
  float er = 1.0f - p * __expf(-a * a);
  er = copysignf(er, s);
  return 0.5f * v * (1.0f + er);
}

// ---------------- router + fused x->bf16 cast ----------------
__global__ __launch_bounds__(256) void k_router(
    const float* __restrict__ x, const float* __restrict__ rw, ushort_t* __restrict__ xbf,
    int* __restrict__ tidx, float* __restrict__ twt, int* __restrict__ counts) {
  int t = blockIdx.x;
  int tid = threadIdx.x;
  int lane = tid & 63, wave = tid >> 6;
  float acc[NE];
#pragma unroll
  for (int e = 0; e < NE; e++) acc[e] = 0.f;
  const float* xr = x + (size_t)t * DIM;
  ushort_t* xbr = xbf + (size_t)t * DIM;
#pragma unroll
  for (int it = 0; it < 2; it++) {
    int d4 = it * 1024 + tid * 4;         // elem base, float4-aligned, coalesced
    float4 v = *reinterpret_cast<const float4*>(xr + d4);
    ushort4v o;
    o.x = f2bf(v.x); o.y = f2bf(v.y); o.z = f2bf(v.z); o.w = f2bf(v.w);
    *reinterpret_cast<ushort4v*>(xbr + d4) = o;   // fused cast
    const float* r0p = rw + (size_t)d4 * NE;
    float xv[4] = {v.x, v.y, v.z, v.w};
#pragma unroll
    for (int j = 0; j < 4; j++) {
      const float* r = r0p + j * NE;
#pragma unroll
      for (int e = 0; e < NE; e++) acc[e] += xv[j] * r[e];
    }
  }
  __shared__ float wsum[4][NE];
#pragma unroll
  for (int e = 0; e < NE; e++) {
    float v = acc[e];
#pragma unroll
    for (int off = 32; off > 0; off >>= 1) v += __shfl_down(v, off);
    if (lane == 0) wsum[wave][e] = v;
  }
  __syncthreads();
  if (tid == 0) {
    float lg[NE];
#pragma unroll
    for (int e = 0; e < NE; e++) lg[e] = wsum[0][e] + wsum[1][e] + wsum[2][e] + wsum[3][e];
    int i0 = 0; float v0 = lg[0];
#pragma unroll
    for (int e = 1; e < NE; e++) if (lg[e] > v0) { v0 = lg[e]; i0 = e; }
    int i1 = -1; float v1 = -3.4e38f;
#pragma unroll
    for (int e = 0; e < NE; e++) if (e != i0 && lg[e] > v1) { v1 = lg[e]; i1 = e; }
    float e1 = expf(v1 - v0);
    float s = 1.f + e1;
    tidx[t * 2 + 0] = i0; tidx[t * 2 + 1] = i1;
    twt[t * 2 + 0] = 1.f / s; twt[t * 2 + 1] = e1 / s;
    atomicAdd(&counts[i0], 1);
    atomicAdd(&counts[i1], 1);
  }
}

// ---------------- weight convert+transpose: fp32 [R][C] -> bf16 [C][R] ----------------
// fp32 staging in [64][65]-padded LDS: write 2-way, transpose-read 2-way (free, m136).
#define TT 64
__global__ __launch_bounds__(256) void k_wcvt(const float* __restrict__ in,
                                              ushort_t* __restrict__ outp, int R, int C) {
  __shared__ float t[TT][TT + 1];
  int e = blockIdx.z;
  const float* src = in + (size_t)e * R * C;
  ushort_t* dst = outp + (size_t)e * R * C;
  int r0 = blockIdx.y * TT, c0 = blockIdx.x * TT;
  int tid = threadIdx.x;
  int rr = tid >> 4;       // 0..15
  int c4 = tid & 15;       // float4 col group
#pragma unroll
  for (int i = 0; i < 4; i++) {
    int r = rr + i * 16;
    float4 v = *reinterpret_cast<const float4*>(src + (size_t)(r0 + r) * C + c0 + c4 * 4);
    t[r][c4 * 4 + 0] = v.x; t[r][c4 * 4 + 1] = v.y;
    t[r][c4 * 4 + 2] = v.z; t[r][c4 * 4 + 3] = v.w;
  }
  __syncthreads();
  int c = tid >> 2, rs = tid & 3;      // out row c0+c, 16 r-elems starting rs*16
  ushort8 v0, v1;
#pragma unroll
  for (int i = 0; i < 8; i++) {
    v0[i] = f2bf(t[rs * 16 + i][c]);
    v1[i] = f2bf(t[rs * 16 + 8 + i][c]);
  }
  ushort_t* drow = dst + (size_t)(c0 + c) * R + r0 + rs * 16;
  *reinterpret_cast<ushort8*>(drow) = v0;
  *reinterpret_cast<ushort8*>(drow + 8) = v1;
}

__global__ void k_scan(const int* __restrict__ counts, int* __restrict__ offsets) {
  if (threadIdx.x == 0) {
    int s = 0;
    for (int e = 0; e < NE; e++) { offsets[e] = s; s += counts[e]; }
    offsets[NE] = s;
  }
}

__global__ void k_fill(const int* __restrict__ tidx, const float* __restrict__ twt,
                       const int* __restrict__ offsets, int* __restrict__ cursors,
                       int* __restrict__ ltok, float* __restrict__ lwt, int* __restrict__ ppos) {
  int t = blockIdx.x * blockDim.x + threadIdx.x;
  if (t >= T_TOK) return;
#pragma unroll
  for (int k = 0; k < TOPK; k++) {
    int e = tidx[t * 2 + k];
    int pos = atomicAdd(&cursors[e], 1);
    int p = offsets[e] + pos;
    ltok[p] = t;
    lwt[p] = twt[t * 2 + k];
    ppos[t * 2 + k] = p;
  }
}

// ---------------- m97-style GEMMs (r6-proven best) + XCD-chunked swizzle ----------------
#define BM 128
#define BN 128
#define BK 32

// XCD-chunked bijective swizzle (nwg divisible by 8): each XCD owns a contiguous
// chunk of work ids; within a chunk, row-tile fastest (B col-panel stays on one XCD).
__device__ __forceinline__ void xcd_decode(int lin, int nwg, int nx, int& xt, int& yt) {
  int q = nwg >> 3;
  int w = (lin & 7) * q + (lin >> 3);
  xt = w % nx;
  yt = w / nx;
}

// GEMM1: H[p,f] = gelu( gather(x)[p,:] @ w1t[e]^T + b1[e] )   w1t: [F][D] bf16
__global__ __launch_bounds__(256) void k_gemm1(
    const ushort_t* __restrict__ xbf, const ushort_t* __restrict__ w1t, const float* __restrict__ b1,
    const int* __restrict__ counts, const int* __restrict__ offsets,
    const int* __restrict__ ltok, ushort_t* __restrict__ H) {
  int e = blockIdx.z;
  int cnt = counts[e];
  int xt, yt;
  xcd_decode(blockIdx.x, (T_TOK / BM) * (FFN / BN), T_TOK / BM, xt, yt);
  int row0 = xt * BM;
  if (row0 >= cnt) return;
  int base = offsets[e];
  int col0 = yt * BN;
  const ushort_t* Bt = w1t + (size_t)e * DIM * FFN;

  __shared__ __align__(16) ushort_t As[BM * BK];   // linear [128][32]
  __shared__ __align__(16) ushort_t Bs[BM * BK];

  int tid = threadIdx.x;
  int wave = tid >> 6, lane = tid & 63;
  int wm = wave >> 1, wn = wave & 1;
  int lm = lane & 15, lg = lane >> 4;

  int srow = tid >> 2, seg = tid & 3;
  const ushort_t* asrc[2]; const ushort_t* bsrc[2];
#pragma unroll
  for (int j = 0; j < 2; j++) {
    int ar = min(row0 + j * 64 + srow, cnt - 1);
    asrc[j] = xbf + (size_t)ltok[base + ar] * DIM + seg * 8;
    bsrc[j] = Bt + (size_t)(col0 + j * 64 + srow) * DIM + seg * 8;
  }
  f32x4 acc[4][4];
#pragma unroll
  for (int m = 0; m < 4; m++)
#pragma unroll
    for (int n = 0; n < 4; n++) acc[m][n] = (f32x4){0.f, 0.f, 0.f, 0.f};

  for (int k0 = 0; k0 < DIM; k0 += BK) {
#pragma unroll
    for (int j = 0; j < 2; j++) {
      gload16(asrc[j] + k0, &As[(j * 256 + wave * 64) * 8]);
      gload16(bsrc[j] + k0, &Bs[(j * 256 + wave * 64) * 8]);
    }
    __syncthreads();   // compiler drains vmcnt before barrier
    bf16x8 af[4], bfv[4];
#pragma unroll
    for (int m = 0; m < 4; m++)
      af[m] = *reinterpret_cast<const bf16x8*>(&As[(wm * 64 + m * 16 + lm) * BK + lg * 8]);
#pragma unroll
    for (int n = 0; n < 4; n++)
      bfv[n] = *reinterpret_cast<const bf16x8*>(&Bs[(wn * 64 + n * 16 + lm) * BK + lg * 8]);
#pragma unroll
    for (int m = 0; m < 4; m++)
#pragma unroll
      for (int n = 0; n < 4; n++)
        acc[m][n] = __builtin_amdgcn_mfma_f32_16x16x32_bf16(af[m], bfv[n], acc[m][n], 0, 0, 0);
    __syncthreads();
  }
#pragma unroll
  for (int m = 0; m < 4; m++) {
#pragma unroll
    for (int n = 0; n < 4; n++) {
      int f = col0 + wn * 64 + n * 16 + lm;
      float bias = b1[e * FFN + f];
#pragma unroll
      for (int r = 0; r < 4; r++) {
        int row = row0 + wm * 64 + m * 16 + lg * 4 + r;
        if (row < cnt) {
          float v = acc[m][n][r] + bias;
          H[(size_t)(base + row) * FFN + f] = f2bf(gelu_exact(v));
        }
      }
    }
  }
}

// GEMM2: contrib[p,d] = cw[p] * ( H[p,:] @ w2t[e]^T + b2[e] )   w2t: [D][F] bf16
__global__ __launch_bounds__(256) void k_gemm2(
    const ushort_t* __restrict__ H, const ushort_t* __restrict__ w2t, const float* __restrict__ b2,
    const int* __restrict__ counts, const int* __restrict__ offsets,
    const float* __restrict__ lwt, ushort_t* __restrict__ contrib) {
  int e = blockIdx.z;
  int cnt = counts[e];
  int xt, yt;
  xcd_decode(blockIdx.x, (T_TOK / BM) * (DIM / BN), T_TOK / BM, xt, yt);
  int row0 = xt * BM;
  if (row0 >= cnt) return;
  int base = offsets[e];
  int col0 = yt * BN;
  const ushort_t* Bt = w2t + (size_t)e * DIM * FFN;

  __shared__ __align__(16) ushort_t As[BM * BK];
  __shared__ __align__(16) ushort_t Bs[BM * BK];

  int tid = threadIdx.x;
  int wave = tid >> 6, lane = tid & 63;
  int wm = wave >> 1, wn = wave & 1;
  int lm = lane & 15, lg = lane >> 4;

  int srow = tid >> 2, seg = tid & 3;
  const ushort_t* asrc[2]; const ushort_t* bsrc[2];
#pragma unroll
  for (int j = 0; j < 2; j++) {
    int ar = min(row0 + j * 64 + srow, cnt - 1);
    asrc[j] = H + (size_t)(base + ar) * FFN + seg * 8;
    bsrc[j] = Bt + (size_t)(col0 + j * 64 + srow) * FFN + seg * 8;
  }
  f32x4 acc[4][4];
#pragma unroll
  for (int m = 0; m < 4; m++)
#pragma unroll
    for (int n = 0; n < 4; n++) acc[m][n] = (f32x4){0.f, 0.f, 0.f, 0.f};

  for (int k0 = 0; k0 < FFN; k0 += BK) {
#pragma unroll
    for (int j = 0; j < 2; j++) {
      gload16(asrc[j] + k0, &As[(j * 256 + wave * 64) * 8]);
      gload16(bsrc[j] + k0, &Bs[(j * 256 + wave * 64) * 8]);
    }
    __syncthreads();
    bf16x8 af[4], bfv[4];
#pragma unroll
    for (int m = 0; m < 4; m++)
      af[m] = *reinterpret_cast<const bf16x8*>(&As[(wm * 64 + m * 16 + lm) * BK + lg * 8]);
#pragma unroll
    for (int n = 0; n < 4; n++)
      bfv[n] = *reinterpret_cast<const bf16x8*>(&Bs[(wn * 64 + n * 16 + lm) * BK + lg * 8]);
#pragma unroll
    for (int m = 0; m < 4; m++)
#pragma unroll
      for (int n = 0; n < 4; n++)
        acc[m][n] = __builtin_amdgcn_mfma_f32_16x16x32_bf16(af[m], bfv[n], acc[m][n], 0, 0, 0);
    __syncthreads();
  }
#pragma unroll
  for (int m = 0; m < 4; m++) {
#pragma unroll
    for (int n = 0; n < 4; n++) {
      int d = col0 + wn * 64 + n * 16 + lm;
      float bias = b2[e * DIM + d];
#pragma unroll
      for (int r = 0; r < 4; r++) {
        int row = row0 + wm * 64 + m * 16 + lg * 4 + r;
        if (row < cnt) {
          float v = (acc[m][n][r] + bias) * lwt[base + row];
          contrib[(size_t)(base + row) * DIM + d] = f2bf(v);
        }
      }
    }
  }
}

// ---------------- combine: out = x + contrib[p0] + contrib[p1] ----------------
__global__ void k_combine(const float* __restrict__ x, const ushort_t* __restrict__ contrib,
                          const int* __restrict__ ppos, float* __restrict__ out) {
  int i = blockIdx.x * blockDim.x + threadIdx.x;
  int t = i / (DIM / 4);
  int dq = i % (DIM / 4);
  int p0 = ppos[t * 2 + 0], p1 = ppos[t * 2 + 1];
  float4 xv = reinterpret_cast<const float4*>(x)[i];
  ushort4v c0 = reinterpret_cast<const ushort4v*>(contrib + (size_t)p0 * DIM)[dq];
  ushort4v c1 = reinterpret_cast<const ushort4v*>(contrib + (size_t)p1 * DIM)[dq];
  float4 o;
  o.x = xv.x + bf2f(c0.x) + bf2f(c1.x);
  o.y = xv.y + bf2f(c0.y) + bf2f(c1.y);
  o.z = xv.z + bf2f(c0.z) + bf2f(c1.z);
  o.w = xv.w + bf2f(c0.w) + bf2f(c1.w);
  reinterpret_cast<float4*>(out)[i] = o;
}

extern "C" void kernel_launch(void* const* d_in, const int* in_sizes, int n_in,
                              void* d_out, int out_size, void* d_ws, size_t ws_size,
                              hipStream_t stream) {
  const float* x  = (const float*)d_in[0];
  const float* rw = (const float*)d_in[1];
  const float* w1 = (const float*)d_in[2];
  const float* b1 = (const float*)d_in[3];
  const float* w2 = (const float*)d_in[4];
  const float* b2 = (const float*)d_in[5];
  float* out = (float*)d_out;
  char* ws = (char*)d_ws;

  const size_t MB = 1u << 20;
  int*   counts  = (int*)(ws);
  int*   offsets = (int*)(ws + 64);
  int*   cursors = (int*)(ws + 128);
  int*   tidx    = (int*)(ws + 1 * MB);
  float* twt     = (float*)(ws + 2 * MB);
  int*   ltok    = (int*)(ws + 3 * MB);
  float* lwt     = (float*)(ws + 4 * MB);
  int*   ppos    = (int*)(ws + 5 * MB);
  // overlaid big buffers (lifetimes disjoint where they overlap):
  ushort_t* xbf     = (ushort_t*)(ws + 8 * MB);     // 32 MB, live router..gemm1
  ushort_t* contrib = (ushort_t*)(ws + 8 * MB);     // 64 MB, live gemm2..combine (xbf dead)
  ushort_t* Hbuf    = (ushort_t*)(ws + 72 * MB);    // 256 MB, live gemm1..gemm2
  ushort_t* w1t     = (ushort_t*)(ws + 328 * MB);   // 256 MB, live wcvt1..gemm1
  ushort_t* w2t     = (ushort_t*)(ws + 328 * MB);   // 256 MB, live wcvt2..gemm2 (after gemm1)
  const size_t NEED = 584 * MB;
  if (ws_size < NEED) {
    hipMemsetAsync(d_out, 0, (size_t)out_size * sizeof(float), stream);
    return;
  }

  hipMemsetAsync(ws, 0, 256, stream);  // counts + cursors
  k_router<<<T_TOK, 256, 0, stream>>>(x, rw, xbf, tidx, twt, counts);
  k_scan<<<1, 64, 0, stream>>>(counts, offsets);
  k_fill<<<T_TOK / 256, 256, 0, stream>>>(tidx, twt, offsets, cursors, ltok, lwt, ppos);
  // w1: [E][D][F] fp32 -> w1t [E][F][D] bf16
  k_wcvt<<<dim3(FFN / TT, DIM / TT, NE), 256, 0, stream>>>(w1, w1t, DIM, FFN);
  k_gemm1<<<dim3((T_TOK / BM) * (FFN / BN), 1, NE), 256, 0, stream>>>(xbf, w1t, b1, counts, offsets, ltok, Hbuf);
  // w2: [E][F][D] fp32 -> w2t [E][D][F] bf16  (after gemm1; reuses w1t region)
  k_wcvt<<<dim3(DIM / TT, FFN / TT, NE), 256, 0, stream>>>(w2, w2t, FFN, DIM);
  k_gemm2<<<dim3((T_TOK / BM) * (DIM / BN), 1, NE), 256, 0, stream>>>(Hbuf, w2t, b2, counts, offsets, lwt, contrib);
  k_combine<<<dim3((T_TOK * (size_t)DIM / 4) / 256), 256, 0, stream>>>(x, contrib, ppos, out);
}

// Round 14
// 2120.754 us; speedup vs baseline: 1.7511x; 1.0222x over previous
//
#include <hip/hip_runtime.h>

// MoE block: B=4,S=2048 -> T=8192 tokens, D=2048, F=8192, E=8, K=2
#define T_TOK 8192
#define DIM   2048
#define FFN   8192
#define NE    8
#define TOPK  2

typedef unsigned short ushort_t;
typedef unsigned short ushort8  __attribute__((ext_vector_type(8)));
typedef unsigned short ushort4v __attribute__((ext_vector_type(4)));
typedef short bf16x8 __attribute__((ext_vector_type(8)));
typedef float f32x4  __attribute__((ext_vector_type(4)));

__device__ __forceinline__ ushort_t f2bf(float f) {
  unsigned int u = __float_as_uint(f);
  u += 0x7FFFu + ((u >> 16) & 1u);   // RNE
  return (ushort_t)(u >> 16);
}
__device__ __forceinline__ float bf2f(ushort_t u) {
  return __uint_as_float(((unsigned int)u) << 16);
}

// async global->LDS, 16B per lane. LDS dest wave-uniform base; HW adds lane*16.
__device__ __forceinline__ void gload16(const void* g, void* l) {
  __builtin_amdgcn_global_load_lds((const __attribute__((address_space(1))) void*)g,
                                   (__attribute__((address_space(3))) void*)l, 16, 0, 0);
}
__device__ __forceinline__ unsigned lds_off(const ushort_t* p) {
  return (unsigned)(uintptr_t)(__attribute__((address_space(3))) const ushort_t*)p;
}
// invisible LDS read: no compiler-inserted vmcnt drain before it
__device__ __forceinline__ bf16x8 ds_read128(unsigned off) {
  bf16x8 r;
  asm volatile("ds_read_b128 %0, %1" : "=v"(r) : "v"(off));
  return r;
}

// exact-erf GELU via Abramowitz-Stegun 7.1.26 (|err| <= 1.5e-7)
__device__ __forceinline__ float gelu_exact(float v) {
  float s = v * 0.70710678118654752f;
  float a = fabsf(s);
  float t = __builtin_amdgcn_rcpf(1.0f + 0.3275911f * a);
  float p = t * (0.254829592f +
            t * (-0.284496736f +
            t * (1.421413741f +
            t * (-1.453152027f +
            t * 1.061405429f))));
  float er = 1.0f - p * __expf(-a * a);
  er = copysignf(er, s);
  return 0.5f * v * (1.0f + er);
}

// ---------------- router + fused x->bf16 cast ----------------
__global__ __launch_bounds__(256) void k_router(
    const float* __restrict__ x, const float* __restrict__ rw, ushort_t* __restrict__ xbf,
    int* __restrict__ tidx, float* __restrict__ twt, int* __restrict__ counts) {
  int t = blockIdx.x;
  int tid = threadIdx.x;
  int lane = tid & 63, wave = tid >> 6;
  float acc[NE];
#pragma unroll
  for (int e = 0; e < NE; e++) acc[e] = 0.f;
  const float* xr = x + (size_t)t * DIM;
  ushort_t* xbr = xbf + (size_t)t * DIM;
#pragma unroll
  for (int it = 0; it < 2; it++) {
    int d4 = it * 1024 + tid * 4;
    float4 v = *reinterpret_cast<const float4*>(xr + d4);
    ushort4v o;
    o.x = f2bf(v.x); o.y = f2bf(v.y); o.z = f2bf(v.z); o.w = f2bf(v.w);
    *reinterpret_cast<ushort4v*>(xbr + d4) = o;
    const float* r0p = rw + (size_t)d4 * NE;
    float xv[4] = {v.x, v.y, v.z, v.w};
#pragma unroll
    for (int j = 0; j < 4; j++) {
      const float* r = r0p + j * NE;
#pragma unroll
      for (int e = 0; e < NE; e++) acc[e] += xv[j] * r[e];
    }
  }
  __shared__ float wsum[4][NE];
#pragma unroll
  for (int e = 0; e < NE; e++) {
    float v = acc[e];
#pragma unroll
    for (int off = 32; off > 0; off >>= 1) v += __shfl_down(v, off);
    if (lane == 0) wsum[wave][e] = v;
  }
  __syncthreads();
  if (tid == 0) {
    float lg[NE];
#pragma unroll
    for (int e = 0; e < NE; e++) lg[e] = wsum[0][e] + wsum[1][e] + wsum[2][e] + wsum[3][e];
    int i0 = 0; float v0 = lg[0];
#pragma unroll
    for (int e = 1; e < NE; e++) if (lg[e] > v0) { v0 = lg[e]; i0 = e; }
    int i1 = -1; float v1 = -3.4e38f;
#pragma unroll
    for (int e = 0; e < NE; e++) if (e != i0 && lg[e] > v1) { v1 = lg[e]; i1 = e; }
    float e1 = expf(v1 - v0);
    float s = 1.f + e1;
    tidx[t * 2 + 0] = i0; tidx[t * 2 + 1] = i1;
    twt[t * 2 + 0] = 1.f / s; twt[t * 2 + 1] = e1 / s;
    atomicAdd(&counts[i0], 1);
    atomicAdd(&counts[i1], 1);
  }
}

// ---------------- weight convert+transpose: fp32 [R][C] -> bf16 [C][R] ----------------
#define TT 64
__global__ __launch_bounds__(256) void k_wcvt(const float* __restrict__ in,
                                              ushort_t* __restrict__ outp, int R, int C) {
  __shared__ float t[TT][TT + 1];
  int e = blockIdx.z;
  const float* src = in + (size_t)e * R * C;
  ushort_t* dst = outp + (size_t)e * R * C;
  int r0 = blockIdx.y * TT, c0 = blockIdx.x * TT;
  int tid = threadIdx.x;
  int rr = tid >> 4;
  int c4 = tid & 15;
#pragma unroll
  for (int i = 0; i < 4; i++) {
    int r = rr + i * 16;
    float4 v = *reinterpret_cast<const float4*>(src + (size_t)(r0 + r) * C + c0 + c4 * 4);
    t[r][c4 * 4 + 0] = v.x; t[r][c4 * 4 + 1] = v.y;
    t[r][c4 * 4 + 2] = v.z; t[r][c4 * 4 + 3] = v.w;
  }
  __syncthreads();
  int c = tid >> 2, rs = tid & 3;
  ushort8 v0, v1;
#pragma unroll
  for (int i = 0; i < 8; i++) {
    v0[i] = f2bf(t[rs * 16 + i][c]);
    v1[i] = f2bf(t[rs * 16 + 8 + i][c]);
  }
  ushort_t* drow = dst + (size_t)(c0 + c) * R + r0 + rs * 16;
  *reinterpret_cast<ushort8*>(drow) = v0;
  *reinterpret_cast<ushort8*>(drow + 8) = v1;
}

__global__ void k_scan(const int* __restrict__ counts, int* __restrict__ offsets) {
  if (threadIdx.x == 0) {
    int s = 0;
    for (int e = 0; e < NE; e++) { offsets[e] = s; s += counts[e]; }
    offsets[NE] = s;
  }
}

__global__ void k_fill(const int* __restrict__ tidx, const float* __restrict__ twt,
                       const int* __restrict__ offsets, int* __restrict__ cursors,
                       int* __restrict__ ltok, float* __restrict__ lwt, int* __restrict__ ppos) {
  int t = blockIdx.x * blockDim.x + threadIdx.x;
  if (t >= T_TOK) return;
#pragma unroll
  for (int k = 0; k < TOPK; k++) {
    int e = tidx[t * 2 + k];
    int pos = atomicAdd(&cursors[e], 1);
    int p = offsets[e] + pos;
    ltok[p] = t;
    lwt[p] = twt[t * 2 + k];
    ppos[t * 2 + k] = p;
  }
}

__device__ __forceinline__ void xcd_decode(int lin, int nwg, int nx, int& xt, int& yt) {
  int q = nwg >> 3;
  int w = (lin & 7) * q + (lin >> 3);
  xt = w % nx;
  yt = w / nx;
}

// ---------------- GEMM1: r6-proven (128x128xBK32, 2-barrier, XCD swizzle) ----------------
#define BM 128
#define BN 128
#define BK 32

__global__ __launch_bounds__(256) void k_gemm1(
    const ushort_t* __restrict__ xbf, const ushort_t* __restrict__ w1t, const float* __restrict__ b1,
    const int* __restrict__ counts, const int* __restrict__ offsets,
    const int* __restrict__ ltok, ushort_t* __restrict__ H) {
  int e = blockIdx.z;
  int cnt = counts[e];
  int xt, yt;
  xcd_decode(blockIdx.x, (T_TOK / BM) * (FFN / BN), T_TOK / BM, xt, yt);
  int row0 = xt * BM;
  if (row0 >= cnt) return;
  int base = offsets[e];
  int col0 = yt * BN;
  const ushort_t* Bt = w1t + (size_t)e * DIM * FFN;

  __shared__ __align__(16) ushort_t As[BM * BK];
  __shared__ __align__(16) ushort_t Bs[BM * BK];

  int tid = threadIdx.x;
  int wave = tid >> 6, lane = tid & 63;
  int wm = wave >> 1, wn = wave & 1;
  int lm = lane & 15, lg = lane >> 4;

  int srow = tid >> 2, seg = tid & 3;
  const ushort_t* asrc[2]; const ushort_t* bsrc[2];
#pragma unroll
  for (int j = 0; j < 2; j++) {
    int ar = min(row0 + j * 64 + srow, cnt - 1);
    asrc[j] = xbf + (size_t)ltok[base + ar] * DIM + seg * 8;
    bsrc[j] = Bt + (size_t)(col0 + j * 64 + srow) * DIM + seg * 8;
  }
  f32x4 acc[4][4];
#pragma unroll
  for (int m = 0; m < 4; m++)
#pragma unroll
    for (int n = 0; n < 4; n++) acc[m][n] = (f32x4){0.f, 0.f, 0.f, 0.f};

  for (int k0 = 0; k0 < DIM; k0 += BK) {
#pragma unroll
    for (int j = 0; j < 2; j++) {
      gload16(asrc[j] + k0, &As[(j * 256 + wave * 64) * 8]);
      gload16(bsrc[j] + k0, &Bs[(j * 256 + wave * 64) * 8]);
    }
    __syncthreads();
    bf16x8 af[4], bfv[4];
#pragma unroll
    for (int m = 0; m < 4; m++)
      af[m] = *reinterpret_cast<const bf16x8*>(&As[(wm * 64 + m * 16 + lm) * BK + lg * 8]);
#pragma unroll
    for (int n = 0; n < 4; n++)
      bfv[n] = *reinterpret_cast<const bf16x8*>(&Bs[(wn * 64 + n * 16 + lm) * BK + lg * 8]);
#pragma unroll
    for (int m = 0; m < 4; m++)
#pragma unroll
      for (int n = 0; n < 4; n++)
        acc[m][n] = __builtin_amdgcn_mfma_f32_16x16x32_bf16(af[m], bfv[n], acc[m][n], 0, 0, 0);
    __syncthreads();
  }
#pragma unroll
  for (int m = 0; m < 4; m++) {
#pragma unroll
    for (int n = 0; n < 4; n++) {
      int f = col0 + wn * 64 + n * 16 + lm;
      float bias = b1[e * FFN + f];
#pragma unroll
      for (int r = 0; r < 4; r++) {
        int row = row0 + wm * 64 + m * 16 + lg * 4 + r;
        if (row < cnt) {
          float v = acc[m][n][r] + bias;
          H[(size_t)(base + row) * FFN + f] = f2bf(gelu_exact(v));
        }
      }
    }
  }
}

// ======== GEMM2: 256x256xBK64, 8 waves, m201-style 4-phase/group pipeline ========
// LDS per op: [2 slot][2 half][128 rows x 64 k] bf16 = 64 KB; A+B = 128 KB.
// XOR swizzle (r7-verified 0-conflict): 16B-chunk c of row r holds logical c^(r&7);
// applied at stage SOURCE and ds_read offset; LDS dest linear.
// Group T (computes K-tile T from slot T&1), 4 phases (C-quadrants):
//  q0: read B(8)+A q0(4); stage A(T+1,h0)          -> bar -> lgkm0 -> 16 MFMA -> bar
//  q1: read A q1;         stage A(T+1,h1),B(T+2,h0)-> bar -> lgkm0 -> 16 MFMA -> bar
//  q2: read A q2;         stage B(T+2,h1)          -> bar -> lgkm0 -> 16 MFMA -> bar
//  q3: read A q3;                                  -> bar -> lgkm0 -> 16 MFMA -> vmcnt(4) -> bar
// vmcnt(4) leaves exactly B(T+2) (newest 4 loads) in flight; in-order retirement
// guarantees A(T+1) and B(T+1) landed. Write-after-read safety: B(T+2) overwrites
// B(T), whose only reads (q0) complete before the q0-end barrier; A(T+1) overwrites
// A(T-1), fully read by group T-1's q3-end barrier.
#define QBM 256
#define QBN 256
#define QBK 64
#define QHALF_E (128 * 64)
#define QSLOT_E (2 * QHALF_E)

__global__ __launch_bounds__(512) void k_gemm2(
    const ushort_t* __restrict__ H, const ushort_t* __restrict__ w2t, const float* __restrict__ b2,
    const int* __restrict__ counts, const int* __restrict__ offsets,
    const float* __restrict__ lwt, ushort_t* __restrict__ contrib) {
  int e = blockIdx.z;
  int cnt = counts[e];
  int xt, yt;
  xcd_decode(blockIdx.x, (T_TOK / QBM) * (DIM / QBN), T_TOK / QBM, xt, yt);
  int row0 = xt * QBM;
  if (row0 >= cnt) return;
  int base = offsets[e];
  int col0 = yt * QBN;
  const ushort_t* Bt = w2t + (size_t)e * DIM * FFN;

  __shared__ __align__(16) ushort_t As[2 * QSLOT_E];
  __shared__ __align__(16) ushort_t Bs[2 * QSLOT_E];

  int tid = threadIdx.x;
  int wid = tid >> 6, lane = tid & 63;
  int wm = wid >> 2, wn = wid & 3;        // 2x4 waves; wave tile 128x64
  int lm = lane & 15, lg = lane >> 4;

  // staging sources (pre-swizzled): chunk c = l*512+tid; row=c>>3; src seg=(c&7)^(row&7)
  const ushort_t* aS[2][2]; const ushort_t* bS[2][2];
#pragma unroll
  for (int l = 0; l < 2; l++) {
    int c = l * 512 + tid;
    int rr = c >> 3;
    int s8 = (c & 7) ^ (rr & 7);
#pragma unroll
    for (int h = 0; h < 2; h++) {
      int ar = min(row0 + h * 128 + rr, cnt - 1);
      aS[h][l] = H + (size_t)(base + ar) * FFN + s8 * 8;
      bS[h][l] = Bt + (size_t)(col0 + h * 128 + rr) * FFN + s8 * 8;
    }
  }
  auto STA = [&](int slot, int h, int k0) {
#pragma unroll
    for (int l = 0; l < 2; l++)
      gload16(aS[h][l] + k0, As + slot * QSLOT_E + h * QHALF_E + (l * 512 + wid * 64) * 8);
  };
  auto STB = [&](int slot, int h, int k0) {
#pragma unroll
    for (int l = 0; l < 2; l++)
      gload16(bS[h][l] + k0, Bs + slot * QSLOT_E + h * QHALF_E + (l * 512 + wid * 64) * 8);
  };

  unsigned abase = lds_off(As), bbase = lds_off(Bs);
  unsigned aoff[8][2], boff[4][2];
#pragma unroll
  for (int m = 0; m < 8; m++)
#pragma unroll
    for (int kk = 0; kk < 2; kk++)
      aoff[m][kk] = abase + (unsigned)((wm * QHALF_E + (m * 16 + lm) * 64 +
                                        (((kk * 4 + lg) ^ (lm & 7)) * 8)) * 2);
#pragma unroll
  for (int n = 0; n < 4; n++)
#pragma unroll
    for (int kk = 0; kk < 2; kk++)
      boff[n][kk] = bbase + (unsigned)(((wn >> 1) * QHALF_E + ((wn & 1) * 64 + n * 16 + lm) * 64 +
                                        (((kk * 4 + lg) ^ (lm & 7)) * 8)) * 2);

  f32x4 acc[8][4];
#pragma unroll
  for (int m = 0; m < 8; m++)
#pragma unroll
    for (int n = 0; n < 4; n++) acc[m][n] = (f32x4){0.f, 0.f, 0.f, 0.f};

  const int NT = FFN / QBK;   // 128 groups
  // prologue: A(0) both halves, B(0) both halves, B(1) both halves (12 loads)
  STA(0, 0, 0); STA(0, 1, 0);
  STB(0, 0, 0); STB(0, 1, 0);
  STB(1, 0, QBK); STB(1, 1, QBK);
  asm volatile("s_waitcnt vmcnt(4)" ::: "memory");   // A(0),B(0) landed; B(1) in flight
  __builtin_amdgcn_s_barrier();

  for (int T = 0; T < NT; ++T) {
    int slot = T & 1;
    unsigned cb = (unsigned)(slot * QSLOT_E * 2);
    bf16x8 bv[4][2];
#pragma unroll
    for (int q = 0; q < 4; q++) {
      bf16x8 af[2][2];
      if (q == 0) {
#pragma unroll
        for (int n = 0; n < 4; n++)
#pragma unroll
          for (int kk = 0; kk < 2; kk++) bv[n][kk] = ds_read128(boff[n][kk] + cb);
      }
#pragma unroll
      for (int mf = 0; mf < 2; mf++)
#pragma unroll
        for (int kk = 0; kk < 2; kk++)
          af[mf][kk] = ds_read128(aoff[q * 2 + mf][kk] + cb);
      if (q == 0 && T + 1 < NT) STA(slot ^ 1, 0, (T + 1) * QBK);
      if (q == 1) {
        if (T + 1 < NT) STA(slot ^ 1, 1, (T + 1) * QBK);
        if (T + 2 < NT) STB(slot, 0, (T + 2) * QBK);
      }
      if (q == 2 && T + 2 < NT) STB(slot, 1, (T + 2) * QBK);
      __builtin_amdgcn_sched_barrier(0);
      __builtin_amdgcn_s_barrier();
      asm volatile("s_waitcnt lgkmcnt(0)" ::: "memory");
      __builtin_amdgcn_sched_barrier(0);
      __builtin_amdgcn_s_setprio(1);
#pragma unroll
      for (int mf = 0; mf < 2; mf++)
#pragma unroll
        for (int nf = 0; nf < 4; nf++)
#pragma unroll
          for (int kk = 0; kk < 2; kk++)
            acc[q * 2 + mf][nf] = __builtin_amdgcn_mfma_f32_16x16x32_bf16(
                af[mf][kk], bv[nf][kk], acc[q * 2 + mf][nf], 0, 0, 0);
      __builtin_amdgcn_s_setprio(0);
      __builtin_amdgcn_sched_barrier(0);
      if (q == 3) {
        if (T < NT - 2) { asm volatile("s_waitcnt vmcnt(4)" ::: "memory"); }
        else            { asm volatile("s_waitcnt vmcnt(0)" ::: "memory"); }
        __builtin_amdgcn_sched_barrier(0);
      }
      __builtin_amdgcn_s_barrier();
      __builtin_amdgcn_sched_barrier(0);
    }
  }

  // epilogue
#pragma unroll
  for (int m = 0; m < 8; m++) {
#pragma unroll
    for (int n = 0; n < 4; n++) {
      int d = col0 + wn * 64 + n * 16 + lm;
      float bias = b2[e * DIM + d];
#pragma unroll
      for (int r = 0; r < 4; r++) {
        int row = row0 + wm * 128 + m * 16 + lg * 4 + r;
        if (row < cnt) {
          float v = (acc[m][n][r] + bias) * lwt[base + row];
          contrib[(size_t)(base + row) * DIM + d] = f2bf(v);
        }
      }
    }
  }
}

// ---------------- combine: out = x + contrib[p0] + contrib[p1] ----------------
__global__ void k_combine(const float* __restrict__ x, const ushort_t* __restrict__ contrib,
                          const int* __restrict__ ppos, float* __restrict__ out) {
  int i = blockIdx.x * blockDim.x + threadIdx.x;
  int t = i / (DIM / 4);
  int dq = i % (DIM / 4);
  int p0 = ppos[t * 2 + 0], p1 = ppos[t * 2 + 1];
  float4 xv = reinterpret_cast<const float4*>(x)[i];
  ushort4v c0 = reinterpret_cast<const ushort4v*>(contrib + (size_t)p0 * DIM)[dq];
  ushort4v c1 = reinterpret_cast<const ushort4v*>(contrib + (size_t)p1 * DIM)[dq];
  float4 o;
  o.x = xv.x + bf2f(c0.x) + bf2f(c1.x);
  o.y = xv.y + bf2f(c0.y) + bf2f(c1.y);
  o.z = xv.z + bf2f(c0.z) + bf2f(c1.z);
  o.w = xv.w + bf2f(c0.w) + bf2f(c1.w);
  reinterpret_cast<float4*>(out)[i] = o;
}

extern "C" void kernel_launch(void* const* d_in, const int* in_sizes, int n_in,
                              void* d_out, int out_size, void* d_ws, size_t ws_size,
                              hipStream_t stream) {
  const float* x  = (const float*)d_in[0];
  const float* rw = (const float*)d_in[1];
  const float* w1 = (const float*)d_in[2];
  const float* b1 = (const float*)d_in[3];
  const float* w2 = (const float*)d_in[4];
  const float* b2 = (const float*)d_in[5];
  float* out = (float*)d_out;
  char* ws = (char*)d_ws;

  const size_t MB = 1u << 20;
  int*   counts  = (int*)(ws);
  int*   offsets = (int*)(ws + 64);
  int*   cursors = (int*)(ws + 128);
  int*   tidx    = (int*)(ws + 1 * MB);
  float* twt     = (float*)(ws + 2 * MB);
  int*   ltok    = (int*)(ws + 3 * MB);
  float* lwt     = (float*)(ws + 4 * MB);
  int*   ppos    = (int*)(ws + 5 * MB);
  // overlaid big buffers (lifetimes disjoint where they overlap):
  ushort_t* xbf     = (ushort_t*)(ws + 8 * MB);     // 32 MB, live router..gemm1
  ushort_t* contrib = (ushort_t*)(ws + 8 * MB);     // 64 MB, live gemm2..combine (xbf dead)
  ushort_t* Hbuf    = (ushort_t*)(ws + 72 * MB);    // 256 MB, live gemm1..gemm2
  ushort_t* w1t     = (ushort_t*)(ws + 328 * MB);   // 256 MB, live wcvt1..gemm1
  ushort_t* w2t     = (ushort_t*)(ws + 328 * MB);   // 256 MB, live wcvt2..gemm2 (after gemm1)
  const size_t NEED = 584 * MB;
  if (ws_size < NEED) {
    hipMemsetAsync(d_out, 0, (size_t)out_size * sizeof(float), stream);
    return;
  }

  hipMemsetAsync(ws, 0, 256, stream);  // counts + cursors
  k_router<<<T_TOK, 256, 0, stream>>>(x, rw, xbf, tidx, twt, counts);
  k_scan<<<1, 64, 0, stream>>>(counts, offsets);
  k_fill<<<T_TOK / 256, 256, 0, stream>>>(tidx, twt, offsets, cursors, ltok, lwt, ppos);
  // w1: [E][D][F] fp32 -> w1t [E][F][D] bf16
  k_wcvt<<<dim3(FFN / TT, DIM / TT, NE), 256, 0, stream>>>(w1, w1t, DIM, FFN);
  k_gemm1<<<dim3((T_TOK / BM) * (FFN / BN), 1, NE), 256, 0, stream>>>(xbf, w1t, b1, counts, offsets, ltok, Hbuf);
  // w2: [E][F][D] fp32 -> w2t [E][D][F] bf16  (after gemm1; reuses w1t region)
  k_wcvt<<<dim3(DIM / TT, FFN / TT, NE), 256, 0, stream>>>(w2, w2t, FFN, DIM);
  k_gemm2<<<dim3((T_TOK / QBM) * (DIM / QBN), 1, NE), 512, 0, stream>>>(Hbuf, w2t, b2, counts, offsets, lwt, contrib);
  k_combine<<<dim3((T_TOK * (size_t)DIM / 4) / 256), 256, 0, stream>>>(x, contrib, ppos, out);
}

// Round 15
// 1999.716 us; speedup vs baseline: 1.8571x; 1.0605x over previous
//
#include <hip/hip_runtime.h>

// MoE block: B=4,S=2048 -> T=8192 tokens, D=2048, F=8192, E=8, K=2
#define T_TOK 8192
#define DIM   2048
#define FFN   8192
#define NE    8
#define TOPK  2

typedef unsigned short ushort_t;
typedef unsigned short ushort8  __attribute__((ext_vector_type(8)));
typedef unsigned short ushort4v __attribute__((ext_vector_type(4)));
typedef short bf16x8 __attribute__((ext_vector_type(8)));
typedef float f32x4  __attribute__((ext_vector_type(4)));

__device__ __forceinline__ ushort_t f2bf(float f) {
  unsigned int u = __float_as_uint(f);
  u += 0x7FFFu + ((u >> 16) & 1u);   // RNE
  return (ushort_t)(u >> 16);
}
__device__ __forceinline__ float bf2f(ushort_t u) {
  return __uint_as_float(((unsigned int)u) << 16);
}

// async global->LDS, 16B per lane. LDS dest wave-uniform base; HW adds lane*16.
__device__ __forceinline__ void gload16(const void* g, void* l) {
  __builtin_amdgcn_global_load_lds((const __attribute__((address_space(1))) void*)g,
                                   (__attribute__((address_space(3))) void*)l, 16, 0, 0);
}
__device__ __forceinline__ unsigned lds_off(const ushort_t* p) {
  return (unsigned)(uintptr_t)(__attribute__((address_space(3))) const ushort_t*)p;
}
// invisible LDS read: no compiler-inserted vmcnt drain before it
__device__ __forceinline__ bf16x8 ds_read128(unsigned off) {
  bf16x8 r;
  asm volatile("ds_read_b128 %0, %1" : "=v"(r) : "v"(off));
  return r;
}

// exact-erf GELU via Abramowitz-Stegun 7.1.26 (|err| <= 1.5e-7)
__device__ __forceinline__ float gelu_exact(float v) {
  float s = v * 0.70710678118654752f;
  float a = fabsf(s);
  float t = __builtin_amdgcn_rcpf(1.0f + 0.3275911f * a);
  float p = t * (0.254829592f +
            t * (-0.284496736f +
            t * (1.421413741f +
            t * (-1.453152027f +
            t * 1.061405429f))));
  float er = 1.0f - p * __expf(-a * a);
  er = copysignf(er, s);
  return 0.5f * v * (1.0f + er);
}

// ---------------- router + fused x->bf16 cast ----------------
__global__ __launch_bounds__(256) void k_router(
    const float* __restrict__ x, const float* __restrict__ rw, ushort_t* __restrict__ xbf,
    int* __restrict__ tidx, float* __restrict__ twt, int* __restrict__ counts) {
  int t = blockIdx.x;
  int tid = threadIdx.x;
  int lane = tid & 63, wave = tid >> 6;
  float acc[NE];
#pragma unroll
  for (int e = 0; e < NE; e++) acc[e] = 0.f;
  const float* xr = x + (size_t)t * DIM;
  ushort_t* xbr = xbf + (size_t)t * DIM;
#pragma unroll
  for (int it = 0; it < 2; it++) {
    int d4 = it * 1024 + tid * 4;
    float4 v = *reinterpret_cast<const float4*>(xr + d4);
    ushort4v o;
    o.x = f2bf(v.x); o.y = f2bf(v.y); o.z = f2bf(v.z); o.w = f2bf(v.w);
    *reinterpret_cast<ushort4v*>(xbr + d4) = o;
    const float* r0p = rw + (size_t)d4 * NE;
    float xv[4] = {v.x, v.y, v.z, v.w};
#pragma unroll
    for (int j = 0; j < 4; j++) {
      const float* r = r0p + j * NE;
#pragma unroll
      for (int e = 0; e < NE; e++) acc[e] += xv[j] * r[e];
    }
  }
  __shared__ float wsum[4][NE];
#pragma unroll
  for (int e = 0; e < NE; e++) {
    float v = acc[e];
#pragma unroll
    for (int off = 32; off > 0; off >>= 1) v += __shfl_down(v, off);
    if (lane == 0) wsum[wave][e] = v;
  }
  __syncthreads();
  if (tid == 0) {
    float lg[NE];
#pragma unroll
    for (int e = 0; e < NE; e++) lg[e] = wsum[0][e] + wsum[1][e] + wsum[2][e] + wsum[3][e];
    int i0 = 0; float v0 = lg[0];
#pragma unroll
    for (int e = 1; e < NE; e++) if (lg[e] > v0) { v0 = lg[e]; i0 = e; }
    int i1 = -1; float v1 = -3.4e38f;
#pragma unroll
    for (int e = 0; e < NE; e++) if (e != i0 && lg[e] > v1) { v1 = lg[e]; i1 = e; }
    float e1 = expf(v1 - v0);
    float s = 1.f + e1;
    tidx[t * 2 + 0] = i0; tidx[t * 2 + 1] = i1;
    twt[t * 2 + 0] = 1.f / s; twt[t * 2 + 1] = e1 / s;
    atomicAdd(&counts[i0], 1);
    atomicAdd(&counts[i1], 1);
  }
}

// ---------------- weight convert+transpose: fp32 [R][C] -> bf16 [C][R] ----------------
#define TT 64
__global__ __launch_bounds__(256) void k_wcvt(const float* __restrict__ in,
                                              ushort_t* __restrict__ outp, int R, int C) {
  __shared__ float t[TT][TT + 1];
  int e = blockIdx.z;
  const float* src = in + (size_t)e * R * C;
  ushort_t* dst = outp + (size_t)e * R * C;
  int r0 = blockIdx.y * TT, c0 = blockIdx.x * TT;
  int tid = threadIdx.x;
  int rr = tid >> 4;
  int c4 = tid & 15;
#pragma unroll
  for (int i = 0; i < 4; i++) {
    int r = rr + i * 16;
    float4 v = *reinterpret_cast<const float4*>(src + (size_t)(r0 + r) * C + c0 + c4 * 4);
    t[r][c4 * 4 + 0] = v.x; t[r][c4 * 4 + 1] = v.y;
    t[r][c4 * 4 + 2] = v.z; t[r][c4 * 4 + 3] = v.w;
  }
  __syncthreads();
  int c = tid >> 2, rs = tid & 3;
  ushort8 v0, v1;
#pragma unroll
  for (int i = 0; i < 8; i++) {
    v0[i] = f2bf(t[rs * 16 + i][c]);
    v1[i] = f2bf(t[rs * 16 + 8 + i][c]);
  }
  ushort_t* drow = dst + (size_t)(c0 + c) * R + r0 + rs * 16;
  *reinterpret_cast<ushort8*>(drow) = v0;
  *reinterpret_cast<ushort8*>(drow + 8) = v1;
}

__global__ void k_scan(const int* __restrict__ counts, int* __restrict__ offsets) {
  if (threadIdx.x == 0) {
    int s = 0;
    for (int e = 0; e < NE; e++) { offsets[e] = s; s += counts[e]; }
    offsets[NE] = s;
  }
}

__global__ void k_fill(const int* __restrict__ tidx, const float* __restrict__ twt,
                       const int* __restrict__ offsets, int* __restrict__ cursors,
                       int* __restrict__ ltok, float* __restrict__ lwt, int* __restrict__ ppos) {
  int t = blockIdx.x * blockDim.x + threadIdx.x;
  if (t >= T_TOK) return;
#pragma unroll
  for (int k = 0; k < TOPK; k++) {
    int e = tidx[t * 2 + k];
    int pos = atomicAdd(&cursors[e], 1);
    int p = offsets[e] + pos;
    ltok[p] = t;
    lwt[p] = twt[t * 2 + k];
    ppos[t * 2 + k] = p;
  }
}

__device__ __forceinline__ void xcd_decode(int lin, int nwg, int nx, int& xt, int& yt) {
  int q = nwg >> 3;
  int w = (lin & 7) * q + (lin >> 3);
  xt = w % nx;
  yt = w / nx;
}

// ======== 8-phase 256x256xBK64 GEMM pipeline (r14-proven on gemm2) ========
// LDS per op: [2 slot][2 half][128 rows x 64 k] bf16 = 64 KB; A+B = 128 KB.
// XOR swizzle: 16B-chunk c of row r holds logical c^(r&7), pre-swizzled source,
// swizzled ds_read offset, linear LDS dest.
// Group T, 4 phases (C-quadrants):
//  q0: read B(8)+A q0(4); stage A(T+1,h0)           -> bar -> lgkm0 -> 16 MFMA -> bar
//  q1: read A q1;         stage A(T+1,h1),B(T+2,h0) -> bar -> lgkm0 -> 16 MFMA -> bar
//  q2: read A q2;         stage B(T+2,h1)           -> bar -> lgkm0 -> 16 MFMA -> bar
//  q3: read A q3;                                   -> bar -> lgkm0 -> 16 MFMA -> vmcnt(4) -> bar
#define QBM 256
#define QBN 256
#define QBK 64
#define QHALF_E (128 * 64)
#define QSLOT_E (2 * QHALF_E)

// The full pipeline body, parameterized over NT; acc left in registers.
#define GEMM8_PIPE(NT_)                                                                 \
  const int NT = (NT_);                                                                 \
  STA(0, 0, 0); STA(0, 1, 0);                                                           \
  STB(0, 0, 0); STB(0, 1, 0);                                                           \
  STB(1, 0, QBK); STB(1, 1, QBK);                                                       \
  asm volatile("s_waitcnt vmcnt(4)" ::: "memory");                                      \
  __builtin_amdgcn_s_barrier();                                                         \
  for (int T = 0; T < NT; ++T) {                                                        \
    int slot = T & 1;                                                                   \
    unsigned cb = (unsigned)(slot * QSLOT_E * 2);                                       \
    bf16x8 bv[4][2];                                                                    \
    _Pragma("unroll")                                                                   \
    for (int q = 0; q < 4; q++) {                                                       \
      bf16x8 af[2][2];                                                                  \
      if (q == 0) {                                                                     \
        _Pragma("unroll")                                                               \
        for (int n = 0; n < 4; n++) {                                                   \
          bv[n][0] = ds_read128(boff[n][0] + cb);                                       \
          bv[n][1] = ds_read128(boff[n][1] + cb);                                       \
        }                                                                               \
      }                                                                                 \
      _Pragma("unroll")                                                                 \
      for (int mf = 0; mf < 2; mf++) {                                                  \
        af[mf][0] = ds_read128(aoff[q * 2 + mf][0] + cb);                               \
        af[mf][1] = ds_read128(aoff[q * 2 + mf][1] + cb);                               \
      }                                                                                 \
      if (q == 0 && T + 1 < NT) STA(slot ^ 1, 0, (T + 1) * QBK);                        \
      if (q == 1) {                                                                     \
        if (T + 1 < NT) STA(slot ^ 1, 1, (T + 1) * QBK);                                \
        if (T + 2 < NT) STB(slot, 0, (T + 2) * QBK);                                    \
      }                                                                                 \
      if (q == 2 && T + 2 < NT) STB(slot, 1, (T + 2) * QBK);                            \
      __builtin_amdgcn_sched_barrier(0);                                                \
      __builtin_amdgcn_s_barrier();                                                     \
      asm volatile("s_waitcnt lgkmcnt(0)" ::: "memory");                                \
      __builtin_amdgcn_sched_barrier(0);                                                \
      __builtin_amdgcn_s_setprio(1);                                                    \
      _Pragma("unroll")                                                                 \
      for (int mf = 0; mf < 2; mf++)                                                    \
        _Pragma("unroll")                                                               \
        for (int nf = 0; nf < 4; nf++) {                                                \
          acc[q * 2 + mf][nf] = __builtin_amdgcn_mfma_f32_16x16x32_bf16(                \
              af[mf][0], bv[nf][0], acc[q * 2 + mf][nf], 0, 0, 0);                      \
          acc[q * 2 + mf][nf] = __builtin_amdgcn_mfma_f32_16x16x32_bf16(                \
              af[mf][1], bv[nf][1], acc[q * 2 + mf][nf], 0, 0, 0);                      \
        }                                                                               \
      __builtin_amdgcn_s_setprio(0);                                                    \
      __builtin_amdgcn_sched_barrier(0);                                                \
      if (q == 3) {                                                                     \
        if (T < NT - 2) { asm volatile("s_waitcnt vmcnt(4)" ::: "memory"); }            \
        else            { asm volatile("s_waitcnt vmcnt(0)" ::: "memory"); }            \
        __builtin_amdgcn_sched_barrier(0);                                              \
      }                                                                                 \
      __builtin_amdgcn_s_barrier();                                                     \
      __builtin_amdgcn_sched_barrier(0);                                                \
    }                                                                                   \
  }

// common per-thread setup for the 8-phase kernels
#define GEMM8_SETUP()                                                                   \
  int tid = threadIdx.x;                                                                \
  int wid = tid >> 6, lane = tid & 63;                                                  \
  int wm = wid >> 2, wn = wid & 3;                                                      \
  int lm = lane & 15, lg = lane >> 4;                                                   \
  unsigned abase = lds_off(As), bbase = lds_off(Bs);                                    \
  unsigned aoff[8][2], boff[4][2];                                                      \
  _Pragma("unroll")                                                                     \
  for (int m = 0; m < 8; m++)                                                           \
    _Pragma("unroll")                                                                   \
    for (int kk = 0; kk < 2; kk++)                                                      \
      aoff[m][kk] = abase + (unsigned)((wm * QHALF_E + (m * 16 + lm) * 64 +             \
                                        (((kk * 4 + lg) ^ (lm & 7)) * 8)) * 2);         \
  _Pragma("unroll")                                                                     \
  for (int n = 0; n < 4; n++)                                                           \
    _Pragma("unroll")                                                                   \
    for (int kk = 0; kk < 2; kk++)                                                      \
      boff[n][kk] = bbase + (unsigned)(((wn >> 1) * QHALF_E +                           \
                                        ((wn & 1) * 64 + n * 16 + lm) * 64 +            \
                                        (((kk * 4 + lg) ^ (lm & 7)) * 8)) * 2);         \
  f32x4 acc[8][4];                                                                      \
  _Pragma("unroll")                                                                     \
  for (int m = 0; m < 8; m++)                                                           \
    _Pragma("unroll")                                                                   \
    for (int n = 0; n < 4; n++) acc[m][n] = (f32x4){0.f, 0.f, 0.f, 0.f};

// GEMM1: H[p,f] = gelu( gather(x)[p,:] @ w1t[e]^T + b1[e] )   w1t: [F][D] bf16
__global__ __launch_bounds__(512) void k_gemm1(
    const ushort_t* __restrict__ xbf, const ushort_t* __restrict__ w1t, const float* __restrict__ b1,
    const int* __restrict__ counts, const int* __restrict__ offsets,
    const int* __restrict__ ltok, ushort_t* __restrict__ H) {
  int e = blockIdx.z;
  int cnt = counts[e];
  int xt, yt;
  xcd_decode(blockIdx.x, (T_TOK / QBM) * (FFN / QBN), T_TOK / QBM, xt, yt);
  int row0 = xt * QBM;
  if (row0 >= cnt) return;
  int base = offsets[e];
  int col0 = yt * QBN;
  const ushort_t* Bt = w1t + (size_t)e * DIM * FFN;

  __shared__ __align__(16) ushort_t As[2 * QSLOT_E];
  __shared__ __align__(16) ushort_t Bs[2 * QSLOT_E];

  // staging sources (pre-swizzled)
  const ushort_t* aS[2][2]; const ushort_t* bS[2][2];
#pragma unroll
  for (int l = 0; l < 2; l++) {
    int c = l * 512 + threadIdx.x;
    int rr = c >> 3;
    int s8 = (c & 7) ^ (rr & 7);
#pragma unroll
    for (int h = 0; h < 2; h++) {
      int ar = min(row0 + h * 128 + rr, cnt - 1);
      aS[h][l] = xbf + (size_t)ltok[base + ar] * DIM + s8 * 8;
      bS[h][l] = Bt + (size_t)(col0 + h * 128 + rr) * DIM + s8 * 8;
    }
  }
  int swid = threadIdx.x >> 6;
  auto STA = [&](int slot, int h, int k0) {
#pragma unroll
    for (int l = 0; l < 2; l++)
      gload16(aS[h][l] + k0, As + slot * QSLOT_E + h * QHALF_E + (l * 512 + swid * 64) * 8);
  };
  auto STB = [&](int slot, int h, int k0) {
#pragma unroll
    for (int l = 0; l < 2; l++)
      gload16(bS[h][l] + k0, Bs + slot * QSLOT_E + h * QHALF_E + (l * 512 + swid * 64) * 8);
  };

  GEMM8_SETUP();
  GEMM8_PIPE(DIM / QBK);

  // epilogue
#pragma unroll
  for (int m = 0; m < 8; m++) {
#pragma unroll
    for (int n = 0; n < 4; n++) {
      int f = col0 + wn * 64 + n * 16 + lm;
      float bias = b1[e * FFN + f];
#pragma unroll
      for (int r = 0; r < 4; r++) {
        int row = row0 + wm * 128 + m * 16 + lg * 4 + r;
        if (row < cnt) {
          float v = acc[m][n][r] + bias;
          H[(size_t)(base + row) * FFN + f] = f2bf(gelu_exact(v));
        }
      }
    }
  }
}

// GEMM2: contrib[p,d] = cw[p] * ( H[p,:] @ w2t[e]^T + b2[e] )   w2t: [D][F] bf16
__global__ __launch_bounds__(512) void k_gemm2(
    const ushort_t* __restrict__ H, const ushort_t* __restrict__ w2t, const float* __restrict__ b2,
    const int* __restrict__ counts, const int* __restrict__ offsets,
    const float* __restrict__ lwt, ushort_t* __restrict__ contrib) {
  int e = blockIdx.z;
  int cnt = counts[e];
  int xt, yt;
  xcd_decode(blockIdx.x, (T_TOK / QBM) * (DIM / QBN), T_TOK / QBM, xt, yt);
  int row0 = xt * QBM;
  if (row0 >= cnt) return;
  int base = offsets[e];
  int col0 = yt * QBN;
  const ushort_t* Bt = w2t + (size_t)e * DIM * FFN;

  __shared__ __align__(16) ushort_t As[2 * QSLOT_E];
  __shared__ __align__(16) ushort_t Bs[2 * QSLOT_E];

  const ushort_t* aS[2][2]; const ushort_t* bS[2][2];
#pragma unroll
  for (int l = 0; l < 2; l++) {
    int c = l * 512 + threadIdx.x;
    int rr = c >> 3;
    int s8 = (c & 7) ^ (rr & 7);
#pragma unroll
    for (int h = 0; h < 2; h++) {
      int ar = min(row0 + h * 128 + rr, cnt - 1);
      aS[h][l] = H + (size_t)(base + ar) * FFN + s8 * 8;
      bS[h][l] = Bt + (size_t)(col0 + h * 128 + rr) * FFN + s8 * 8;
    }
  }
  int swid = threadIdx.x >> 6;
  auto STA = [&](int slot, int h, int k0) {
#pragma unroll
    for (int l = 0; l < 2; l++)
      gload16(aS[h][l] + k0, As + slot * QSLOT_E + h * QHALF_E + (l * 512 + swid * 64) * 8);
  };
  auto STB = [&](int slot, int h, int k0) {
#pragma unroll
    for (int l = 0; l < 2; l++)
      gload16(bS[h][l] + k0, Bs + slot * QSLOT_E + h * QHALF_E + (l * 512 + swid * 64) * 8);
  };

  GEMM8_SETUP();
  GEMM8_PIPE(FFN / QBK);

  // epilogue
#pragma unroll
  for (int m = 0; m < 8; m++) {
#pragma unroll
    for (int n = 0; n < 4; n++) {
      int d = col0 + wn * 64 + n * 16 + lm;
      float bias = b2[e * DIM + d];
#pragma unroll
      for (int r = 0; r < 4; r++) {
        int row = row0 + wm * 128 + m * 16 + lg * 4 + r;
        if (row < cnt) {
          float v = (acc[m][n][r] + bias) * lwt[base + row];
          contrib[(size_t)(base + row) * DIM + d] = f2bf(v);
        }
      }
    }
  }
}

// ---------------- combine: out = x + contrib[p0] + contrib[p1] ----------------
__global__ void k_combine(const float* __restrict__ x, const ushort_t* __restrict__ contrib,
                          const int* __restrict__ ppos, float* __restrict__ out) {
  int i = blockIdx.x * blockDim.x + threadIdx.x;
  int t = i / (DIM / 4);
  int dq = i % (DIM / 4);
  int p0 = ppos[t * 2 + 0], p1 = ppos[t * 2 + 1];
  float4 xv = reinterpret_cast<const float4*>(x)[i];
  ushort4v c0 = reinterpret_cast<const ushort4v*>(contrib + (size_t)p0 * DIM)[dq];
  ushort4v c1 = reinterpret_cast<const ushort4v*>(contrib + (size_t)p1 * DIM)[dq];
  float4 o;
  o.x = xv.x + bf2f(c0.x) + bf2f(c1.x);
  o.y = xv.y + bf2f(c0.y) + bf2f(c1.y);
  o.z = xv.z + bf2f(c0.z) + bf2f(c1.z);
  o.w = xv.w + bf2f(c0.w) + bf2f(c1.w);
  reinterpret_cast<float4*>(out)[i] = o;
}

extern "C" void kernel_launch(void* const* d_in, const int* in_sizes, int n_in,
                              void* d_out, int out_size, void* d_ws, size_t ws_size,
                              hipStream_t stream) {
  const float* x  = (const float*)d_in[0];
  const float* rw = (const float*)d_in[1];
  const float* w1 = (const float*)d_in[2];
  const float* b1 = (const float*)d_in[3];
  const float* w2 = (const float*)d_in[4];
  const float* b2 = (const float*)d_in[5];
  float* out = (float*)d_out;
  char* ws = (char*)d_ws;

  const size_t MB = 1u << 20;
  int*   counts  = (int*)(ws);
  int*   offsets = (int*)(ws + 64);
  int*   cursors = (int*)(ws + 128);
  int*   tidx    = (int*)(ws + 1 * MB);
  float* twt     = (float*)(ws + 2 * MB);
  int*   ltok    = (int*)(ws + 3 * MB);
  float* lwt     = (float*)(ws + 4 * MB);
  int*   ppos    = (int*)(ws + 5 * MB);
  // overlaid big buffers (lifetimes disjoint where they overlap):
  ushort_t* xbf     = (ushort_t*)(ws + 8 * MB);     // 32 MB, live router..gemm1
  ushort_t* contrib = (ushort_t*)(ws + 8 * MB);     // 64 MB, live gemm2..combine (xbf dead)
  ushort_t* Hbuf    = (ushort_t*)(ws + 72 * MB);    // 256 MB, live gemm1..gemm2
  ushort_t* w1t     = (ushort_t*)(ws + 328 * MB);   // 256 MB, live wcvt1..gemm1
  ushort_t* w2t     = (ushort_t*)(ws + 328 * MB);   // 256 MB, live wcvt2..gemm2 (after gemm1)
  const size_t NEED = 584 * MB;
  if (ws_size < NEED) {
    hipMemsetAsync(d_out, 0, (size_t)out_size * sizeof(float), stream);
    return;
  }

  hipMemsetAsync(ws, 0, 256, stream);  // counts + cursors
  k_router<<<T_TOK, 256, 0, stream>>>(x, rw, xbf, tidx, twt, counts);
  k_scan<<<1, 64, 0, stream>>>(counts, offsets);
  k_fill<<<T_TOK / 256, 256, 0, stream>>>(tidx, twt, offsets, cursors, ltok, lwt, ppos);
  // w1: [E][D][F] fp32 -> w1t [E][F][D] bf16
  k_wcvt<<<dim3(FFN / TT, DIM / TT, NE), 256, 0, stream>>>(w1, w1t, DIM, FFN);
  k_gemm1<<<dim3((T_TOK / QBM) * (FFN / QBN), 1, NE), 512, 0, stream>>>(xbf, w1t, b1, counts, offsets, ltok, Hbuf);
  // w2: [E][F][D] fp32 -> w2t [E][D][F] bf16  (after gemm1; reuses w1t region)
  k_wcvt<<<dim3(DIM / TT, FFN / TT, NE), 256, 0, stream>>>(w2, w2t, FFN, DIM);
  k_gemm2<<<dim3((T_TOK / QBM) * (DIM / QBN), 1, NE), 512, 0, stream>>>(Hbuf, w2t, b2, counts, offsets, lwt, contrib);
  k_combine<<<dim3((T_TOK * (size_t)DIM / 4) / 256), 256, 0, stream>>>(x, contrib, ppos, out);
}

// Round 16
// 1890.271 us; speedup vs baseline: 1.9646x; 1.0579x over previous
//
#include <hip/hip_runtime.h>

// MoE block: B=4,S=2048 -> T=8192 tokens, D=2048, F=8192, E=8, K=2
#define T_TOK 8192
#define DIM   2048
#define FFN   8192
#define NE    8
#define TOPK  2

typedef unsigned short ushort_t;
typedef unsigned short ushort8  __attribute__((ext_vector_type(8)));
typedef unsigned short ushort4v __attribute__((ext_vector_type(4)));
typedef short bf16x8 __attribute__((ext_vector_type(8)));
typedef float f32x4  __attribute__((ext_vector_type(4)));

__device__ __forceinline__ ushort_t f2bf(float f) {
  unsigned int u = __float_as_uint(f);
  u += 0x7FFFu + ((u >> 16) & 1u);   // RNE
  return (ushort_t)(u >> 16);
}
__device__ __forceinline__ float bf2f(ushort_t u) {
  return __uint_as_float(((unsigned int)u) << 16);
}

// async global->LDS, 16B per lane. LDS dest wave-uniform base; HW adds lane*16.
__device__ __forceinline__ void gload16(const void* g, void* l) {
  __builtin_amdgcn_global_load_lds((const __attribute__((address_space(1))) void*)g,
                                   (__attribute__((address_space(3))) void*)l, 16, 0, 0);
}
__device__ __forceinline__ unsigned lds_off(const ushort_t* p) {
  return (unsigned)(uintptr_t)(__attribute__((address_space(3))) const ushort_t*)p;
}
// invisible LDS read: no compiler-inserted vmcnt drain before it
__device__ __forceinline__ bf16x8 ds_read128(unsigned off) {
  bf16x8 r;
  asm volatile("ds_read_b128 %0, %1" : "=v"(r) : "v"(off));
  return r;
}

// exact-erf GELU via Abramowitz-Stegun 7.1.26 (|err| <= 1.5e-7)
__device__ __forceinline__ float gelu_exact(float v) {
  float s = v * 0.70710678118654752f;
  float a = fabsf(s);
  float t = __builtin_amdgcn_rcpf(1.0f + 0.3275911f * a);
  float p = t * (0.254829592f +
            t * (-0.284496736f +
            t * (1.421413741f +
            t * (-1.453152027f +
            t * 1.061405429f))));
  float er = 1.0f - p * __expf(-a * a);
  er = copysignf(er, s);
  return 0.5f * v * (1.0f + er);
}

// ---------------- router + fused x->bf16 cast ----------------
__global__ __launch_bounds__(256) void k_router(
    const float* __restrict__ x, const float* __restrict__ rw, ushort_t* __restrict__ xbf,
    int* __restrict__ tidx, float* __restrict__ twt, int* __restrict__ counts) {
  int t = blockIdx.x;
  int tid = threadIdx.x;
  int lane = tid & 63, wave = tid >> 6;
  float acc[NE];
#pragma unroll
  for (int e = 0; e < NE; e++) acc[e] = 0.f;
  const float* xr = x + (size_t)t * DIM;
  ushort_t* xbr = xbf + (size_t)t * DIM;
#pragma unroll
  for (int it = 0; it < 2; it++) {
    int d4 = it * 1024 + tid * 4;
    float4 v = *reinterpret_cast<const float4*>(xr + d4);
    ushort4v o;
    o.x = f2bf(v.x); o.y = f2bf(v.y); o.z = f2bf(v.z); o.w = f2bf(v.w);
    *reinterpret_cast<ushort4v*>(xbr + d4) = o;
    const float* r0p = rw + (size_t)d4 * NE;
    float xv[4] = {v.x, v.y, v.z, v.w};
#pragma unroll
    for (int j = 0; j < 4; j++) {
      const float* r = r0p + j * NE;
#pragma unroll
      for (int e = 0; e < NE; e++) acc[e] += xv[j] * r[e];
    }
  }
  __shared__ float wsum[4][NE];
#pragma unroll
  for (int e = 0; e < NE; e++) {
    float v = acc[e];
#pragma unroll
    for (int off = 32; off > 0; off >>= 1) v += __shfl_down(v, off);
    if (lane == 0) wsum[wave][e] = v;
  }
  __syncthreads();
  if (tid == 0) {
    float lg[NE];
#pragma unroll
    for (int e = 0; e < NE; e++) lg[e] = wsum[0][e] + wsum[1][e] + wsum[2][e] + wsum[3][e];
    int i0 = 0; float v0 = lg[0];
#pragma unroll
    for (int e = 1; e < NE; e++) if (lg[e] > v0) { v0 = lg[e]; i0 = e; }
    int i1 = -1; float v1 = -3.4e38f;
#pragma unroll
    for (int e = 0; e < NE; e++) if (e != i0 && lg[e] > v1) { v1 = lg[e]; i1 = e; }
    float e1 = expf(v1 - v0);
    float s = 1.f + e1;
    tidx[t * 2 + 0] = i0; tidx[t * 2 + 1] = i1;
    twt[t * 2 + 0] = 1.f / s; twt[t * 2 + 1] = e1 / s;
    atomicAdd(&counts[i0], 1);
    atomicAdd(&counts[i1], 1);
  }
}

// ---------------- weight convert+transpose: fp32 [R][C] -> bf16 [C][R] ----------------
#define TT 64
__global__ __launch_bounds__(256) void k_wcvt(const float* __restrict__ in,
                                              ushort_t* __restrict__ outp, int R, int C) {
  __shared__ float t[TT][TT + 1];
  int e = blockIdx.z;
  const float* src = in + (size_t)e * R * C;
  ushort_t* dst = outp + (size_t)e * R * C;
  int r0 = blockIdx.y * TT, c0 = blockIdx.x * TT;
  int tid = threadIdx.x;
  int rr = tid >> 4;
  int c4 = tid & 15;
#pragma unroll
  for (int i = 0; i < 4; i++) {
    int r = rr + i * 16;
    float4 v = *reinterpret_cast<const float4*>(src + (size_t)(r0 + r) * C + c0 + c4 * 4);
    t[r][c4 * 4 + 0] = v.x; t[r][c4 * 4 + 1] = v.y;
    t[r][c4 * 4 + 2] = v.z; t[r][c4 * 4 + 3] = v.w;
  }
  __syncthreads();
  int c = tid >> 2, rs = tid & 3;
  ushort8 v0, v1;
#pragma unroll
  for (int i = 0; i < 8; i++) {
    v0[i] = f2bf(t[rs * 16 + i][c]);
    v1[i] = f2bf(t[rs * 16 + 8 + i][c]);
  }
  ushort_t* drow = dst + (size_t)(c0 + c) * R + r0 + rs * 16;
  *reinterpret_cast<ushort8*>(drow) = v0;
  *reinterpret_cast<ushort8*>(drow + 8) = v1;
}

__global__ void k_scan(const int* __restrict__ counts, int* __restrict__ offsets) {
  if (threadIdx.x == 0) {
    int s = 0;
    for (int e = 0; e < NE; e++) { offsets[e] = s; s += counts[e]; }
    offsets[NE] = s;
  }
}

__global__ void k_fill(const int* __restrict__ tidx, const float* __restrict__ twt,
                       const int* __restrict__ offsets, int* __restrict__ cursors,
                       int* __restrict__ ltok, float* __restrict__ lwt, int* __restrict__ ppos) {
  int t = blockIdx.x * blockDim.x + threadIdx.x;
  if (t >= T_TOK) return;
#pragma unroll
  for (int k = 0; k < TOPK; k++) {
    int e = tidx[t * 2 + k];
    int pos = atomicAdd(&cursors[e], 1);
    int p = offsets[e] + pos;
    ltok[p] = t;
    lwt[p] = twt[t * 2 + k];
    ppos[t * 2 + k] = p;
  }
}

__device__ __forceinline__ void xcd_decode(int lin, int nwg, int nx, int& xt, int& yt) {
  int q = nwg >> 3;
  int w = (lin & 7) * q + (lin >> 3);
  xt = w % nx;
  yt = w / nx;
}

// ======== 8-phase 256x256xBK64 GEMM pipeline + read-ahead (r15 + counted lgkm) ========
// LDS per op: [2 slot][2 half][128 x 64] bf16 = 64 KB; A+B = 128 KB.
// XOR swizzle: chunk c of row r holds logical c^(r&7); pre-swizzled source + read offset.
// Group T (slot s=T&1), phases (2 barriers/group — hazard-audited):
//  q0: BAR; read bv(8)+A0(4)+A1(4); STA(s^1,h0,T+1); lgkm(4)[bv,A0 done; A1 fly]; MFMA q0(A0)
//  q1: BAR; read A2;  STA(s^1,h1,T+1); STB(s,h0,T+2); lgkm(4)[A1 done; A2 fly]; MFMA q1(A1)
//  q2:      read A3;  STB(s,h1,T+2);                  lgkm(4)[A2 done; A3 fly]; MFMA q2(A2)
//  q3:                                                lgkm(0)[A3 done];         MFMA q3(A3); vmcnt(4)
// Hazards: q0-BAR covers STA WAR (prev group's A-reads done at its q3 lgkm0) and
// staged-landed for q0 reads (all waves' vmcnt precede it). q1-BAR covers STB WAR
// (bv reads done at q0 lgkm4). q2's STB(s,h1) covered by q1-BAR. vmcnt(4): leaves
// B(T+2)'s 4 newest; A(T+1),B(T+1) landed (in-order retirement).
#define QBM 256
#define QBN 256
#define QBK 64
#define QHALF_E (128 * 64)
#define QSLOT_E (2 * QHALF_E)

#define RD_A(RR, qq)                                                                    \
  RR[0][0] = ds_read128(aoff[(qq) * 2 + 0][0] + cb);                                    \
  RR[0][1] = ds_read128(aoff[(qq) * 2 + 0][1] + cb);                                    \
  RR[1][0] = ds_read128(aoff[(qq) * 2 + 1][0] + cb);                                    \
  RR[1][1] = ds_read128(aoff[(qq) * 2 + 1][1] + cb);

#define PH_MFMA(qq, RR)                                                                 \
  __builtin_amdgcn_s_setprio(1);                                                        \
  _Pragma("unroll")                                                                     \
  for (int mf = 0; mf < 2; mf++)                                                        \
    _Pragma("unroll")                                                                   \
    for (int nf = 0; nf < 4; nf++) {                                                    \
      acc[(qq) * 2 + mf][nf] = __builtin_amdgcn_mfma_f32_16x16x32_bf16(                 \
          RR[mf][0], bv[nf][0], acc[(qq) * 2 + mf][nf], 0, 0, 0);                       \
      acc[(qq) * 2 + mf][nf] = __builtin_amdgcn_mfma_f32_16x16x32_bf16(                 \
          RR[mf][1], bv[nf][1], acc[(qq) * 2 + mf][nf], 0, 0, 0);                       \
    }                                                                                   \
  __builtin_amdgcn_s_setprio(0);

#define GEMM8_PIPE(NT_)                                                                 \
  const int NT = (NT_);                                                                 \
  STA(0, 0, 0); STA(0, 1, 0);                                                           \
  STB(0, 0, 0); STB(0, 1, 0);                                                           \
  STB(1, 0, QBK); STB(1, 1, QBK);                                                       \
  asm volatile("s_waitcnt vmcnt(4)" ::: "memory");                                      \
  for (int T = 0; T < NT; ++T) {                                                        \
    int slot = T & 1;                                                                   \
    unsigned cb = (unsigned)(slot * QSLOT_E * 2);                                       \
    bf16x8 bv[4][2], rA[2][2], rB[2][2];                                                \
    /* q0 */                                                                            \
    __builtin_amdgcn_sched_barrier(0);                                                  \
    __builtin_amdgcn_s_barrier();                                                       \
    __builtin_amdgcn_sched_barrier(0);                                                  \
    _Pragma("unroll")                                                                   \
    for (int n = 0; n < 4; n++) {                                                       \
      bv[n][0] = ds_read128(boff[n][0] + cb);                                           \
      bv[n][1] = ds_read128(boff[n][1] + cb);                                           \
    }                                                                                   \
    RD_A(rA, 0)                                                                         \
    RD_A(rB, 1)                                                                         \
    if (T + 1 < NT) { STA(slot ^ 1, 0, (T + 1) * QBK); }                                \
    __builtin_amdgcn_sched_barrier(0);                                                  \
    asm volatile("s_waitcnt lgkmcnt(4)" ::: "memory");                                  \
    __builtin_amdgcn_sched_barrier(0);                                                  \
    PH_MFMA(0, rA)                                                                      \
    /* q1 */                                                                            \
    __builtin_amdgcn_sched_barrier(0);                                                  \
    __builtin_amdgcn_s_barrier();                                                       \
    __builtin_amdgcn_sched_barrier(0);                                                  \
    RD_A(rA, 2)                                                                         \
    if (T + 1 < NT) { STA(slot ^ 1, 1, (T + 1) * QBK); }                                \
    if (T + 2 < NT) { STB(slot, 0, (T + 2) * QBK); }                                    \
    __builtin_amdgcn_sched_barrier(0);                                                  \
    asm volatile("s_waitcnt lgkmcnt(4)" ::: "memory");                                  \
    __builtin_amdgcn_sched_barrier(0);                                                  \
    PH_MFMA(1, rB)                                                                      \
    /* q2 (no barrier needed: STB(s,h1) covered by q1-BAR) */                           \
    __builtin_amdgcn_sched_barrier(0);                                                  \
    RD_A(rB, 3)                                                                         \
    if (T + 2 < NT) { STB(slot, 1, (T + 2) * QBK); }                                    \
    __builtin_amdgcn_sched_barrier(0);                                                  \
    asm volatile("s_waitcnt lgkmcnt(4)" ::: "memory");                                  \
    __builtin_amdgcn_sched_barrier(0);                                                  \
    PH_MFMA(2, rA)                                                                      \
    /* q3 (registers only) */                                                           \
    __builtin_amdgcn_sched_barrier(0);                                                  \
    asm volatile("s_waitcnt lgkmcnt(0)" ::: "memory");                                  \
    __builtin_amdgcn_sched_barrier(0);                                                  \
    PH_MFMA(3, rB)                                                                      \
    __builtin_amdgcn_sched_barrier(0);                                                  \
    if (T < NT - 2) { asm volatile("s_waitcnt vmcnt(4)" ::: "memory"); }                \
    else            { asm volatile("s_waitcnt vmcnt(0)" ::: "memory"); }                \
    __builtin_amdgcn_sched_barrier(0);                                                  \
  }

// common per-thread setup for the 8-phase kernels
#define GEMM8_SETUP()                                                                   \
  int tid = threadIdx.x;                                                                \
  int wid = tid >> 6, lane = tid & 63;                                                  \
  int wm = wid >> 2, wn = wid & 3;                                                      \
  int lm = lane & 15, lg = lane >> 4;                                                   \
  unsigned abase = lds_off(As), bbase = lds_off(Bs);                                    \
  unsigned aoff[8][2], boff[4][2];                                                      \
  _Pragma("unroll")                                                                     \
  for (int m = 0; m < 8; m++)                                                           \
    _Pragma("unroll")                                                                   \
    for (int kk = 0; kk < 2; kk++)                                                      \
      aoff[m][kk] = abase + (unsigned)((wm * QHALF_E + (m * 16 + lm) * 64 +             \
                                        (((kk * 4 + lg) ^ (lm & 7)) * 8)) * 2);         \
  _Pragma("unroll")                                                                     \
  for (int n = 0; n < 4; n++)                                                           \
    _Pragma("unroll")                                                                   \
    for (int kk = 0; kk < 2; kk++)                                                      \
      boff[n][kk] = bbase + (unsigned)(((wn >> 1) * QHALF_E +                           \
                                        ((wn & 1) * 64 + n * 16 + lm) * 64 +            \
                                        (((kk * 4 + lg) ^ (lm & 7)) * 8)) * 2);         \
  f32x4 acc[8][4];                                                                      \
  _Pragma("unroll")                                                                     \
  for (int m = 0; m < 8; m++)                                                           \
    _Pragma("unroll")                                                                   \
    for (int n = 0; n < 4; n++) acc[m][n] = (f32x4){0.f, 0.f, 0.f, 0.f};

// GEMM1: H[p,f] = gelu( gather(x)[p,:] @ w1t[e]^T + b1[e] )   w1t: [F][D] bf16
__global__ __launch_bounds__(512) void k_gemm1(
    const ushort_t* __restrict__ xbf, const ushort_t* __restrict__ w1t, const float* __restrict__ b1,
    const int* __restrict__ counts, const int* __restrict__ offsets,
    const int* __restrict__ ltok, ushort_t* __restrict__ H) {
  int e = blockIdx.z;
  int cnt = counts[e];
  int xt, yt;
  xcd_decode(blockIdx.x, (T_TOK / QBM) * (FFN / QBN), T_TOK / QBM, xt, yt);
  int row0 = xt * QBM;
  if (row0 >= cnt) return;
  int base = offsets[e];
  int col0 = yt * QBN;
  const ushort_t* Bt = w1t + (size_t)e * DIM * FFN;

  __shared__ __align__(16) ushort_t As[2 * QSLOT_E];
  __shared__ __align__(16) ushort_t Bs[2 * QSLOT_E];

  // staging sources (pre-swizzled)
  const ushort_t* aS[2][2]; const ushort_t* bS[2][2];
#pragma unroll
  for (int l = 0; l < 2; l++) {
    int c = l * 512 + threadIdx.x;
    int rr = c >> 3;
    int s8 = (c & 7) ^ (rr & 7);
#pragma unroll
    for (int h = 0; h < 2; h++) {
      int ar = min(row0 + h * 128 + rr, cnt - 1);
      aS[h][l] = xbf + (size_t)ltok[base + ar] * DIM + s8 * 8;
      bS[h][l] = Bt + (size_t)(col0 + h * 128 + rr) * DIM + s8 * 8;
    }
  }
  int swid = threadIdx.x >> 6;
  auto STA = [&](int slot, int h, int k0) {
#pragma unroll
    for (int l = 0; l < 2; l++)
      gload16(aS[h][l] + k0, As + slot * QSLOT_E + h * QHALF_E + (l * 512 + swid * 64) * 8);
  };
  auto STB = [&](int slot, int h, int k0) {
#pragma unroll
    for (int l = 0; l < 2; l++)
      gload16(bS[h][l] + k0, Bs + slot * QSLOT_E + h * QHALF_E + (l * 512 + swid * 64) * 8);
  };

  GEMM8_SETUP();
  GEMM8_PIPE(DIM / QBK);

  // epilogue
#pragma unroll
  for (int m = 0; m < 8; m++) {
#pragma unroll
    for (int n = 0; n < 4; n++) {
      int f = col0 + wn * 64 + n * 16 + lm;
      float bias = b1[e * FFN + f];
#pragma unroll
      for (int r = 0; r < 4; r++) {
        int row = row0 + wm * 128 + m * 16 + lg * 4 + r;
        if (row < cnt) {
          float v = acc[m][n][r] + bias;
          H[(size_t)(base + row) * FFN + f] = f2bf(gelu_exact(v));
        }
      }
    }
  }
}

// GEMM2: contrib[p,d] = cw[p] * ( H[p,:] @ w2t[e]^T + b2[e] )   w2t: [D][F] bf16
__global__ __launch_bounds__(512) void k_gemm2(
    const ushort_t* __restrict__ H, const ushort_t* __restrict__ w2t, const float* __restrict__ b2,
    const int* __restrict__ counts, const int* __restrict__ offsets,
    const float* __restrict__ lwt, ushort_t* __restrict__ contrib) {
  int e = blockIdx.z;
  int cnt = counts[e];
  int xt, yt;
  xcd_decode(blockIdx.x, (T_TOK / QBM) * (DIM / QBN), T_TOK / QBM, xt, yt);
  int row0 = xt * QBM;
  if (row0 >= cnt) return;
  int base = offsets[e];
  int col0 = yt * QBN;
  const ushort_t* Bt = w2t + (size_t)e * DIM * FFN;

  __shared__ __align__(16) ushort_t As[2 * QSLOT_E];
  __shared__ __align__(16) ushort_t Bs[2 * QSLOT_E];

  const ushort_t* aS[2][2]; const ushort_t* bS[2][2];
#pragma unroll
  for (int l = 0; l < 2; l++) {
    int c = l * 512 + threadIdx.x;
    int rr = c >> 3;
    int s8 = (c & 7) ^ (rr & 7);
#pragma unroll
    for (int h = 0; h < 2; h++) {
      int ar = min(row0 + h * 128 + rr, cnt - 1);
      aS[h][l] = H + (size_t)(base + ar) * FFN + s8 * 8;
      bS[h][l] = Bt + (size_t)(col0 + h * 128 + rr) * FFN + s8 * 8;
    }
  }
  int swid = threadIdx.x >> 6;
  auto STA = [&](int slot, int h, int k0) {
#pragma unroll
    for (int l = 0; l < 2; l++)
      gload16(aS[h][l] + k0, As + slot * QSLOT_E + h * QHALF_E + (l * 512 + swid * 64) * 8);
  };
  auto STB = [&](int slot, int h, int k0) {
#pragma unroll
    for (int l = 0; l < 2; l++)
      gload16(bS[h][l] + k0, Bs + slot * QSLOT_E + h * QHALF_E + (l * 512 + swid * 64) * 8);
  };

  GEMM8_SETUP();
  GEMM8_PIPE(FFN / QBK);

  // epilogue
#pragma unroll
  for (int m = 0; m < 8; m++) {
#pragma unroll
    for (int n = 0; n < 4; n++) {
      int d = col0 + wn * 64 + n * 16 + lm;
      float bias = b2[e * DIM + d];
#pragma unroll
      for (int r = 0; r < 4; r++) {
        int row = row0 + wm * 128 + m * 16 + lg * 4 + r;
        if (row < cnt) {
          float v = (acc[m][n][r] + bias) * lwt[base + row];
          contrib[(size_t)(base + row) * DIM + d] = f2bf(v);
        }
      }
    }
  }
}

// ---------------- combine: out = x + contrib[p0] + contrib[p1] ----------------
__global__ void k_combine(const float* __restrict__ x, const ushort_t* __restrict__ contrib,
                          const int* __restrict__ ppos, float* __restrict__ out) {
  int i = blockIdx.x * blockDim.x + threadIdx.x;
  int t = i / (DIM / 4);
  int dq = i % (DIM / 4);
  int p0 = ppos[t * 2 + 0], p1 = ppos[t * 2 + 1];
  float4 xv = reinterpret_cast<const float4*>(x)[i];
  ushort4v c0 = reinterpret_cast<const ushort4v*>(contrib + (size_t)p0 * DIM)[dq];
  ushort4v c1 = reinterpret_cast<const ushort4v*>(contrib + (size_t)p1 * DIM)[dq];
  float4 o;
  o.x = xv.x + bf2f(c0.x) + bf2f(c1.x);
  o.y = xv.y + bf2f(c0.y) + bf2f(c1.y);
  o.z = xv.z + bf2f(c0.z) + bf2f(c1.z);
  o.w = xv.w + bf2f(c0.w) + bf2f(c1.w);
  reinterpret_cast<float4*>(out)[i] = o;
}

extern "C" void kernel_launch(void* const* d_in, const int* in_sizes, int n_in,
                              void* d_out, int out_size, void* d_ws, size_t ws_size,
                              hipStream_t stream) {
  const float* x  = (const float*)d_in[0];
  const float* rw = (const float*)d_in[1];
  const float* w1 = (const float*)d_in[2];
  const float* b1 = (const float*)d_in[3];
  const float* w2 = (const float*)d_in[4];
  const float* b2 = (const float*)d_in[5];
  float* out = (float*)d_out;
  char* ws = (char*)d_ws;

  const size_t MB = 1u << 20;
  int*   counts  = (int*)(ws);
  int*   offsets = (int*)(ws + 64);
  int*   cursors = (int*)(ws + 128);
  int*   tidx    = (int*)(ws + 1 * MB);
  float* twt     = (float*)(ws + 2 * MB);
  int*   ltok    = (int*)(ws + 3 * MB);
  float* lwt     = (float*)(ws + 4 * MB);
  int*   ppos    = (int*)(ws + 5 * MB);
  // overlaid big buffers (lifetimes disjoint where they overlap):
  ushort_t* xbf     = (ushort_t*)(ws + 8 * MB);     // 32 MB, live router..gemm1
  ushort_t* contrib = (ushort_t*)(ws + 8 * MB);     // 64 MB, live gemm2..combine (xbf dead)
  ushort_t* Hbuf    = (ushort_t*)(ws + 72 * MB);    // 256 MB, live gemm1..gemm2
  ushort_t* w1t     = (ushort_t*)(ws + 328 * MB);   // 256 MB, live wcvt1..gemm1
  ushort_t* w2t     = (ushort_t*)(ws + 328 * MB);   // 256 MB, live wcvt2..gemm2 (after gemm1)
  const size_t NEED = 584 * MB;
  if (ws_size < NEED) {
    hipMemsetAsync(d_out, 0, (size_t)out_size * sizeof(float), stream);
    return;
  }

  hipMemsetAsync(ws, 0, 256, stream);  // counts + cursors
  k_router<<<T_TOK, 256, 0, stream>>>(x, rw, xbf, tidx, twt, counts);
  k_scan<<<1, 64, 0, stream>>>(counts, offsets);
  k_fill<<<T_TOK / 256, 256, 0, stream>>>(tidx, twt, offsets, cursors, ltok, lwt, ppos);
  // w1: [E][D][F] fp32 -> w1t [E][F][D] bf16
  k_wcvt<<<dim3(FFN / TT, DIM / TT, NE), 256, 0, stream>>>(w1, w1t, DIM, FFN);
  k_gemm1<<<dim3((T_TOK / QBM) * (FFN / QBN), 1, NE), 512, 0, stream>>>(xbf, w1t, b1, counts, offsets, ltok, Hbuf);
  // w2: [E][F][D] fp32 -> w2t [E][D][F] bf16  (after gemm1; reuses w1t region)
  k_wcvt<<<dim3(DIM / TT, FFN / TT, NE), 256, 0, stream>>>(w2, w2t, FFN, DIM);
  k_gemm2<<<dim3((T_TOK / QBM) * (DIM / QBN), 1, NE), 512, 0, stream>>>(Hbuf, w2t, b2, counts, offsets, lwt, contrib);
  k_combine<<<dim3((T_TOK * (size_t)DIM / 4) / 256), 256, 0, stream>>>(x, contrib, ppos, out);
}